// Round 9
// baseline (459.037 us; speedup 1.0000x reference)
//
#include <hip/hip_runtime.h>
#include <hip/hip_bf16.h>
#include <cstddef>
#include <cstdint>

// Problem constants
#define D_MODEL 256
#define NHEAD   8
#define HDIM    32
#define NLEV    3
#define NPNT    4
#define DFF     1024
#define BATCH   8
#define LQ      3600
#define LIN     4725   // 60*60 + 30*30 + 15*15
#define MROWS   (BATCH*LQ)   // 28800; row order is (lq,b): m = lq*8 + b

typedef short bf16x8 __attribute__((ext_vector_type(8)));
typedef float f32x4  __attribute__((ext_vector_type(4)));

__device__ __forceinline__ unsigned short f2b(float x) {
    unsigned int u = __float_as_uint(x);
    unsigned int r = (u + 0x7fffu + ((u >> 16) & 1u)) >> 16;   // RNE
    return (unsigned short)r;
}
__device__ __forceinline__ float b2f(unsigned short s) {
    return __uint_as_float(((unsigned int)s) << 16);
}

#define GLDS16(g, l) __builtin_amdgcn_global_load_lds( \
    (const __attribute__((address_space(1))) void*)(g), \
    (__attribute__((address_space(3))) void*)(l), 16, 0, 0)

#define WAIT_VM0()  asm volatile("s_waitcnt vmcnt(0)" ::: "memory")
#define WAIT_LGKM0() asm volatile("s_waitcnt lgkmcnt(0)" ::: "memory")

// ---------------------------------------------------------------------------
// Merged prep: [0,7200) conv tgt->bf16; [7200,16650) conv src->bf16;
// [16650,17618) weight convert; [17618,17623) query_pos projections.
#define WTOT 991232
__global__ __launch_bounds__(256) void prep_kernel(
    const float* __restrict__ tgt, unsigned short* __restrict__ tgtb,
    const float* __restrict__ srcf, unsigned short* __restrict__ srcb,
    const float* __restrict__ w_in, const float* __restrict__ w_out,
    const float* __restrict__ w_val, const float* __restrict__ w_cross,
    const float* __restrict__ w_so, const float* __restrict__ w_aw,
    const float* __restrict__ w_f1, const float* __restrict__ w_f2,
    unsigned short* __restrict__ wdst,
    const float* __restrict__ qp, const float* __restrict__ so_b,
    const float* __restrict__ aw_b, float* __restrict__ qpv)
{
    const int bid = blockIdx.x;
    const int tid = threadIdx.x;
    if (bid < 7200) {
        int i = bid * 256 + tid;
        float4 v = ((const float4*)tgt)[i];
        ushort4 o; o.x = f2b(v.x); o.y = f2b(v.y); o.z = f2b(v.z); o.w = f2b(v.w);
        ((ushort4*)tgtb)[i] = o;
    } else if (bid < 16650) {
        int i = (bid - 7200) * 256 + tid;
        float4 v = ((const float4*)srcf)[i];
        ushort4 o; o.x = f2b(v.x); o.y = f2b(v.y); o.z = f2b(v.z); o.w = f2b(v.w);
        ((ushort4*)srcb)[i] = o;
    } else if (bid < 17618) {
        int idx = ((bid - 16650) * 256 + tid) * 4;
        if (idx >= WTOT) return;
        const float* src; int off;
        if      (idx < 196608) { src = w_in;    off = idx; }
        else if (idx < 262144) { src = w_out;   off = idx - 196608; }
        else if (idx < 327680) { src = w_val;   off = idx - 262144; }
        else if (idx < 393216) { src = w_cross; off = idx - 327680; }
        else if (idx < 442368) { src = w_so;    off = idx - 393216; }
        else if (idx < 466944) { src = w_aw;    off = idx - 442368; }
        else if (idx < 729088) { src = w_f1;    off = idx - 466944; }
        else                   { src = w_f2;    off = idx - 729088; }
        float4 v = *(const float4*)(src + off);
        ushort4 o; o.x = f2b(v.x); o.y = f2b(v.y); o.z = f2b(v.z); o.w = f2b(v.w);
        *(ushort4*)(wdst + idx) = o;
    } else {
        int o = (bid - 17618) * 256 + tid;
        if (o >= 768 + 192 + 96) return;
        const float* wrow;
        if (o < 768)       wrow = w_in + (size_t)o * D_MODEL;
        else if (o < 960)  wrow = w_so + (size_t)(o - 768) * D_MODEL;
        else               wrow = w_aw + (size_t)(o - 960) * D_MODEL;
        float acc = 0.f;
        for (int d = 0; d < D_MODEL; ++d) acc += qp[d] * wrow[d];
        qpv[o] = acc;
        if (o >= 768) {
            float bias = (o < 960) ? so_b[o - 768] : aw_b[o - 960];
            qpv[1056 + (o - 768)] = acc + bias;
        }
    }
}

// ---------------------------------------------------------------------------
// bf16 MFMA GEMM (R4 proven version): 128x128 tile, BK=64 (2x32 panels),
// global_load_lds width=16 staging.
__global__ __launch_bounds__(256) void gemm_bf16(
    const unsigned short* __restrict__ A,
    const unsigned short* __restrict__ W,
    const float* __restrict__ bias,
    const float* __restrict__ bias2, int b2lim,
    float* __restrict__ Cf, unsigned short* __restrict__ Cb,
    int M, int N, int K, int relu)
{
    __shared__ __align__(16) unsigned short As[2 * 128 * 32];   // 16 KB
    __shared__ __align__(16) unsigned short Bs[2 * 128 * 32];   // 16 KB
    const int tid  = threadIdx.x;
    const int wave = tid >> 6;
    const int lane = tid & 63;
    const int m0 = blockIdx.x * 128;
    const int n0 = blockIdx.y * 128;

    const int lr  = lane >> 2;
    const int lc8 = (lane & 3) * 8;
    int ar0 = m0 + wave * 32 + lr;      if (ar0 > M - 1) ar0 = M - 1;
    int ar1 = m0 + wave * 32 + 16 + lr; if (ar1 > M - 1) ar1 = M - 1;
    int br0 = n0 + wave * 32 + lr;      if (br0 > N - 1) br0 = N - 1;
    int br1 = n0 + wave * 32 + 16 + lr; if (br1 > N - 1) br1 = N - 1;
    const unsigned short* pa0 = A + (size_t)ar0 * K + lc8;
    const unsigned short* pa1 = A + (size_t)ar1 * K + lc8;
    const unsigned short* pb0 = W + (size_t)br0 * K + lc8;
    const unsigned short* pb1 = W + (size_t)br1 * K + lc8;
    unsigned short* la0 = As + wave * 1024;
    unsigned short* la1 = As + wave * 1024 + 512;
    unsigned short* lb0 = Bs + wave * 1024;
    unsigned short* lb1 = Bs + wave * 1024 + 512;

    const int wm = (wave >> 1) * 64;
    const int wn = (wave & 1) * 64;
    const int fr = lane & 15;
    const int fk = (lane >> 4) * 8;

    f32x4 acc[4][4] = {};

    for (int k0 = 0; k0 < K; k0 += 64) {
        GLDS16(pa0, la0); GLDS16(pa0 + 32, la0 + 4096);
        GLDS16(pa1, la1); GLDS16(pa1 + 32, la1 + 4096);
        GLDS16(pb0, lb0); GLDS16(pb0 + 32, lb0 + 4096);
        GLDS16(pb1, lb1); GLDS16(pb1 + 32, lb1 + 4096);
        pa0 += 64; pa1 += 64; pb0 += 64; pb1 += 64;
        __syncthreads();
#pragma unroll
        for (int p = 0; p < 2; ++p) {
            bf16x8 af[4], bfv[4];
#pragma unroll
            for (int i = 0; i < 4; ++i)
                af[i] = *(const bf16x8*)&As[p * 4096 + (wm + i * 16 + fr) * 32 + fk];
#pragma unroll
            for (int j = 0; j < 4; ++j)
                bfv[j] = *(const bf16x8*)&Bs[p * 4096 + (wn + j * 16 + fr) * 32 + fk];
#pragma unroll
            for (int i = 0; i < 4; ++i)
#pragma unroll
                for (int j = 0; j < 4; ++j)
                    acc[i][j] = __builtin_amdgcn_mfma_f32_16x16x32_bf16(
                        af[i], bfv[j], acc[i][j], 0, 0, 0);
        }
        __syncthreads();
    }

    const int quad = lane >> 4;
#pragma unroll
    for (int j = 0; j < 4; ++j) {
        const int col = n0 + wn + j * 16 + fr;
        if (col >= N) continue;
        float bv = 0.f;
        if (bias) bv += bias[col];
        if (bias2 && col < b2lim) bv += bias2[col];
#pragma unroll
        for (int i = 0; i < 4; ++i) {
#pragma unroll
            for (int r = 0; r < 4; ++r) {
                const int row = m0 + wm + i * 16 + quad * 4 + r;
                if (row >= M) continue;
                float v = acc[i][j][r] + bv;
                if (relu) v = fmaxf(v, 0.f);
                if (Cf) Cf[(size_t)row * N + col] = v;
                if (Cb) Cb[(size_t)row * N + col] = f2b(v);
            }
        }
    }
}

// ---------------------------------------------------------------------------
// GEMM (N=256, full row per block) + residual + LayerNorm fused (R4 proven).
// Now used only for LN2 (out_proj + tgt residual).
__global__ __launch_bounds__(256) void gemm_ln(
    const unsigned short* __restrict__ A,    // M x K bf16
    const unsigned short* __restrict__ W,    // 256 x K bf16
    const float* __restrict__ bias,          // 256
    const float* __restrict__ resid,         // M x 256 fp32
    const float* __restrict__ g, const float* __restrict__ bb,
    float* __restrict__ outf, unsigned short* __restrict__ outb, int K)
{
    __shared__ __align__(16) unsigned short As[2 * 64 * 32];    // 8 KB
    __shared__ __align__(16) unsigned short Bs[2 * 256 * 32];   // 32 KB
    const int tid  = threadIdx.x;
    const int wave = tid >> 6;
    const int lane = tid & 63;
    const int m0 = blockIdx.x * 64;

    const int arow = tid >> 2;
    const int akc  = (tid & 3) * 8;
    const unsigned short* pa = A + (size_t)(m0 + arow) * K + akc;
    unsigned short* la = As + tid * 8;
    const unsigned short* pb0 = W + (size_t)(arow)       * K + akc;
    const unsigned short* pb1 = W + (size_t)(64  + arow) * K + akc;
    const unsigned short* pb2 = W + (size_t)(128 + arow) * K + akc;
    const unsigned short* pb3 = W + (size_t)(192 + arow) * K + akc;
    unsigned short* lb0 = Bs + tid * 8;
    unsigned short* lb1 = Bs + 2048 + tid * 8;
    unsigned short* lb2 = Bs + 4096 + tid * 8;
    unsigned short* lb3 = Bs + 6144 + tid * 8;

    const int fr = lane & 15;
    const int fk = (lane >> 4) * 8;
    const int quad = lane >> 4;
    const int colbase = wave * 64;

    f32x4 acc[4][4] = {};

    for (int k0 = 0; k0 < K; k0 += 64) {
        GLDS16(pa, la);        GLDS16(pa + 32, la + 2048);
        GLDS16(pb0, lb0);      GLDS16(pb0 + 32, lb0 + 8192);
        GLDS16(pb1, lb1);      GLDS16(pb1 + 32, lb1 + 8192);
        GLDS16(pb2, lb2);      GLDS16(pb2 + 32, lb2 + 8192);
        GLDS16(pb3, lb3);      GLDS16(pb3 + 32, lb3 + 8192);
        pa += 64; pb0 += 64; pb1 += 64; pb2 += 64; pb3 += 64;
        __syncthreads();
#pragma unroll
        for (int p = 0; p < 2; ++p) {
            bf16x8 af[4], bfv[4];
#pragma unroll
            for (int i = 0; i < 4; ++i)
                af[i] = *(const bf16x8*)&As[p * 2048 + (i * 16 + fr) * 32 + fk];
#pragma unroll
            for (int j = 0; j < 4; ++j)
                bfv[j] = *(const bf16x8*)&Bs[p * 8192 + (colbase + j * 16 + fr) * 32 + fk];
#pragma unroll
            for (int i = 0; i < 4; ++i)
#pragma unroll
                for (int j = 0; j < 4; ++j)
                    acc[i][j] = __builtin_amdgcn_mfma_f32_16x16x32_bf16(
                        af[i], bfv[j], acc[i][j], 0, 0, 0);
        }
        __syncthreads();
    }

    // ---- fused epilogue: v = acc + bias + resid; LN over 256 cols ----
    float2* red = (float2*)As;   // 256 entries, aliases As (post-barrier safe)
    float rs[4][4], rq[4][4];
#pragma unroll
    for (int i = 0; i < 4; ++i) {
#pragma unroll
        for (int r = 0; r < 4; ++r) {
            const int row = m0 + i * 16 + quad * 4 + r;
            float s = 0.f, q = 0.f;
#pragma unroll
            for (int j = 0; j < 4; ++j) {
                const int col = colbase + j * 16 + fr;
                float v = acc[i][j][r] + bias[col] + resid[(size_t)row * 256 + col];
                acc[i][j][r] = v;
                s += v; q += v * v;
            }
            rs[i][r] = s; rq[i][r] = q;
        }
    }
#pragma unroll
    for (int off = 1; off < 16; off <<= 1) {
#pragma unroll
        for (int i = 0; i < 4; ++i)
#pragma unroll
            for (int r = 0; r < 4; ++r) {
                rs[i][r] += __shfl_xor(rs[i][r], off);
                rq[i][r] += __shfl_xor(rq[i][r], off);
            }
    }
    if ((lane & 15) == 0) {
#pragma unroll
        for (int i = 0; i < 4; ++i)
#pragma unroll
            for (int r = 0; r < 4; ++r)
                red[wave * 64 + i * 16 + quad * 4 + r] = make_float2(rs[i][r], rq[i][r]);
    }
    __syncthreads();
#pragma unroll
    for (int i = 0; i < 4; ++i) {
#pragma unroll
        for (int r = 0; r < 4; ++r) {
            const int rl = i * 16 + quad * 4 + r;
            const float2 t0 = red[rl], t1 = red[64 + rl], t2 = red[128 + rl], t3 = red[192 + rl];
            const float sum = t0.x + t1.x + t2.x + t3.x;
            const float sq  = t0.y + t1.y + t2.y + t3.y;
            const float mean = sum * (1.f / 256.f);
            const float var  = sq * (1.f / 256.f) - mean * mean;
            const float inv  = rsqrtf(var + 1e-5f);
            const int row = m0 + rl;
#pragma unroll
            for (int j = 0; j < 4; ++j) {
                const int col = colbase + j * 16 + fr;
                const float val = (acc[i][j][r] - mean) * inv * g[col] + bb[col];
                outf[(size_t)row * 256 + col] = val;
                if (outb) outb[(size_t)row * 256 + col] = f2b(val);
            }
        }
    }
}

// ---------------------------------------------------------------------------
// MEGAFUSED v2: cross_out GEMM + LN1 + FFN + LN3, wave-private staging
// pipeline. KEY INSIGHT (R8 audit): in every compute phase each wave reads
// ONLY the Wc quarter it staged itself (gemm1/cross: rows wave*16..+15 =
// its c=wave*8+j stage rows; gemm2: rows wave*64..+63 = ditto). So Wc
// staging needs NO cross-wave barriers — only hid, the A-stage, and the
// LN1 handoff are cross-wave. New schedule per h (2 barriers, was 4):
//   [bar: W1[h] drained] bv<-ds_read own region; lgkmcnt(0);
//   GLDS W2[h] -> own region (overwrite safe: regs hold data);
//   gemm1 MFMA; hid write; bar (drains W2[h], covered by gemm1 time);
//   b2v,a2 <- ds_read; lgkmcnt(0); GLDS W1[h+1]; gemm2 MFMA;
//   bar (drains W1[h+1], covered by gemm2).
// Cross loop: zero barriers (wave-local vmcnt(0) waits only).
// Numerics identical to R8 (same K-order, same rounding points).
// NO min-waves bound (R1/R2 spill lesson; VGPR/WRITE_SIZE tripwires).
__global__ __launch_bounds__(256) void cross_ffn_kernel(
    const unsigned short* __restrict__ A,     // msoutb M x 256 bf16
    const unsigned short* __restrict__ Wcr,   // 256 x 256 bf16 (cross_out)
    const float* __restrict__ bcr,            // cross_out_b
    const float* __restrict__ resid1,         // t (LN2 out) M x 256 fp32
    const float* __restrict__ g1, const float* __restrict__ b1g,
    float* __restrict__ t2,                   // scratch M x 256 fp32
    const unsigned short* __restrict__ W1,    // 1024 x 256 bf16
    const float* __restrict__ b1,             // 1024
    const unsigned short* __restrict__ W2,    // 256 x 1024 bf16
    const float* __restrict__ b2,             // 256
    const float* __restrict__ g3, const float* __restrict__ b3g,
    float* __restrict__ outf)
{
    __shared__ __align__(16) unsigned short Wc[16384];   // A-stage / W-chunks
    __shared__ __align__(16) unsigned short hid[2304];   // 32 x 72 (padded)
    const int tid  = threadIdx.x;
    const int wave = tid >> 6;
    const int lane = tid & 63;
    const int m0 = blockIdx.x * 32;
    const int fr   = lane & 15;
    const int quad = lane >> 4;
    const int xm   = fr & 7;           // XOR mask for swizzled fragment reads
    float2* red = (float2*)hid;        // 128 float2 = 1 KB (LN reductions)

    // ---- stage A=msout (32 rows) into Wc[0..8192), swizzled ----
#pragma unroll
    for (int j = 0; j < 4; ++j) {
        const int c  = wave * 4 + j;               // 0..15
        const int rA = c * 2 + (lane >> 5);        // row 0..31
        const int k8 = (lane & 31) ^ (rA & 7);
        GLDS16(A + (size_t)(m0 + rA) * 256 + k8 * 8, Wc + c * 512);
    }
    // ---- per-lane swizzled staging offsets for 64-row x 256-k chunks ----
    int w1off[8], w2off[8];
#pragma unroll
    for (int j = 0; j < 8; ++j) {
        const int c  = wave * 8 + j;               // 0..31
        const int n1 = c * 2 + (lane >> 5);        // chunk row 0..63
        const int k1 = (lane & 31) ^ (n1 & 7);
        w1off[j] = n1 * 256 + k1 * 8;              // + chunk*16384
        const int n2 = c * 8 + (lane >> 3);        // W2 row 0..255
        const int k2 = (lane & 7) ^ (n2 & 7);
        w2off[j] = n2 * 1024 + k2 * 8;             // + h*64
    }
    __syncthreads();                   // A visible (cross-wave af reads)
    bf16x8 af[2][8];
#pragma unroll
    for (int i = 0; i < 2; ++i)
#pragma unroll
        for (int s = 0; s < 8; ++s)
            af[i][s] = *(const bf16x8*)&Wc[((i * 16 + fr) * 32 + ((s * 4 + quad) ^ xm)) * 8];
    WAIT_LGKM0();
    __syncthreads();                   // all af reads done before Wcr stage

    // ================= PHASE 1: cross_out GEMM (4 chunks, 0 barriers) =====
    // Each wave stages+reads only its own Wc quarter -> wave-local waits.
#pragma unroll
    for (int j = 0; j < 8; ++j)
        GLDS16(Wcr + w1off[j], Wc + (wave * 8 + j) * 512);
    f32x4 accc[4][2] = {};
    for (int c = 0; c < 4; ++c) {
        WAIT_VM0();                    // Wcr[c] arrived (wave-local)
        bf16x8 bv[8];
#pragma unroll
        for (int s = 0; s < 8; ++s)
            bv[s] = *(const bf16x8*)&Wc[((wave * 16 + fr) * 32 + ((s * 4 + quad) ^ xm)) * 8];
        WAIT_LGKM0();                  // reads done before overwrite
        if (c < 3) {
#pragma unroll
            for (int j = 0; j < 8; ++j)
                GLDS16(Wcr + (size_t)(c + 1) * 16384 + w1off[j], Wc + (wave * 8 + j) * 512);
        }
#pragma unroll
        for (int s = 0; s < 8; ++s) {
            accc[c][0] = __builtin_amdgcn_mfma_f32_16x16x32_bf16(af[0][s], bv[s], accc[c][0], 0, 0, 0);
            accc[c][1] = __builtin_amdgcn_mfma_f32_16x16x32_bf16(af[1][s], bv[s], accc[c][1], 0, 0, 0);
        }
    }

    // ---- LN1: v = accc + bcr + resid1; normalize over 256 cols ----
    float rs[2][4], rq[2][4];
#pragma unroll
    for (int x = 0; x < 2; ++x) {
#pragma unroll
        for (int r = 0; r < 4; ++r) {
            const int row = m0 + x * 16 + quad * 4 + r;
            float s = 0.f, q = 0.f;
#pragma unroll
            for (int c = 0; c < 4; ++c) {
                const int col = c * 64 + wave * 16 + fr;
                float v = accc[c][x][r] + bcr[col] + resid1[(size_t)row * 256 + col];
                accc[c][x][r] = v;
                s += v; q += v * v;
            }
            rs[x][r] = s; rq[x][r] = q;
        }
    }
#pragma unroll
    for (int off = 1; off < 16; off <<= 1) {
#pragma unroll
        for (int x = 0; x < 2; ++x)
#pragma unroll
            for (int r = 0; r < 4; ++r) {
                rs[x][r] += __shfl_xor(rs[x][r], off);
                rq[x][r] += __shfl_xor(rq[x][r], off);
            }
    }
    if ((lane & 15) == 0) {
#pragma unroll
        for (int x = 0; x < 2; ++x)
#pragma unroll
            for (int r = 0; r < 4; ++r)
                red[wave * 32 + x * 16 + quad * 4 + r] = make_float2(rs[x][r], rq[x][r]);
    }
    __syncthreads();   // red visible; all waves' c=3 Wc reads done (handoff safe)
#pragma unroll
    for (int x = 0; x < 2; ++x) {
#pragma unroll
        for (int r = 0; r < 4; ++r) {
            const int rl = x * 16 + quad * 4 + r;
            const float2 t0 = red[rl], t1 = red[32 + rl], t2r = red[64 + rl], t3 = red[96 + rl];
            const float sum = t0.x + t1.x + t2r.x + t3.x;
            const float sq  = t0.y + t1.y + t2r.y + t3.y;
            const float mean = sum * (1.f / 256.f);
            const float var  = sq * (1.f / 256.f) - mean * mean;
            const float inv  = rsqrtf(var + 1e-5f);
            const int row = m0 + rl;
#pragma unroll
            for (int c = 0; c < 4; ++c) {
                const int col = c * 64 + wave * 16 + fr;
                const float val = (accc[c][x][r] - mean) * inv * g1[col] + b1g[col];
                t2[(size_t)row * 256 + col] = val;
                // bf16 handoff into A-stage layout (local row rl, col)
                const int g8 = col >> 3;
                Wc[rl * 256 + ((g8 ^ (rl & 7)) << 3) + (col & 7)] = f2b(val);
            }
        }
    }
    __syncthreads();   // handoff visible; red reads done
    // reload af = LN1 output fragments
#pragma unroll
    for (int i = 0; i < 2; ++i)
#pragma unroll
        for (int s = 0; s < 8; ++s)
            af[i][s] = *(const bf16x8*)&Wc[((i * 16 + fr) * 32 + ((s * 4 + quad) ^ xm)) * 8];
    WAIT_LGKM0();
    __syncthreads();   // all af reloads done before W1[0] stage overwrites

    // ================= PHASE 2: FFN, 2 barriers per h =================
#pragma unroll
    for (int j = 0; j < 8; ++j)
        GLDS16(W1 + w1off[j], Wc + (wave * 8 + j) * 512);
    WAIT_VM0();        // W1[0] arrived (first iter only: exposed)

    f32x4 acc2[2][4] = {};

    for (int h = 0; h < 16; ++h) {
        // ---- gemm1: bv from own W1 region -> regs; restage own region ----
        bf16x8 bv[8];
#pragma unroll
        for (int s = 0; s < 8; ++s)
            bv[s] = *(const bf16x8*)&Wc[((wave * 16 + fr) * 32 + ((s * 4 + quad) ^ xm)) * 8];
        WAIT_LGKM0();
#pragma unroll
        for (int j = 0; j < 8; ++j)
            GLDS16(W2 + (size_t)h * 64 + w2off[j], Wc + (wave * 8 + j) * 512);
        f32x4 acc1[2] = {};
#pragma unroll
        for (int s = 0; s < 8; ++s) {
            acc1[0] = __builtin_amdgcn_mfma_f32_16x16x32_bf16(af[0][s], bv[s], acc1[0], 0, 0, 0);
            acc1[1] = __builtin_amdgcn_mfma_f32_16x16x32_bf16(af[1][s], bv[s], acc1[1], 0, 0, 0);
        }
        const float bias1 = b1[h * 64 + wave * 16 + fr];
#pragma unroll
        for (int i = 0; i < 2; ++i)
#pragma unroll
            for (int r = 0; r < 4; ++r) {
                float v = fmaxf(acc1[i][r] + bias1, 0.f);
                hid[(i * 16 + quad * 4 + r) * 72 + wave * 16 + fr] = f2b(v);
            }
        __syncthreads();   // hid visible; W2[h] drained (covered by gemm1)
        // ---- gemm2: b2v from own W2 region + a2 from hid -> regs ----
#pragma unroll
        for (int s = 0; s < 2; ++s) {
            bf16x8 a2[2], b2v[4];
#pragma unroll
            for (int j2 = 0; j2 < 4; ++j2) {
                const int nb = wave * 64 + j2 * 16 + fr;
                b2v[j2] = *(const bf16x8*)&Wc[(nb * 8 + ((s * 4 + quad) ^ xm)) * 8];
            }
#pragma unroll
            for (int i = 0; i < 2; ++i)
                a2[i] = *(const bf16x8*)&hid[(i * 16 + fr) * 72 + s * 32 + quad * 8];
            if (s == 1) {
                WAIT_LGKM0();          // all Wc/hid reads done
                if (h < 15) {
#pragma unroll
                    for (int j = 0; j < 8; ++j)
                        GLDS16(W1 + (size_t)(h + 1) * 16384 + w1off[j], Wc + (wave * 8 + j) * 512);
                }
            }
#pragma unroll
            for (int i = 0; i < 2; ++i)
#pragma unroll
                for (int j2 = 0; j2 < 4; ++j2)
                    acc2[i][j2] = __builtin_amdgcn_mfma_f32_16x16x32_bf16(
                        a2[i], b2v[j2], acc2[i][j2], 0, 0, 0);
        }
        __syncthreads();   // hid free for next h; W1[h+1] drained (covered)
    }

    // ---- epilogue: v = acc2 + b2 + t2(resid, self-written); LN3 ----
    const int colbase = wave * 64;
#pragma unroll
    for (int x = 0; x < 2; ++x) {
#pragma unroll
        for (int r = 0; r < 4; ++r) {
            const int row = m0 + x * 16 + quad * 4 + r;
            float s = 0.f, q = 0.f;
#pragma unroll
            for (int y = 0; y < 4; ++y) {
                const int col = colbase + y * 16 + fr;
                float v = acc2[x][y][r] + b2[col] + t2[(size_t)row * 256 + col];
                acc2[x][y][r] = v;
                s += v; q += v * v;
            }
            rs[x][r] = s; rq[x][r] = q;
        }
    }
#pragma unroll
    for (int off = 1; off < 16; off <<= 1) {
#pragma unroll
        for (int x = 0; x < 2; ++x)
#pragma unroll
            for (int r = 0; r < 4; ++r) {
                rs[x][r] += __shfl_xor(rs[x][r], off);
                rq[x][r] += __shfl_xor(rq[x][r], off);
            }
    }
    if ((lane & 15) == 0) {
#pragma unroll
        for (int x = 0; x < 2; ++x)
#pragma unroll
            for (int r = 0; r < 4; ++r)
                red[wave * 32 + x * 16 + quad * 4 + r] = make_float2(rs[x][r], rq[x][r]);
    }
    __syncthreads();
#pragma unroll
    for (int x = 0; x < 2; ++x) {
#pragma unroll
        for (int r = 0; r < 4; ++r) {
            const int rl = x * 16 + quad * 4 + r;
            const float2 t0 = red[rl], t1 = red[32 + rl], t2r = red[64 + rl], t3 = red[96 + rl];
            const float sum = t0.x + t1.x + t2r.x + t3.x;
            const float sq  = t0.y + t1.y + t2r.y + t3.y;
            const float mean = sum * (1.f / 256.f);
            const float var  = sq * (1.f / 256.f) - mean * mean;
            const float inv  = rsqrtf(var + 1e-5f);
            const int row = m0 + rl;
#pragma unroll
            for (int y = 0; y < 4; ++y) {
                const int col = colbase + y * 16 + fr;
                outf[(size_t)row * 256 + col] = (acc2[x][y][r] - mean) * inv * g3[col] + b3g[col];
            }
        }
    }
}

// ---------------------------------------------------------------------------
// Self-attention over S=8 (batch axis). Row order (lq,b): row = n*8 + s.
__global__ __launch_bounds__(256) void self_attn_kernel(
    const unsigned short* __restrict__ qkv, unsigned short* __restrict__ ctx)
{
    __shared__ float sh[8][768];
    __shared__ float ls[8][8][8];   // [h][s][t]
    const int n = blockIdx.x;
    const int t = threadIdx.x;
#pragma unroll
    for (int s = 0; s < 8; ++s) {
        const unsigned short* row = qkv + (size_t)(n * 8 + s) * 768;
        sh[s][t]       = b2f(row[t]);
        sh[s][t + 256] = b2f(row[t + 256]);
        sh[s][t + 512] = b2f(row[t + 512]);
    }
    __syncthreads();
    const int h = t >> 5, j = t & 31;
#pragma unroll
    for (int pair = j; pair < 64; pair += 32) {
        const int s = pair >> 3, tt = pair & 7;
        float acc = 0.f;
#pragma unroll
        for (int d = 0; d < 32; ++d)
            acc += sh[s][h * 32 + d] * sh[tt][256 + h * 32 + d];
        ls[h][s][tt] = acc * 0.17677669529663687f;
    }
    __syncthreads();
    if (t < 64) {
        const int hh = t >> 3, s = t & 7;
        float mx = -1e30f;
        for (int tt = 0; tt < 8; ++tt) mx = fmaxf(mx, ls[hh][s][tt]);
        float sum = 0.f;
        for (int tt = 0; tt < 8; ++tt) { float e = expf(ls[hh][s][tt] - mx); ls[hh][s][tt] = e; sum += e; }
        const float inv = 1.f / sum;
        for (int tt = 0; tt < 8; ++tt) ls[hh][s][tt] *= inv;
    }
    __syncthreads();
#pragma unroll
    for (int s = 0; s < 8; ++s) {
        float acc = 0.f;
#pragma unroll
        for (int tt = 0; tt < 8; ++tt)
            acc += ls[h][s][tt] * sh[tt][512 + h * 32 + j];
        ctx[(size_t)(n * 8 + s) * D_MODEL + h * 32 + j] = f2b(acc);
    }
}

// ---------------------------------------------------------------------------
// Merged msprep + deformable sampling (R6 proven).
__global__ __launch_bounds__(256) void msdeform_kernel(
    const unsigned short* __restrict__ value,
    const float* __restrict__ comb,
    unsigned short* __restrict__ out)
{
    const int bid = blockIdx.x;
    const int b   = bid & 7;
    const int lq0 = (bid >> 3) * 4;
    const int r    = threadIdx.x >> 6;
    const int lane = threadIdx.x & 63;
    const int h = lane >> 3;
    const int l = lane & 7;
    const int lq = lq0 + r;
    const int m = lq * 8 + b;

    // ---- load raw offsets + attention logits for (m,h) ----
    const float* offp = comb + (size_t)m * 288 + h * 24;
    const float* awp  = comb + (size_t)m * 288 + 192 + h * 12;
    float off[24], aw[12];
#pragma unroll
    for (int i = 0; i < 6; ++i) *(float4*)&off[i * 4] = ((const float4*)offp)[i];
#pragma unroll
    for (int i = 0; i < 3; ++i) *(float4*)&aw[i * 4] = ((const float4*)awp)[i];

    float mx = aw[0];
#pragma unroll
    for (int i = 1; i < 12; ++i) mx = fmaxf(mx, aw[i]);
    float se = 0.f;
#pragma unroll
    for (int i = 0; i < 12; ++i) { aw[i] = __expf(aw[i] - mx); se += aw[i]; }
    const float inv = 1.f / se;

    const float refx = ((lq % 60) + 0.5f) * (1.f / 60.f);
    const float refy = ((lq / 60) + 0.5f) * (1.f / 60.f);
    const int HW[3] = {60, 30, 15};
    const int ST[3] = {0, 3600, 4500};

    const unsigned short* vbase = value + (size_t)b * LIN * 256 + h * 32 + l * 4;

    float a0 = 0.f, a1 = 0.f, a2 = 0.f, a3 = 0.f;
#pragma unroll
    for (int lev = 0; lev < NLEV; ++lev) {
        const int Wl = HW[lev], s0 = ST[lev];
        const float fWl = (float)Wl;
#pragma unroll
        for (int p = 0; p < NPNT; ++p) {
            const int pt = lev * 4 + p;
            const float ox = off[lev * 8 + p * 2];
            const float oy = off[lev * 8 + p * 2 + 1];
            const float px = refx * fWl + ox - 0.5f;
            const float py = refy * fWl + oy - 0.5f;
            const float x0f = floorf(px), y0f = floorf(py);
            const float fx = px - x0f, fy = py - y0f;
            const int x0 = (int)x0f, y0 = (int)y0f;
            const float aww = aw[pt] * inv;
            const float vx0 = (x0 >= 0 && x0 < Wl) ? 1.f : 0.f;
            const float vx1 = (x0 >= -1 && x0 < Wl - 1) ? 1.f : 0.f;
            const float vy0 = (y0 >= 0 && y0 < Wl) ? 1.f : 0.f;
            const float vy1 = (y0 >= -1 && y0 < Wl - 1) ? 1.f : 0.f;
            const int xc0 = min(max(x0, 0), Wl - 1);
            const int xc1 = min(max(x0 + 1, 0), Wl - 1);
            const int yc0 = min(max(y0, 0), Wl - 1);
            const int yc1 = min(max(y0 + 1, 0), Wl - 1);
            const int sx  = xc1 - xc0;
            const int syW = (yc1 - yc0) * Wl;
            const int i00 = s0 + yc0 * Wl + xc0;
            const float w00 = (1.f - fx) * (1.f - fy) * aww * vx0 * vy0;
            const float w01 = fx * (1.f - fy) * aww * vx1 * vy0;
            const float w10 = (1.f - fx) * fy * aww * vx0 * vy1;
            const float w11 = fx * fy * aww * vx1 * vy1;
            const int i01 = i00 + sx;
            const int i10 = i00 + syW;
            const int i11 = i10 + sx;
            const ushort4 g00 = *(const ushort4*)(vbase + (size_t)i00 * 256);
            const ushort4 g01 = *(const ushort4*)(vbase + (size_t)i01 * 256);
            const ushort4 g10 = *(const ushort4*)(vbase + (size_t)i10 * 256);
            const ushort4 g11 = *(const ushort4*)(vbase + (size_t)i11 * 256);
            a0 += b2f(g00.x) * w00 + b2f(g01.x) * w01 + b2f(g10.x) * w10 + b2f(g11.x) * w11;
            a1 += b2f(g00.y) * w00 + b2f(g01.y) * w01 + b2f(g10.y) * w10 + b2f(g11.y) * w11;
            a2 += b2f(g00.z) * w00 + b2f(g01.z) * w01 + b2f(g10.z) * w10 + b2f(g11.z) * w11;
            a3 += b2f(g00.w) * w00 + b2f(g01.w) * w01 + b2f(g10.w) * w10 + b2f(g11.w) * w11;
        }
    }
    ushort4 o;
    o.x = f2b(a0); o.y = f2b(a1); o.z = f2b(a2); o.w = f2b(a3);
    *(ushort4*)(out + (size_t)m * 256 + h * 32 + l * 4) = o;
}

// ---------------------------------------------------------------------------
extern "C" void kernel_launch(void* const* d_in, const int* in_sizes, int n_in,
                              void* d_out, int out_size, void* d_ws, size_t ws_size,
                              hipStream_t stream)
{
    (void)in_sizes; (void)n_in; (void)out_size; (void)ws_size;
    const float* tgt          = (const float*)d_in[0];   // (LQ,B,D): (lq,b)-major rows
    const float* qp           = (const float*)d_in[1];
    const float* src          = (const float*)d_in[2];
    const float* in_proj_w    = (const float*)d_in[5];
    const float* in_proj_b    = (const float*)d_in[6];
    const float* out_proj_w   = (const float*)d_in[7];
    const float* out_proj_b   = (const float*)d_in[8];
    const float* samp_off_w   = (const float*)d_in[9];
    const float* samp_off_b   = (const float*)d_in[10];
    const float* attn_w_w     = (const float*)d_in[11];
    const float* attn_w_b     = (const float*)d_in[12];
    const float* value_proj_w = (const float*)d_in[13];
    const float* value_proj_b = (const float*)d_in[14];
    const float* cross_out_w  = (const float*)d_in[15];
    const float* cross_out_b  = (const float*)d_in[16];
    const float* ln1_g = (const float*)d_in[17];
    const float* ln1_b = (const float*)d_in[18];
    const float* ln2_g = (const float*)d_in[19];
    const float* ln2_b = (const float*)d_in[20];
    const float* ln3_g = (const float*)d_in[21];
    const float* ln3_b = (const float*)d_in[22];
    const float* ffn_w1 = (const float*)d_in[23];
    const float* ffn_b1 = (const float*)d_in[24];
    const float* ffn_w2 = (const float*)d_in[25];
    const float* ffn_b2 = (const float*)d_in[26];
    float* out = (float*)d_out;

    // ---- fp32 arena (floats) ----
    float* ws    = (float*)d_ws;
    float* t     = ws;                    // LN2 out (residual for LN1)
    float* t2    = ws + 7372800;          // LN1 out scratch (cross_ffn self RW)
    float* comb  = ws + 14745600;         // 28800x288 off+aw (raw, fp32)
    float* qpv   = ws + 23040000;         // 1056 qp-proj + 288 cbias
    float* cbias = qpv + 1056;

    // ---- bf16 arena (ushort), after fp32 arena (byte 92,165,376) ----
    unsigned short* bws    = (unsigned short*)((char*)d_ws + 92165376);
    unsigned short* s1     = bws;                  // tgtb -> ctxb -> tb
    unsigned short* tgtb   = s1;
    unsigned short* ctxb   = s1;
    unsigned short* tb     = s1;
    unsigned short* s2     = bws + 7372800;        // qkvb / valueb+msoutb
    unsigned short* qkvb   = s2;
    unsigned short* valueb = s2;
    unsigned short* msoutb = s2 + 9676800;
    unsigned short* srcb   = bws + 36864000;
    unsigned short* wtsb   = bws + 46540800;       // 991,232 shorts

    // 1. merged prep (conversions + weight cast + query_pos projections)
    prep_kernel<<<17623, 256, 0, stream>>>(tgt, tgtb, src, srcb,
                                           in_proj_w, out_proj_w, value_proj_w,
                                           cross_out_w, samp_off_w, attn_w_w,
                                           ffn_w1, ffn_w2, wtsb,
                                           qp, samp_off_b, attn_w_b, qpv);
    // 2. QKV projection (Q,K cols get query_pos bias via qpv, cols < 512)
    gemm_bf16<<<dim3(225, 6), 256, 0, stream>>>(tgtb, wtsb + 0, in_proj_b, qpv, 512,
                                                nullptr, qkvb, MROWS, 768, 256, 0);
    // 3. self-attention over batch axis
    self_attn_kernel<<<3600, 256, 0, stream>>>(qkvb, ctxb);
    // 4. t = LN2(tgt + out_proj(ctx))   [fused; in-place ctxb->tb safe]
    gemm_ln<<<450, 256, 0, stream>>>(ctxb, wtsb + 196608, out_proj_b, tgt,
                                     ln2_g, ln2_b, t, tb, 256);
    // 5. value projection (M = 37800)
    gemm_bf16<<<dim3(296, 2), 256, 0, stream>>>(srcb, wtsb + 262144, value_proj_b, nullptr, 0,
                                                nullptr, valueb, BATCH * LIN, 256, 256, 0);
    // 6. fused sampling-offset + attn-weight projection (N = 288)
    gemm_bf16<<<dim3(225, 3), 256, 0, stream>>>(tb, wtsb + 393216, cbias, nullptr, 0,
                                                comb, nullptr, MROWS, 288, 256, 0);
    // 7. deformable sampling with inline softmax/bilinear setup
    msdeform_kernel<<<7200, 256, 0, stream>>>(valueb, comb, msoutb);
    // 8. out = LN3(t2 + FFN(t2)), t2 = LN1(t + cross_out(msout))  [megafused]
    cross_ffn_kernel<<<900, 256, 0, stream>>>(msoutb, wtsb + 327680, cross_out_b,
                                              t, ln1_g, ln1_b, t2,
                                              wtsb + 466944, ffn_b1,
                                              wtsb + 729088, ffn_b2,
                                              ln3_g, ln3_b, out);
}

// Round 10
// 445.616 us; speedup vs baseline: 1.0301x; 1.0301x over previous
//
#include <hip/hip_runtime.h>
#include <hip/hip_bf16.h>
#include <cstddef>
#include <cstdint>

// Problem constants
#define D_MODEL 256
#define NHEAD   8
#define HDIM    32
#define NLEV    3
#define NPNT    4
#define DFF     1024
#define BATCH   8
#define LQ      3600
#define LIN     4725   // 60*60 + 30*30 + 15*15
#define MROWS   (BATCH*LQ)   // 28800; row order is (lq,b): m = lq*8 + b

typedef short bf16x8 __attribute__((ext_vector_type(8)));
typedef float f32x4  __attribute__((ext_vector_type(4)));

__device__ __forceinline__ unsigned short f2b(float x) {
    unsigned int u = __float_as_uint(x);
    unsigned int r = (u + 0x7fffu + ((u >> 16) & 1u)) >> 16;   // RNE
    return (unsigned short)r;
}
__device__ __forceinline__ float b2f(unsigned short s) {
    return __uint_as_float(((unsigned int)s) << 16);
}

#define GLDS16(g, l) __builtin_amdgcn_global_load_lds( \
    (const __attribute__((address_space(1))) void*)(g), \
    (__attribute__((address_space(3))) void*)(l), 16, 0, 0)

#define WAIT_VM0()  asm volatile("s_waitcnt vmcnt(0)" ::: "memory")
#define WAIT_LGKM0() asm volatile("s_waitcnt lgkmcnt(0)" ::: "memory")

// ---------------------------------------------------------------------------
// Merged prep: [0,7200) conv tgt->bf16; [7200,16650) conv src->bf16;
// [16650,17618) weight convert; [17618,17623) query_pos projections.
#define WTOT 991232
__global__ __launch_bounds__(256) void prep_kernel(
    const float* __restrict__ tgt, unsigned short* __restrict__ tgtb,
    const float* __restrict__ srcf, unsigned short* __restrict__ srcb,
    const float* __restrict__ w_in, const float* __restrict__ w_out,
    const float* __restrict__ w_val, const float* __restrict__ w_cross,
    const float* __restrict__ w_so, const float* __restrict__ w_aw,
    const float* __restrict__ w_f1, const float* __restrict__ w_f2,
    unsigned short* __restrict__ wdst,
    const float* __restrict__ qp, const float* __restrict__ so_b,
    const float* __restrict__ aw_b, float* __restrict__ qpv)
{
    const int bid = blockIdx.x;
    const int tid = threadIdx.x;
    if (bid < 7200) {
        int i = bid * 256 + tid;
        float4 v = ((const float4*)tgt)[i];
        ushort4 o; o.x = f2b(v.x); o.y = f2b(v.y); o.z = f2b(v.z); o.w = f2b(v.w);
        ((ushort4*)tgtb)[i] = o;
    } else if (bid < 16650) {
        int i = (bid - 7200) * 256 + tid;
        float4 v = ((const float4*)srcf)[i];
        ushort4 o; o.x = f2b(v.x); o.y = f2b(v.y); o.z = f2b(v.z); o.w = f2b(v.w);
        ((ushort4*)srcb)[i] = o;
    } else if (bid < 17618) {
        int idx = ((bid - 16650) * 256 + tid) * 4;
        if (idx >= WTOT) return;
        const float* src; int off;
        if      (idx < 196608) { src = w_in;    off = idx; }
        else if (idx < 262144) { src = w_out;   off = idx - 196608; }
        else if (idx < 327680) { src = w_val;   off = idx - 262144; }
        else if (idx < 393216) { src = w_cross; off = idx - 327680; }
        else if (idx < 442368) { src = w_so;    off = idx - 393216; }
        else if (idx < 466944) { src = w_aw;    off = idx - 442368; }
        else if (idx < 729088) { src = w_f1;    off = idx - 466944; }
        else                   { src = w_f2;    off = idx - 729088; }
        float4 v = *(const float4*)(src + off);
        ushort4 o; o.x = f2b(v.x); o.y = f2b(v.y); o.z = f2b(v.z); o.w = f2b(v.w);
        *(ushort4*)(wdst + idx) = o;
    } else {
        int o = (bid - 17618) * 256 + tid;
        if (o >= 768 + 192 + 96) return;
        const float* wrow;
        if (o < 768)       wrow = w_in + (size_t)o * D_MODEL;
        else if (o < 960)  wrow = w_so + (size_t)(o - 768) * D_MODEL;
        else               wrow = w_aw + (size_t)(o - 960) * D_MODEL;
        float acc = 0.f;
        for (int d = 0; d < D_MODEL; ++d) acc += qp[d] * wrow[d];
        qpv[o] = acc;
        if (o >= 768) {
            float bias = (o < 960) ? so_b[o - 768] : aw_b[o - 960];
            qpv[1056 + (o - 768)] = acc + bias;
        }
    }
}

// ---------------------------------------------------------------------------
// bf16 MFMA GEMM (R4 proven version): 128x128 tile, BK=64 (2x32 panels),
// global_load_lds width=16 staging.
__global__ __launch_bounds__(256) void gemm_bf16(
    const unsigned short* __restrict__ A,
    const unsigned short* __restrict__ W,
    const float* __restrict__ bias,
    const float* __restrict__ bias2, int b2lim,
    float* __restrict__ Cf, unsigned short* __restrict__ Cb,
    int M, int N, int K, int relu)
{
    __shared__ __align__(16) unsigned short As[2 * 128 * 32];   // 16 KB
    __shared__ __align__(16) unsigned short Bs[2 * 128 * 32];   // 16 KB
    const int tid  = threadIdx.x;
    const int wave = tid >> 6;
    const int lane = tid & 63;
    const int m0 = blockIdx.x * 128;
    const int n0 = blockIdx.y * 128;

    const int lr  = lane >> 2;
    const int lc8 = (lane & 3) * 8;
    int ar0 = m0 + wave * 32 + lr;      if (ar0 > M - 1) ar0 = M - 1;
    int ar1 = m0 + wave * 32 + 16 + lr; if (ar1 > M - 1) ar1 = M - 1;
    int br0 = n0 + wave * 32 + lr;      if (br0 > N - 1) br0 = N - 1;
    int br1 = n0 + wave * 32 + 16 + lr; if (br1 > N - 1) br1 = N - 1;
    const unsigned short* pa0 = A + (size_t)ar0 * K + lc8;
    const unsigned short* pa1 = A + (size_t)ar1 * K + lc8;
    const unsigned short* pb0 = W + (size_t)br0 * K + lc8;
    const unsigned short* pb1 = W + (size_t)br1 * K + lc8;
    unsigned short* la0 = As + wave * 1024;
    unsigned short* la1 = As + wave * 1024 + 512;
    unsigned short* lb0 = Bs + wave * 1024;
    unsigned short* lb1 = Bs + wave * 1024 + 512;

    const int wm = (wave >> 1) * 64;
    const int wn = (wave & 1) * 64;
    const int fr = lane & 15;
    const int fk = (lane >> 4) * 8;

    f32x4 acc[4][4] = {};

    for (int k0 = 0; k0 < K; k0 += 64) {
        GLDS16(pa0, la0); GLDS16(pa0 + 32, la0 + 4096);
        GLDS16(pa1, la1); GLDS16(pa1 + 32, la1 + 4096);
        GLDS16(pb0, lb0); GLDS16(pb0 + 32, lb0 + 4096);
        GLDS16(pb1, lb1); GLDS16(pb1 + 32, lb1 + 4096);
        pa0 += 64; pa1 += 64; pb0 += 64; pb1 += 64;
        __syncthreads();
#pragma unroll
        for (int p = 0; p < 2; ++p) {
            bf16x8 af[4], bfv[4];
#pragma unroll
            for (int i = 0; i < 4; ++i)
                af[i] = *(const bf16x8*)&As[p * 4096 + (wm + i * 16 + fr) * 32 + fk];
#pragma unroll
            for (int j = 0; j < 4; ++j)
                bfv[j] = *(const bf16x8*)&Bs[p * 4096 + (wn + j * 16 + fr) * 32 + fk];
#pragma unroll
            for (int i = 0; i < 4; ++i)
#pragma unroll
                for (int j = 0; j < 4; ++j)
                    acc[i][j] = __builtin_amdgcn_mfma_f32_16x16x32_bf16(
                        af[i], bfv[j], acc[i][j], 0, 0, 0);
        }
        __syncthreads();
    }

    const int quad = lane >> 4;
#pragma unroll
    for (int j = 0; j < 4; ++j) {
        const int col = n0 + wn + j * 16 + fr;
        if (col >= N) continue;
        float bv = 0.f;
        if (bias) bv += bias[col];
        if (bias2 && col < b2lim) bv += bias2[col];
#pragma unroll
        for (int i = 0; i < 4; ++i) {
#pragma unroll
            for (int r = 0; r < 4; ++r) {
                const int row = m0 + wm + i * 16 + quad * 4 + r;
                if (row >= M) continue;
                float v = acc[i][j][r] + bv;
                if (relu) v = fmaxf(v, 0.f);
                if (Cf) Cf[(size_t)row * N + col] = v;
                if (Cb) Cb[(size_t)row * N + col] = f2b(v);
            }
        }
    }
}

// ---------------------------------------------------------------------------
// GEMM (N=256, full row per block) + residual + LayerNorm fused (R4 proven).
// Now used only for LN2 (out_proj + tgt residual).
__global__ __launch_bounds__(256) void gemm_ln(
    const unsigned short* __restrict__ A,    // M x K bf16
    const unsigned short* __restrict__ W,    // 256 x K bf16
    const float* __restrict__ bias,          // 256
    const float* __restrict__ resid,         // M x 256 fp32
    const float* __restrict__ g, const float* __restrict__ bb,
    float* __restrict__ outf, unsigned short* __restrict__ outb, int K)
{
    __shared__ __align__(16) unsigned short As[2 * 64 * 32];    // 8 KB
    __shared__ __align__(16) unsigned short Bs[2 * 256 * 32];   // 32 KB
    const int tid  = threadIdx.x;
    const int wave = tid >> 6;
    const int lane = tid & 63;
    const int m0 = blockIdx.x * 64;

    const int arow = tid >> 2;
    const int akc  = (tid & 3) * 8;
    const unsigned short* pa = A + (size_t)(m0 + arow) * K + akc;
    unsigned short* la = As + tid * 8;
    const unsigned short* pb0 = W + (size_t)(arow)       * K + akc;
    const unsigned short* pb1 = W + (size_t)(64  + arow) * K + akc;
    const unsigned short* pb2 = W + (size_t)(128 + arow) * K + akc;
    const unsigned short* pb3 = W + (size_t)(192 + arow) * K + akc;
    unsigned short* lb0 = Bs + tid * 8;
    unsigned short* lb1 = Bs + 2048 + tid * 8;
    unsigned short* lb2 = Bs + 4096 + tid * 8;
    unsigned short* lb3 = Bs + 6144 + tid * 8;

    const int fr = lane & 15;
    const int fk = (lane >> 4) * 8;
    const int quad = lane >> 4;
    const int colbase = wave * 64;

    f32x4 acc[4][4] = {};

    for (int k0 = 0; k0 < K; k0 += 64) {
        GLDS16(pa, la);        GLDS16(pa + 32, la + 2048);
        GLDS16(pb0, lb0);      GLDS16(pb0 + 32, lb0 + 8192);
        GLDS16(pb1, lb1);      GLDS16(pb1 + 32, lb1 + 8192);
        GLDS16(pb2, lb2);      GLDS16(pb2 + 32, lb2 + 8192);
        GLDS16(pb3, lb3);      GLDS16(pb3 + 32, lb3 + 8192);
        pa += 64; pb0 += 64; pb1 += 64; pb2 += 64; pb3 += 64;
        __syncthreads();
#pragma unroll
        for (int p = 0; p < 2; ++p) {
            bf16x8 af[4], bfv[4];
#pragma unroll
            for (int i = 0; i < 4; ++i)
                af[i] = *(const bf16x8*)&As[p * 2048 + (i * 16 + fr) * 32 + fk];
#pragma unroll
            for (int j = 0; j < 4; ++j)
                bfv[j] = *(const bf16x8*)&Bs[p * 8192 + (colbase + j * 16 + fr) * 32 + fk];
#pragma unroll
            for (int i = 0; i < 4; ++i)
#pragma unroll
                for (int j = 0; j < 4; ++j)
                    acc[i][j] = __builtin_amdgcn_mfma_f32_16x16x32_bf16(
                        af[i], bfv[j], acc[i][j], 0, 0, 0);
        }
        __syncthreads();
    }

    // ---- fused epilogue: v = acc + bias + resid; LN over 256 cols ----
    float2* red = (float2*)As;   // 256 entries, aliases As (post-barrier safe)
    float rs[4][4], rq[4][4];
#pragma unroll
    for (int i = 0; i < 4; ++i) {
#pragma unroll
        for (int r = 0; r < 4; ++r) {
            const int row = m0 + i * 16 + quad * 4 + r;
            float s = 0.f, q = 0.f;
#pragma unroll
            for (int j = 0; j < 4; ++j) {
                const int col = colbase + j * 16 + fr;
                float v = acc[i][j][r] + bias[col] + resid[(size_t)row * 256 + col];
                acc[i][j][r] = v;
                s += v; q += v * v;
            }
            rs[i][r] = s; rq[i][r] = q;
        }
    }
#pragma unroll
    for (int off = 1; off < 16; off <<= 1) {
#pragma unroll
        for (int i = 0; i < 4; ++i)
#pragma unroll
            for (int r = 0; r < 4; ++r) {
                rs[i][r] += __shfl_xor(rs[i][r], off);
                rq[i][r] += __shfl_xor(rq[i][r], off);
            }
    }
    if ((lane & 15) == 0) {
#pragma unroll
        for (int i = 0; i < 4; ++i)
#pragma unroll
            for (int r = 0; r < 4; ++r)
                red[wave * 64 + i * 16 + quad * 4 + r] = make_float2(rs[i][r], rq[i][r]);
    }
    __syncthreads();
#pragma unroll
    for (int i = 0; i < 4; ++i) {
#pragma unroll
        for (int r = 0; r < 4; ++r) {
            const int rl = i * 16 + quad * 4 + r;
            const float2 t0 = red[rl], t1 = red[64 + rl], t2 = red[128 + rl], t3 = red[192 + rl];
            const float sum = t0.x + t1.x + t2.x + t3.x;
            const float sq  = t0.y + t1.y + t2.y + t3.y;
            const float mean = sum * (1.f / 256.f);
            const float var  = sq * (1.f / 256.f) - mean * mean;
            const float inv  = rsqrtf(var + 1e-5f);
            const int row = m0 + rl;
#pragma unroll
            for (int j = 0; j < 4; ++j) {
                const int col = colbase + j * 16 + fr;
                const float val = (acc[i][j][r] - mean) * inv * g[col] + bb[col];
                outf[(size_t)row * 256 + col] = val;
                if (outb) outb[(size_t)row * 256 + col] = f2b(val);
            }
        }
    }
}

// ---------------------------------------------------------------------------
// MEGAFUSED v2 (R9 proven: 96.5 us, -15% vs v1): cross_out GEMM + LN1 +
// FFN + LN3, wave-private staging pipeline. Each wave reads ONLY the Wc
// quarter it staged itself -> Wc staging uses wave-local vmcnt/lgkm waits;
// barriers only at the cross-wave hazards (hid, A-stage, LN1 handoff).
// 2 barriers per h (was 4). Numerics identical to the two-kernel path.
__global__ __launch_bounds__(256) void cross_ffn_kernel(
    const unsigned short* __restrict__ A,     // msoutb M x 256 bf16
    const unsigned short* __restrict__ Wcr,   // 256 x 256 bf16 (cross_out)
    const float* __restrict__ bcr,            // cross_out_b
    const float* __restrict__ resid1,         // t (LN2 out) M x 256 fp32
    const float* __restrict__ g1, const float* __restrict__ b1g,
    float* __restrict__ t2,                   // scratch M x 256 fp32
    const unsigned short* __restrict__ W1,    // 1024 x 256 bf16
    const float* __restrict__ b1,             // 1024
    const unsigned short* __restrict__ W2,    // 256 x 1024 bf16
    const float* __restrict__ b2,             // 256
    const float* __restrict__ g3, const float* __restrict__ b3g,
    float* __restrict__ outf)
{
    __shared__ __align__(16) unsigned short Wc[16384];   // A-stage / W-chunks
    __shared__ __align__(16) unsigned short hid[2304];   // 32 x 72 (padded)
    const int tid  = threadIdx.x;
    const int wave = tid >> 6;
    const int lane = tid & 63;
    const int m0 = blockIdx.x * 32;
    const int fr   = lane & 15;
    const int quad = lane >> 4;
    const int xm   = fr & 7;           // XOR mask for swizzled fragment reads
    float2* red = (float2*)hid;        // 128 float2 = 1 KB (LN reductions)

    // ---- stage A=msout (32 rows) into Wc[0..8192), swizzled ----
#pragma unroll
    for (int j = 0; j < 4; ++j) {
        const int c  = wave * 4 + j;               // 0..15
        const int rA = c * 2 + (lane >> 5);        // row 0..31
        const int k8 = (lane & 31) ^ (rA & 7);
        GLDS16(A + (size_t)(m0 + rA) * 256 + k8 * 8, Wc + c * 512);
    }
    // ---- per-lane swizzled staging offsets for 64-row x 256-k chunks ----
    int w1off[8], w2off[8];
#pragma unroll
    for (int j = 0; j < 8; ++j) {
        const int c  = wave * 8 + j;               // 0..31
        const int n1 = c * 2 + (lane >> 5);        // chunk row 0..63
        const int k1 = (lane & 31) ^ (n1 & 7);
        w1off[j] = n1 * 256 + k1 * 8;              // + chunk*16384
        const int n2 = c * 8 + (lane >> 3);        // W2 row 0..255
        const int k2 = (lane & 7) ^ (n2 & 7);
        w2off[j] = n2 * 1024 + k2 * 8;             // + h*64
    }
    __syncthreads();                   // A visible (cross-wave af reads)
    bf16x8 af[2][8];
#pragma unroll
    for (int i = 0; i < 2; ++i)
#pragma unroll
        for (int s = 0; s < 8; ++s)
            af[i][s] = *(const bf16x8*)&Wc[((i * 16 + fr) * 32 + ((s * 4 + quad) ^ xm)) * 8];
    WAIT_LGKM0();
    __syncthreads();                   // all af reads done before Wcr stage

    // ================= PHASE 1: cross_out GEMM (4 chunks, 0 barriers) =====
    // Each wave stages+reads only its own Wc quarter -> wave-local waits.
#pragma unroll
    for (int j = 0; j < 8; ++j)
        GLDS16(Wcr + w1off[j], Wc + (wave * 8 + j) * 512);
    f32x4 accc[4][2] = {};
    for (int c = 0; c < 4; ++c) {
        WAIT_VM0();                    // Wcr[c] arrived (wave-local)
        bf16x8 bv[8];
#pragma unroll
        for (int s = 0; s < 8; ++s)
            bv[s] = *(const bf16x8*)&Wc[((wave * 16 + fr) * 32 + ((s * 4 + quad) ^ xm)) * 8];
        WAIT_LGKM0();                  // reads done before overwrite
        if (c < 3) {
#pragma unroll
            for (int j = 0; j < 8; ++j)
                GLDS16(Wcr + (size_t)(c + 1) * 16384 + w1off[j], Wc + (wave * 8 + j) * 512);
        }
#pragma unroll
        for (int s = 0; s < 8; ++s) {
            accc[c][0] = __builtin_amdgcn_mfma_f32_16x16x32_bf16(af[0][s], bv[s], accc[c][0], 0, 0, 0);
            accc[c][1] = __builtin_amdgcn_mfma_f32_16x16x32_bf16(af[1][s], bv[s], accc[c][1], 0, 0, 0);
        }
    }

    // ---- LN1: v = accc + bcr + resid1; normalize over 256 cols ----
    float rs[2][4], rq[2][4];
#pragma unroll
    for (int x = 0; x < 2; ++x) {
#pragma unroll
        for (int r = 0; r < 4; ++r) {
            const int row = m0 + x * 16 + quad * 4 + r;
            float s = 0.f, q = 0.f;
#pragma unroll
            for (int c = 0; c < 4; ++c) {
                const int col = c * 64 + wave * 16 + fr;
                float v = accc[c][x][r] + bcr[col] + resid1[(size_t)row * 256 + col];
                accc[c][x][r] = v;
                s += v; q += v * v;
            }
            rs[x][r] = s; rq[x][r] = q;
        }
    }
#pragma unroll
    for (int off = 1; off < 16; off <<= 1) {
#pragma unroll
        for (int x = 0; x < 2; ++x)
#pragma unroll
            for (int r = 0; r < 4; ++r) {
                rs[x][r] += __shfl_xor(rs[x][r], off);
                rq[x][r] += __shfl_xor(rq[x][r], off);
            }
    }
    if ((lane & 15) == 0) {
#pragma unroll
        for (int x = 0; x < 2; ++x)
#pragma unroll
            for (int r = 0; r < 4; ++r)
                red[wave * 32 + x * 16 + quad * 4 + r] = make_float2(rs[x][r], rq[x][r]);
    }
    __syncthreads();   // red visible; all waves' c=3 Wc reads done (handoff safe)
#pragma unroll
    for (int x = 0; x < 2; ++x) {
#pragma unroll
        for (int r = 0; r < 4; ++r) {
            const int rl = x * 16 + quad * 4 + r;
            const float2 t0 = red[rl], t1 = red[32 + rl], t2r = red[64 + rl], t3 = red[96 + rl];
            const float sum = t0.x + t1.x + t2r.x + t3.x;
            const float sq  = t0.y + t1.y + t2r.y + t3.y;
            const float mean = sum * (1.f / 256.f);
            const float var  = sq * (1.f / 256.f) - mean * mean;
            const float inv  = rsqrtf(var + 1e-5f);
            const int row = m0 + rl;
#pragma unroll
            for (int c = 0; c < 4; ++c) {
                const int col = c * 64 + wave * 16 + fr;
                const float val = (accc[c][x][r] - mean) * inv * g1[col] + b1g[col];
                t2[(size_t)row * 256 + col] = val;
                // bf16 handoff into A-stage layout (local row rl, col)
                const int g8 = col >> 3;
                Wc[rl * 256 + ((g8 ^ (rl & 7)) << 3) + (col & 7)] = f2b(val);
            }
        }
    }
    __syncthreads();   // handoff visible; red reads done
    // reload af = LN1 output fragments
#pragma unroll
    for (int i = 0; i < 2; ++i)
#pragma unroll
        for (int s = 0; s < 8; ++s)
            af[i][s] = *(const bf16x8*)&Wc[((i * 16 + fr) * 32 + ((s * 4 + quad) ^ xm)) * 8];
    WAIT_LGKM0();
    __syncthreads();   // all af reloads done before W1[0] stage overwrites

    // ================= PHASE 2: FFN, 2 barriers per h =================
#pragma unroll
    for (int j = 0; j < 8; ++j)
        GLDS16(W1 + w1off[j], Wc + (wave * 8 + j) * 512);
    WAIT_VM0();        // W1[0] arrived (first iter only: exposed)

    f32x4 acc2[2][4] = {};

    for (int h = 0; h < 16; ++h) {
        // ---- gemm1: bv from own W1 region -> regs; restage own region ----
        bf16x8 bv[8];
#pragma unroll
        for (int s = 0; s < 8; ++s)
            bv[s] = *(const bf16x8*)&Wc[((wave * 16 + fr) * 32 + ((s * 4 + quad) ^ xm)) * 8];
        WAIT_LGKM0();
#pragma unroll
        for (int j = 0; j < 8; ++j)
            GLDS16(W2 + (size_t)h * 64 + w2off[j], Wc + (wave * 8 + j) * 512);
        f32x4 acc1[2] = {};
#pragma unroll
        for (int s = 0; s < 8; ++s) {
            acc1[0] = __builtin_amdgcn_mfma_f32_16x16x32_bf16(af[0][s], bv[s], acc1[0], 0, 0, 0);
            acc1[1] = __builtin_amdgcn_mfma_f32_16x16x32_bf16(af[1][s], bv[s], acc1[1], 0, 0, 0);
        }
        const float bias1 = b1[h * 64 + wave * 16 + fr];
#pragma unroll
        for (int i = 0; i < 2; ++i)
#pragma unroll
            for (int r = 0; r < 4; ++r) {
                float v = fmaxf(acc1[i][r] + bias1, 0.f);
                hid[(i * 16 + quad * 4 + r) * 72 + wave * 16 + fr] = f2b(v);
            }
        __syncthreads();   // hid visible; W2[h] drained (covered by gemm1)
        // ---- gemm2: b2v from own W2 region + a2 from hid -> regs ----
#pragma unroll
        for (int s = 0; s < 2; ++s) {
            bf16x8 a2[2], b2v[4];
#pragma unroll
            for (int j2 = 0; j2 < 4; ++j2) {
                const int nb = wave * 64 + j2 * 16 + fr;
                b2v[j2] = *(const bf16x8*)&Wc[(nb * 8 + ((s * 4 + quad) ^ xm)) * 8];
            }
#pragma unroll
            for (int i = 0; i < 2; ++i)
                a2[i] = *(const bf16x8*)&hid[(i * 16 + fr) * 72 + s * 32 + quad * 8];
            if (s == 1) {
                WAIT_LGKM0();          // all Wc/hid reads done
                if (h < 15) {
#pragma unroll
                    for (int j = 0; j < 8; ++j)
                        GLDS16(W1 + (size_t)(h + 1) * 16384 + w1off[j], Wc + (wave * 8 + j) * 512);
                }
            }
#pragma unroll
            for (int i = 0; i < 2; ++i)
#pragma unroll
                for (int j2 = 0; j2 < 4; ++j2)
                    acc2[i][j2] = __builtin_amdgcn_mfma_f32_16x16x32_bf16(
                        a2[i], b2v[j2], acc2[i][j2], 0, 0, 0);
        }
        __syncthreads();   // hid free for next h; W1[h+1] drained (covered)
    }

    // ---- epilogue: v = acc2 + b2 + t2(resid, self-written); LN3 ----
    const int colbase = wave * 64;
#pragma unroll
    for (int x = 0; x < 2; ++x) {
#pragma unroll
        for (int r = 0; r < 4; ++r) {
            const int row = m0 + x * 16 + quad * 4 + r;
            float s = 0.f, q = 0.f;
#pragma unroll
            for (int y = 0; y < 4; ++y) {
                const int col = colbase + y * 16 + fr;
                float v = acc2[x][y][r] + b2[col] + t2[(size_t)row * 256 + col];
                acc2[x][y][r] = v;
                s += v; q += v * v;
            }
            rs[x][r] = s; rq[x][r] = q;
        }
    }
#pragma unroll
    for (int off = 1; off < 16; off <<= 1) {
#pragma unroll
        for (int x = 0; x < 2; ++x)
#pragma unroll
            for (int r = 0; r < 4; ++r) {
                rs[x][r] += __shfl_xor(rs[x][r], off);
                rq[x][r] += __shfl_xor(rq[x][r], off);
            }
    }
    if ((lane & 15) == 0) {
#pragma unroll
        for (int x = 0; x < 2; ++x)
#pragma unroll
            for (int r = 0; r < 4; ++r)
                red[wave * 32 + x * 16 + quad * 4 + r] = make_float2(rs[x][r], rq[x][r]);
    }
    __syncthreads();
#pragma unroll
    for (int x = 0; x < 2; ++x) {
#pragma unroll
        for (int r = 0; r < 4; ++r) {
            const int rl = x * 16 + quad * 4 + r;
            const float2 t0 = red[rl], t1 = red[32 + rl], t2r = red[64 + rl], t3 = red[96 + rl];
            const float sum = t0.x + t1.x + t2r.x + t3.x;
            const float sq  = t0.y + t1.y + t2r.y + t3.y;
            const float mean = sum * (1.f / 256.f);
            const float var  = sq * (1.f / 256.f) - mean * mean;
            const float inv  = rsqrtf(var + 1e-5f);
            const int row = m0 + rl;
#pragma unroll
            for (int y = 0; y < 4; ++y) {
                const int col = colbase + y * 16 + fr;
                outf[(size_t)row * 256 + col] = (acc2[x][y][r] - mean) * inv * g3[col] + b3g[col];
            }
        }
    }
}

// ---------------------------------------------------------------------------
// Self-attention over S=8 (batch axis). Row order (lq,b): row = n*8 + s.
// v2: VECTORIZED global I/O (Common-mistake #2 fix). Old version did 24
// scalar ushort loads + 8 scalar stores per thread (2 B/lane = 1/8 coalesced
// width). Now: QKV slab (8x768 shorts) loaded as 3x bf16x8 per thread
// (16 B/lane); PV output staged in 4 KB LDS then stored as 1x bf16x8 per
// thread. Compute phases and rounding points unchanged.
__global__ __launch_bounds__(256) void self_attn_kernel(
    const unsigned short* __restrict__ qkv, unsigned short* __restrict__ ctx)
{
    __shared__ float sh[8][768];                    // 24 KB
    __shared__ float ls[8][8][8];                   // [h][s][t], 2 KB
    __shared__ __align__(16) unsigned short ob[2048];  // 8 rows x 256, 4 KB
    const int n = blockIdx.x;
    const int t = threadIdx.x;

    // ---- vector load: 8 rows x 768 shorts = 6144 shorts; 24/thread ----
    const unsigned short* base = qkv + (size_t)n * 8 * 768;
#pragma unroll
    for (int i = 0; i < 3; ++i) {
        const int idx = (i * 256 + t) * 8;          // 16B-aligned short index
        bf16x8 v = *(const bf16x8*)&base[idx];
        const int s = idx / 768;                    // row 0..7 (768 % 8 == 0)
        const int c = idx - s * 768;
#pragma unroll
        for (int j = 0; j < 8; ++j)
            sh[s][c + j] = b2f((unsigned short)v[j]);
    }
    __syncthreads();
    const int h = t >> 5, j = t & 31;
#pragma unroll
    for (int pair = j; pair < 64; pair += 32) {
        const int s = pair >> 3, tt = pair & 7;
        float acc = 0.f;
#pragma unroll
        for (int d = 0; d < 32; ++d)
            acc += sh[s][h * 32 + d] * sh[tt][256 + h * 32 + d];
        ls[h][s][tt] = acc * 0.17677669529663687f;
    }
    __syncthreads();
    if (t < 64) {
        const int hh = t >> 3, s = t & 7;
        float mx = -1e30f;
        for (int tt = 0; tt < 8; ++tt) mx = fmaxf(mx, ls[hh][s][tt]);
        float sum = 0.f;
        for (int tt = 0; tt < 8; ++tt) { float e = expf(ls[hh][s][tt] - mx); ls[hh][s][tt] = e; sum += e; }
        const float inv = 1.f / sum;
        for (int tt = 0; tt < 8; ++tt) ls[hh][s][tt] *= inv;
    }
    __syncthreads();
    // ---- PV -> LDS staging (channel = h*32+j = t) ----
#pragma unroll
    for (int s = 0; s < 8; ++s) {
        float acc = 0.f;
#pragma unroll
        for (int tt = 0; tt < 8; ++tt)
            acc += ls[h][s][tt] * sh[tt][512 + h * 32 + j];
        ob[s * 256 + t] = f2b(acc);
    }
    __syncthreads();
    // ---- vector store: 2048 shorts = 256 threads x bf16x8 ----
    ((bf16x8*)ctx)[(size_t)n * 256 + t] = ((const bf16x8*)ob)[t];
}

// ---------------------------------------------------------------------------
// Merged msprep + deformable sampling (R6 proven).
__global__ __launch_bounds__(256) void msdeform_kernel(
    const unsigned short* __restrict__ value,
    const float* __restrict__ comb,
    unsigned short* __restrict__ out)
{
    const int bid = blockIdx.x;
    const int b   = bid & 7;
    const int lq0 = (bid >> 3) * 4;
    const int r    = threadIdx.x >> 6;
    const int lane = threadIdx.x & 63;
    const int h = lane >> 3;
    const int l = lane & 7;
    const int lq = lq0 + r;
    const int m = lq * 8 + b;

    // ---- load raw offsets + attention logits for (m,h) ----
    const float* offp = comb + (size_t)m * 288 + h * 24;
    const float* awp  = comb + (size_t)m * 288 + 192 + h * 12;
    float off[24], aw[12];
#pragma unroll
    for (int i = 0; i < 6; ++i) *(float4*)&off[i * 4] = ((const float4*)offp)[i];
#pragma unroll
    for (int i = 0; i < 3; ++i) *(float4*)&aw[i * 4] = ((const float4*)awp)[i];

    float mx = aw[0];
#pragma unroll
    for (int i = 1; i < 12; ++i) mx = fmaxf(mx, aw[i]);
    float se = 0.f;
#pragma unroll
    for (int i = 0; i < 12; ++i) { aw[i] = __expf(aw[i] - mx); se += aw[i]; }
    const float inv = 1.f / se;

    const float refx = ((lq % 60) + 0.5f) * (1.f / 60.f);
    const float refy = ((lq / 60) + 0.5f) * (1.f / 60.f);
    const int HW[3] = {60, 30, 15};
    const int ST[3] = {0, 3600, 4500};

    const unsigned short* vbase = value + (size_t)b * LIN * 256 + h * 32 + l * 4;

    float a0 = 0.f, a1 = 0.f, a2 = 0.f, a3 = 0.f;
#pragma unroll
    for (int lev = 0; lev < NLEV; ++lev) {
        const int Wl = HW[lev], s0 = ST[lev];
        const float fWl = (float)Wl;
#pragma unroll
        for (int p = 0; p < NPNT; ++p) {
            const int pt = lev * 4 + p;
            const float ox = off[lev * 8 + p * 2];
            const float oy = off[lev * 8 + p * 2 + 1];
            const float px = refx * fWl + ox - 0.5f;
            const float py = refy * fWl + oy - 0.5f;
            const float x0f = floorf(px), y0f = floorf(py);
            const float fx = px - x0f, fy = py - y0f;
            const int x0 = (int)x0f, y0 = (int)y0f;
            const float aww = aw[pt] * inv;
            const float vx0 = (x0 >= 0 && x0 < Wl) ? 1.f : 0.f;
            const float vx1 = (x0 >= -1 && x0 < Wl - 1) ? 1.f : 0.f;
            const float vy0 = (y0 >= 0 && y0 < Wl) ? 1.f : 0.f;
            const float vy1 = (y0 >= -1 && y0 < Wl - 1) ? 1.f : 0.f;
            const int xc0 = min(max(x0, 0), Wl - 1);
            const int xc1 = min(max(x0 + 1, 0), Wl - 1);
            const int yc0 = min(max(y0, 0), Wl - 1);
            const int yc1 = min(max(y0 + 1, 0), Wl - 1);
            const int sx  = xc1 - xc0;
            const int syW = (yc1 - yc0) * Wl;
            const int i00 = s0 + yc0 * Wl + xc0;
            const float w00 = (1.f - fx) * (1.f - fy) * aww * vx0 * vy0;
            const float w01 = fx * (1.f - fy) * aww * vx1 * vy0;
            const float w10 = (1.f - fx) * fy * aww * vx0 * vy1;
            const float w11 = fx * fy * aww * vx1 * vy1;
            const int i01 = i00 + sx;
            const int i10 = i00 + syW;
            const int i11 = i10 + sx;
            const ushort4 g00 = *(const ushort4*)(vbase + (size_t)i00 * 256);
            const ushort4 g01 = *(const ushort4*)(vbase + (size_t)i01 * 256);
            const ushort4 g10 = *(const ushort4*)(vbase + (size_t)i10 * 256);
            const ushort4 g11 = *(const ushort4*)(vbase + (size_t)i11 * 256);
            a0 += b2f(g00.x) * w00 + b2f(g01.x) * w01 + b2f(g10.x) * w10 + b2f(g11.x) * w11;
            a1 += b2f(g00.y) * w00 + b2f(g01.y) * w01 + b2f(g10.y) * w10 + b2f(g11.y) * w11;
            a2 += b2f(g00.z) * w00 + b2f(g01.z) * w01 + b2f(g10.z) * w10 + b2f(g11.z) * w11;
            a3 += b2f(g00.w) * w00 + b2f(g01.w) * w01 + b2f(g10.w) * w10 + b2f(g11.w) * w11;
        }
    }
    ushort4 o;
    o.x = f2b(a0); o.y = f2b(a1); o.z = f2b(a2); o.w = f2b(a3);
    *(ushort4*)(out + (size_t)m * 256 + h * 32 + l * 4) = o;
}

// ---------------------------------------------------------------------------
extern "C" void kernel_launch(void* const* d_in, const int* in_sizes, int n_in,
                              void* d_out, int out_size, void* d_ws, size_t ws_size,
                              hipStream_t stream)
{
    (void)in_sizes; (void)n_in; (void)out_size; (void)ws_size;
    const float* tgt          = (const float*)d_in[0];   // (LQ,B,D): (lq,b)-major rows
    const float* qp           = (const float*)d_in[1];
    const float* src          = (const float*)d_in[2];
    const float* in_proj_w    = (const float*)d_in[5];
    const float* in_proj_b    = (const float*)d_in[6];
    const float* out_proj_w   = (const float*)d_in[7];
    const float* out_proj_b   = (const float*)d_in[8];
    const float* samp_off_w   = (const float*)d_in[9];
    const float* samp_off_b   = (const float*)d_in[10];
    const float* attn_w_w     = (const float*)d_in[11];
    const float* attn_w_b     = (const float*)d_in[12];
    const float* value_proj_w = (const float*)d_in[13];
    const float* value_proj_b = (const float*)d_in[14];
    const float* cross_out_w  = (const float*)d_in[15];
    const float* cross_out_b  = (const float*)d_in[16];
    const float* ln1_g = (const float*)d_in[17];
    const float* ln1_b = (const float*)d_in[18];
    const float* ln2_g = (const float*)d_in[19];
    const float* ln2_b = (const float*)d_in[20];
    const float* ln3_g = (const float*)d_in[21];
    const float* ln3_b = (const float*)d_in[22];
    const float* ffn_w1 = (const float*)d_in[23];
    const float* ffn_b1 = (const float*)d_in[24];
    const float* ffn_w2 = (const float*)d_in[25];
    const float* ffn_b2 = (const float*)d_in[26];
    float* out = (float*)d_out;

    // ---- fp32 arena (floats) ----
    float* ws    = (float*)d_ws;
    float* t     = ws;                    // LN2 out (residual for LN1)
    float* t2    = ws + 7372800;          // LN1 out scratch (cross_ffn self RW)
    float* comb  = ws + 14745600;         // 28800x288 off+aw (raw, fp32)
    float* qpv   = ws + 23040000;         // 1056 qp-proj + 288 cbias
    float* cbias = qpv + 1056;

    // ---- bf16 arena (ushort), after fp32 arena (byte 92,165,376) ----
    unsigned short* bws    = (unsigned short*)((char*)d_ws + 92165376);
    unsigned short* s1     = bws;                  // tgtb -> ctxb -> tb
    unsigned short* tgtb   = s1;
    unsigned short* ctxb   = s1;
    unsigned short* tb     = s1;
    unsigned short* s2     = bws + 7372800;        // qkvb / valueb+msoutb
    unsigned short* qkvb   = s2;
    unsigned short* valueb = s2;
    unsigned short* msoutb = s2 + 9676800;
    unsigned short* srcb   = bws + 36864000;
    unsigned short* wtsb   = bws + 46540800;       // 991,232 shorts

    // 1. merged prep (conversions + weight cast + query_pos projections)
    prep_kernel<<<17623, 256, 0, stream>>>(tgt, tgtb, src, srcb,
                                           in_proj_w, out_proj_w, value_proj_w,
                                           cross_out_w, samp_off_w, attn_w_w,
                                           ffn_w1, ffn_w2, wtsb,
                                           qp, samp_off_b, attn_w_b, qpv);
    // 2. QKV projection (Q,K cols get query_pos bias via qpv, cols < 512)
    gemm_bf16<<<dim3(225, 6), 256, 0, stream>>>(tgtb, wtsb + 0, in_proj_b, qpv, 512,
                                                nullptr, qkvb, MROWS, 768, 256, 0);
    // 3. self-attention over batch axis (vectorized I/O)
    self_attn_kernel<<<3600, 256, 0, stream>>>(qkvb, ctxb);
    // 4. t = LN2(tgt + out_proj(ctx))   [fused; in-place ctxb->tb safe]
    gemm_ln<<<450, 256, 0, stream>>>(ctxb, wtsb + 196608, out_proj_b, tgt,
                                     ln2_g, ln2_b, t, tb, 256);
    // 5. value projection (M = 37800)
    gemm_bf16<<<dim3(296, 2), 256, 0, stream>>>(srcb, wtsb + 262144, value_proj_b, nullptr, 0,
                                                nullptr, valueb, BATCH * LIN, 256, 256, 0);
    // 6. fused sampling-offset + attn-weight projection (N = 288)
    gemm_bf16<<<dim3(225, 3), 256, 0, stream>>>(tb, wtsb + 393216, cbias, nullptr, 0,
                                                comb, nullptr, MROWS, 288, 256, 0);
    // 7. deformable sampling with inline softmax/bilinear setup
    msdeform_kernel<<<7200, 256, 0, stream>>>(valueb, comb, msoutb);
    // 8. out = LN3(t2 + FFN(t2)), t2 = LN1(t + cross_out(msout))  [megafused]
    cross_ffn_kernel<<<900, 256, 0, stream>>>(msoutb, wtsb + 327680, cross_out_b,
                                              t, ln1_g, ln1_b, t2,
                                              wtsb + 466944, ffn_b1,
                                              wtsb + 729088, ffn_b2,
                                              ln3_g, ln3_b, out);
}

// Round 11
// 444.527 us; speedup vs baseline: 1.0326x; 1.0024x over previous
//
#include <hip/hip_runtime.h>
#include <hip/hip_bf16.h>
#include <cstddef>
#include <cstdint>

// Problem constants
#define D_MODEL 256
#define NHEAD   8
#define HDIM    32
#define NLEV    3
#define NPNT    4
#define DFF     1024
#define BATCH   8
#define LQ      3600
#define LIN     4725   // 60*60 + 30*30 + 15*15
#define MROWS   (BATCH*LQ)   // 28800; row order is (lq,b): m = lq*8 + b

typedef short bf16x8 __attribute__((ext_vector_type(8)));
typedef float f32x4  __attribute__((ext_vector_type(4)));

__device__ __forceinline__ unsigned short f2b(float x) {
    unsigned int u = __float_as_uint(x);
    unsigned int r = (u + 0x7fffu + ((u >> 16) & 1u)) >> 16;   // RNE
    return (unsigned short)r;
}
__device__ __forceinline__ float b2f(unsigned short s) {
    return __uint_as_float(((unsigned int)s) << 16);
}

#define GLDS16(g, l) __builtin_amdgcn_global_load_lds( \
    (const __attribute__((address_space(1))) void*)(g), \
    (__attribute__((address_space(3))) void*)(l), 16, 0, 0)

#define WAIT_VM0()  asm volatile("s_waitcnt vmcnt(0)" ::: "memory")
#define WAIT_LGKM0() asm volatile("s_waitcnt lgkmcnt(0)" ::: "memory")

// ---------------------------------------------------------------------------
// Merged prep: [0,7200) conv tgt->bf16; [7200,16650) conv src->bf16;
// [16650,17618) weight convert; [17618,17623) query_pos projections.
#define WTOT 991232
__global__ __launch_bounds__(256) void prep_kernel(
    const float* __restrict__ tgt, unsigned short* __restrict__ tgtb,
    const float* __restrict__ srcf, unsigned short* __restrict__ srcb,
    const float* __restrict__ w_in, const float* __restrict__ w_out,
    const float* __restrict__ w_val, const float* __restrict__ w_cross,
    const float* __restrict__ w_so, const float* __restrict__ w_aw,
    const float* __restrict__ w_f1, const float* __restrict__ w_f2,
    unsigned short* __restrict__ wdst,
    const float* __restrict__ qp, const float* __restrict__ so_b,
    const float* __restrict__ aw_b, float* __restrict__ qpv)
{
    const int bid = blockIdx.x;
    const int tid = threadIdx.x;
    if (bid < 7200) {
        int i = bid * 256 + tid;
        float4 v = ((const float4*)tgt)[i];
        ushort4 o; o.x = f2b(v.x); o.y = f2b(v.y); o.z = f2b(v.z); o.w = f2b(v.w);
        ((ushort4*)tgtb)[i] = o;
    } else if (bid < 16650) {
        int i = (bid - 7200) * 256 + tid;
        float4 v = ((const float4*)srcf)[i];
        ushort4 o; o.x = f2b(v.x); o.y = f2b(v.y); o.z = f2b(v.z); o.w = f2b(v.w);
        ((ushort4*)srcb)[i] = o;
    } else if (bid < 17618) {
        int idx = ((bid - 16650) * 256 + tid) * 4;
        if (idx >= WTOT) return;
        const float* src; int off;
        if      (idx < 196608) { src = w_in;    off = idx; }
        else if (idx < 262144) { src = w_out;   off = idx - 196608; }
        else if (idx < 327680) { src = w_val;   off = idx - 262144; }
        else if (idx < 393216) { src = w_cross; off = idx - 327680; }
        else if (idx < 442368) { src = w_so;    off = idx - 393216; }
        else if (idx < 466944) { src = w_aw;    off = idx - 442368; }
        else if (idx < 729088) { src = w_f1;    off = idx - 466944; }
        else                   { src = w_f2;    off = idx - 729088; }
        float4 v = *(const float4*)(src + off);
        ushort4 o; o.x = f2b(v.x); o.y = f2b(v.y); o.z = f2b(v.z); o.w = f2b(v.w);
        *(ushort4*)(wdst + idx) = o;
    } else {
        int o = (bid - 17618) * 256 + tid;
        if (o >= 768 + 192 + 96) return;
        const float* wrow;
        if (o < 768)       wrow = w_in + (size_t)o * D_MODEL;
        else if (o < 960)  wrow = w_so + (size_t)(o - 768) * D_MODEL;
        else               wrow = w_aw + (size_t)(o - 960) * D_MODEL;
        float acc = 0.f;
        for (int d = 0; d < D_MODEL; ++d) acc += qp[d] * wrow[d];
        qpv[o] = acc;
        if (o >= 768) {
            float bias = (o < 960) ? so_b[o - 768] : aw_b[o - 960];
            qpv[1056 + (o - 768)] = acc + bias;
        }
    }
}

// ---------------------------------------------------------------------------
// bf16 MFMA GEMM (R4 proven version): 128x128 tile, BK=64 (2x32 panels),
// global_load_lds width=16 staging.
__global__ __launch_bounds__(256) void gemm_bf16(
    const unsigned short* __restrict__ A,
    const unsigned short* __restrict__ W,
    const float* __restrict__ bias,
    const float* __restrict__ bias2, int b2lim,
    float* __restrict__ Cf, unsigned short* __restrict__ Cb,
    int M, int N, int K, int relu)
{
    __shared__ __align__(16) unsigned short As[2 * 128 * 32];   // 16 KB
    __shared__ __align__(16) unsigned short Bs[2 * 128 * 32];   // 16 KB
    const int tid  = threadIdx.x;
    const int wave = tid >> 6;
    const int lane = tid & 63;
    const int m0 = blockIdx.x * 128;
    const int n0 = blockIdx.y * 128;

    const int lr  = lane >> 2;
    const int lc8 = (lane & 3) * 8;
    int ar0 = m0 + wave * 32 + lr;      if (ar0 > M - 1) ar0 = M - 1;
    int ar1 = m0 + wave * 32 + 16 + lr; if (ar1 > M - 1) ar1 = M - 1;
    int br0 = n0 + wave * 32 + lr;      if (br0 > N - 1) br0 = N - 1;
    int br1 = n0 + wave * 32 + 16 + lr; if (br1 > N - 1) br1 = N - 1;
    const unsigned short* pa0 = A + (size_t)ar0 * K + lc8;
    const unsigned short* pa1 = A + (size_t)ar1 * K + lc8;
    const unsigned short* pb0 = W + (size_t)br0 * K + lc8;
    const unsigned short* pb1 = W + (size_t)br1 * K + lc8;
    unsigned short* la0 = As + wave * 1024;
    unsigned short* la1 = As + wave * 1024 + 512;
    unsigned short* lb0 = Bs + wave * 1024;
    unsigned short* lb1 = Bs + wave * 1024 + 512;

    const int wm = (wave >> 1) * 64;
    const int wn = (wave & 1) * 64;
    const int fr = lane & 15;
    const int fk = (lane >> 4) * 8;

    f32x4 acc[4][4] = {};

    for (int k0 = 0; k0 < K; k0 += 64) {
        GLDS16(pa0, la0); GLDS16(pa0 + 32, la0 + 4096);
        GLDS16(pa1, la1); GLDS16(pa1 + 32, la1 + 4096);
        GLDS16(pb0, lb0); GLDS16(pb0 + 32, lb0 + 4096);
        GLDS16(pb1, lb1); GLDS16(pb1 + 32, lb1 + 4096);
        pa0 += 64; pa1 += 64; pb0 += 64; pb1 += 64;
        __syncthreads();
#pragma unroll
        for (int p = 0; p < 2; ++p) {
            bf16x8 af[4], bfv[4];
#pragma unroll
            for (int i = 0; i < 4; ++i)
                af[i] = *(const bf16x8*)&As[p * 4096 + (wm + i * 16 + fr) * 32 + fk];
#pragma unroll
            for (int j = 0; j < 4; ++j)
                bfv[j] = *(const bf16x8*)&Bs[p * 4096 + (wn + j * 16 + fr) * 32 + fk];
#pragma unroll
            for (int i = 0; i < 4; ++i)
#pragma unroll
                for (int j = 0; j < 4; ++j)
                    acc[i][j] = __builtin_amdgcn_mfma_f32_16x16x32_bf16(
                        af[i], bfv[j], acc[i][j], 0, 0, 0);
        }
        __syncthreads();
    }

    const int quad = lane >> 4;
#pragma unroll
    for (int j = 0; j < 4; ++j) {
        const int col = n0 + wn + j * 16 + fr;
        if (col >= N) continue;
        float bv = 0.f;
        if (bias) bv += bias[col];
        if (bias2 && col < b2lim) bv += bias2[col];
#pragma unroll
        for (int i = 0; i < 4; ++i) {
#pragma unroll
            for (int r = 0; r < 4; ++r) {
                const int row = m0 + wm + i * 16 + quad * 4 + r;
                if (row >= M) continue;
                float v = acc[i][j][r] + bv;
                if (relu) v = fmaxf(v, 0.f);
                if (Cf) Cf[(size_t)row * N + col] = v;
                if (Cb) Cb[(size_t)row * N + col] = f2b(v);
            }
        }
    }
}

// ---------------------------------------------------------------------------
// MEGAFUSED LN2+OFFS: out_proj GEMM + LN2 + sampling-offset/attn-weight
// projection, one kernel, 32 rows/block (900 blocks). Reuses the R9-proven
// cross_ffn wave-private machinery: each wave stages and reads ONLY its own
// Wc quarter -> zero barriers inside both GEMM loops.
// Phase 1: ctx = A @ Wo^T (4 chunks, K asc = gemm_ln's order) + bo + tgt
//   resid + LN2 -> t fp32 (global) + bf16 handoff in Wc A-stage layout.
// Phase 2: comb = LN2out @ Wso^T + cbias, N=288 = 5 chunks of 64 (last
//   chunk: source rows clamped to 287; garbage cols >=288 never written).
// Eliminates: gemm_ln launch + tb round-trip (29.4 MB) + the old offs
// gemm's 75%-idle third column-block. Numerics bit-identical.
__global__ __launch_bounds__(256) void ln2_offs_kernel(
    const unsigned short* __restrict__ A,     // ctxb M x 256 bf16
    const unsigned short* __restrict__ Wo,    // 256 x 256 bf16 (out_proj)
    const float* __restrict__ bo,             // out_proj_b
    const float* __restrict__ resid,          // tgt M x 256 fp32
    const float* __restrict__ g2, const float* __restrict__ b2g,
    float* __restrict__ tout,                 // t M x 256 fp32
    const unsigned short* __restrict__ Wso,   // 288 x 256 bf16 (so+aw)
    const float* __restrict__ cbias,          // 288
    float* __restrict__ comb)                 // M x 288 fp32
{
    __shared__ __align__(16) unsigned short Wc[16384];   // A-stage / W-chunks
    __shared__ float2 red[128];                          // LN reduction, 1 KB
    const int tid  = threadIdx.x;
    const int wave = tid >> 6;
    const int lane = tid & 63;
    const int m0 = blockIdx.x * 32;
    const int fr   = lane & 15;
    const int quad = lane >> 4;
    const int xm   = fr & 7;

    // ---- stage A=ctx (32 rows) into Wc[0..8192), swizzled ----
#pragma unroll
    for (int j = 0; j < 4; ++j) {
        const int c  = wave * 4 + j;
        const int rA = c * 2 + (lane >> 5);
        const int k8 = (lane & 31) ^ (rA & 7);
        GLDS16(A + (size_t)(m0 + rA) * 256 + k8 * 8, Wc + c * 512);
    }
    // ---- per-lane swizzled staging offsets (64-row x 256-k chunks) ----
    int w1off[8], w4off[8];
#pragma unroll
    for (int j = 0; j < 8; ++j) {
        const int c  = wave * 8 + j;
        const int n1 = c * 2 + (lane >> 5);        // chunk row 0..63
        const int k1 = (lane & 31) ^ (n1 & 7);
        w1off[j] = n1 * 256 + k1 * 8;
        const int n4 = (n1 < 32) ? n1 : 31;        // clamped for Wso chunk 4
        const int k4 = (lane & 31) ^ (n4 & 7);
        w4off[j] = n4 * 256 + k4 * 8;
    }
    __syncthreads();                   // A visible (cross-wave af reads)
    bf16x8 af[2][8];
#pragma unroll
    for (int i = 0; i < 2; ++i)
#pragma unroll
        for (int s = 0; s < 8; ++s)
            af[i][s] = *(const bf16x8*)&Wc[((i * 16 + fr) * 32 + ((s * 4 + quad) ^ xm)) * 8];
    WAIT_LGKM0();
    __syncthreads();                   // all af reads done before Wo stage

    // ================= PHASE 1: out_proj GEMM (4 chunks, 0 barriers) ======
#pragma unroll
    for (int j = 0; j < 8; ++j)
        GLDS16(Wo + w1off[j], Wc + (wave * 8 + j) * 512);
    f32x4 accc[4][2] = {};
    for (int c = 0; c < 4; ++c) {
        WAIT_VM0();
        bf16x8 bv[8];
#pragma unroll
        for (int s = 0; s < 8; ++s)
            bv[s] = *(const bf16x8*)&Wc[((wave * 16 + fr) * 32 + ((s * 4 + quad) ^ xm)) * 8];
        WAIT_LGKM0();
        if (c < 3) {
#pragma unroll
            for (int j = 0; j < 8; ++j)
                GLDS16(Wo + (size_t)(c + 1) * 16384 + w1off[j], Wc + (wave * 8 + j) * 512);
        }
#pragma unroll
        for (int s = 0; s < 8; ++s) {
            accc[c][0] = __builtin_amdgcn_mfma_f32_16x16x32_bf16(af[0][s], bv[s], accc[c][0], 0, 0, 0);
            accc[c][1] = __builtin_amdgcn_mfma_f32_16x16x32_bf16(af[1][s], bv[s], accc[c][1], 0, 0, 0);
        }
    }

    // ---- LN2: v = accc + bo + resid; normalize over 256 cols ----
    float rs[2][4], rq[2][4];
#pragma unroll
    for (int x = 0; x < 2; ++x) {
#pragma unroll
        for (int r = 0; r < 4; ++r) {
            const int row = m0 + x * 16 + quad * 4 + r;
            float s = 0.f, q = 0.f;
#pragma unroll
            for (int c = 0; c < 4; ++c) {
                const int col = c * 64 + wave * 16 + fr;
                float v = accc[c][x][r] + bo[col] + resid[(size_t)row * 256 + col];
                accc[c][x][r] = v;
                s += v; q += v * v;
            }
            rs[x][r] = s; rq[x][r] = q;
        }
    }
#pragma unroll
    for (int off = 1; off < 16; off <<= 1) {
#pragma unroll
        for (int x = 0; x < 2; ++x)
#pragma unroll
            for (int r = 0; r < 4; ++r) {
                rs[x][r] += __shfl_xor(rs[x][r], off);
                rq[x][r] += __shfl_xor(rq[x][r], off);
            }
    }
    if ((lane & 15) == 0) {
#pragma unroll
        for (int x = 0; x < 2; ++x)
#pragma unroll
            for (int r = 0; r < 4; ++r)
                red[wave * 32 + x * 16 + quad * 4 + r] = make_float2(rs[x][r], rq[x][r]);
    }
    __syncthreads();   // red visible; all waves' c=3 Wc reads done
#pragma unroll
    for (int x = 0; x < 2; ++x) {
#pragma unroll
        for (int r = 0; r < 4; ++r) {
            const int rl = x * 16 + quad * 4 + r;
            const float2 t0 = red[rl], t1 = red[32 + rl], t2r = red[64 + rl], t3 = red[96 + rl];
            const float sum = t0.x + t1.x + t2r.x + t3.x;
            const float sq  = t0.y + t1.y + t2r.y + t3.y;
            const float mean = sum * (1.f / 256.f);
            const float var  = sq * (1.f / 256.f) - mean * mean;
            const float inv  = rsqrtf(var + 1e-5f);
            const int row = m0 + rl;
#pragma unroll
            for (int c = 0; c < 4; ++c) {
                const int col = c * 64 + wave * 16 + fr;
                const float val = (accc[c][x][r] - mean) * inv * g2[col] + b2g[col];
                tout[(size_t)row * 256 + col] = val;
                const int g8 = col >> 3;
                Wc[rl * 256 + ((g8 ^ (rl & 7)) << 3) + (col & 7)] = f2b(val);
            }
        }
    }
    __syncthreads();   // handoff visible; red reads done
    // reload af = LN2 output fragments
#pragma unroll
    for (int i = 0; i < 2; ++i)
#pragma unroll
        for (int s = 0; s < 8; ++s)
            af[i][s] = *(const bf16x8*)&Wc[((i * 16 + fr) * 32 + ((s * 4 + quad) ^ xm)) * 8];
    WAIT_LGKM0();
    __syncthreads();   // all af reloads done before Wso[0] stage overwrites

    // ================= PHASE 2: offs GEMM (5 chunks, 0 barriers) ==========
#pragma unroll
    for (int j = 0; j < 8; ++j)
        GLDS16(Wso + w1off[j], Wc + (wave * 8 + j) * 512);
    f32x4 accP[5][2] = {};
    for (int c = 0; c < 5; ++c) {
        WAIT_VM0();
        bf16x8 bv[8];
#pragma unroll
        for (int s = 0; s < 8; ++s)
            bv[s] = *(const bf16x8*)&Wc[((wave * 16 + fr) * 32 + ((s * 4 + quad) ^ xm)) * 8];
        WAIT_LGKM0();
        if (c < 4) {
            if (c < 3) {
#pragma unroll
                for (int j = 0; j < 8; ++j)
                    GLDS16(Wso + (size_t)(c + 1) * 16384 + w1off[j], Wc + (wave * 8 + j) * 512);
            } else {
                // chunk 4: rows 256..287 valid; clamped sources for 288+
#pragma unroll
                for (int j = 0; j < 8; ++j)
                    GLDS16(Wso + (size_t)4 * 16384 + w4off[j], Wc + (wave * 8 + j) * 512);
            }
        }
#pragma unroll
        for (int s = 0; s < 8; ++s) {
            accP[c][0] = __builtin_amdgcn_mfma_f32_16x16x32_bf16(af[0][s], bv[s], accP[c][0], 0, 0, 0);
            accP[c][1] = __builtin_amdgcn_mfma_f32_16x16x32_bf16(af[1][s], bv[s], accP[c][1], 0, 0, 0);
        }
    }

    // ---- epilogue: comb = accP + cbias (cols < 288 only) ----
#pragma unroll
    for (int c = 0; c < 5; ++c) {
        const int col = c * 64 + wave * 16 + fr;
        if (col >= 288) continue;
        const float cb = cbias[col];
#pragma unroll
        for (int x = 0; x < 2; ++x)
#pragma unroll
            for (int r = 0; r < 4; ++r) {
                const int row = m0 + x * 16 + quad * 4 + r;
                comb[(size_t)row * 288 + col] = accP[c][x][r] + cb;
            }
    }
}

// ---------------------------------------------------------------------------
// MEGAFUSED v2 (R9 proven: 96.5 us): cross_out GEMM + LN1 + FFN + LN3,
// wave-private staging pipeline. 2 barriers per h.
__global__ __launch_bounds__(256) void cross_ffn_kernel(
    const unsigned short* __restrict__ A,     // msoutb M x 256 bf16
    const unsigned short* __restrict__ Wcr,   // 256 x 256 bf16 (cross_out)
    const float* __restrict__ bcr,            // cross_out_b
    const float* __restrict__ resid1,         // t (LN2 out) M x 256 fp32
    const float* __restrict__ g1, const float* __restrict__ b1g,
    float* __restrict__ t2,                   // scratch M x 256 fp32
    const unsigned short* __restrict__ W1,    // 1024 x 256 bf16
    const float* __restrict__ b1,             // 1024
    const unsigned short* __restrict__ W2,    // 256 x 1024 bf16
    const float* __restrict__ b2,             // 256
    const float* __restrict__ g3, const float* __restrict__ b3g,
    float* __restrict__ outf)
{
    __shared__ __align__(16) unsigned short Wc[16384];   // A-stage / W-chunks
    __shared__ __align__(16) unsigned short hid[2304];   // 32 x 72 (padded)
    const int tid  = threadIdx.x;
    const int wave = tid >> 6;
    const int lane = tid & 63;
    const int m0 = blockIdx.x * 32;
    const int fr   = lane & 15;
    const int quad = lane >> 4;
    const int xm   = fr & 7;           // XOR mask for swizzled fragment reads
    float2* red = (float2*)hid;        // 128 float2 = 1 KB (LN reductions)

    // ---- stage A=msout (32 rows) into Wc[0..8192), swizzled ----
#pragma unroll
    for (int j = 0; j < 4; ++j) {
        const int c  = wave * 4 + j;               // 0..15
        const int rA = c * 2 + (lane >> 5);        // row 0..31
        const int k8 = (lane & 31) ^ (rA & 7);
        GLDS16(A + (size_t)(m0 + rA) * 256 + k8 * 8, Wc + c * 512);
    }
    // ---- per-lane swizzled staging offsets for 64-row x 256-k chunks ----
    int w1off[8], w2off[8];
#pragma unroll
    for (int j = 0; j < 8; ++j) {
        const int c  = wave * 8 + j;               // 0..31
        const int n1 = c * 2 + (lane >> 5);        // chunk row 0..63
        const int k1 = (lane & 31) ^ (n1 & 7);
        w1off[j] = n1 * 256 + k1 * 8;              // + chunk*16384
        const int n2 = c * 8 + (lane >> 3);        // W2 row 0..255
        const int k2 = (lane & 7) ^ (n2 & 7);
        w2off[j] = n2 * 1024 + k2 * 8;             // + h*64
    }
    __syncthreads();                   // A visible (cross-wave af reads)
    bf16x8 af[2][8];
#pragma unroll
    for (int i = 0; i < 2; ++i)
#pragma unroll
        for (int s = 0; s < 8; ++s)
            af[i][s] = *(const bf16x8*)&Wc[((i * 16 + fr) * 32 + ((s * 4 + quad) ^ xm)) * 8];
    WAIT_LGKM0();
    __syncthreads();                   // all af reads done before Wcr stage

    // ================= PHASE 1: cross_out GEMM (4 chunks, 0 barriers) =====
#pragma unroll
    for (int j = 0; j < 8; ++j)
        GLDS16(Wcr + w1off[j], Wc + (wave * 8 + j) * 512);
    f32x4 accc[4][2] = {};
    for (int c = 0; c < 4; ++c) {
        WAIT_VM0();                    // Wcr[c] arrived (wave-local)
        bf16x8 bv[8];
#pragma unroll
        for (int s = 0; s < 8; ++s)
            bv[s] = *(const bf16x8*)&Wc[((wave * 16 + fr) * 32 + ((s * 4 + quad) ^ xm)) * 8];
        WAIT_LGKM0();                  // reads done before overwrite
        if (c < 3) {
#pragma unroll
            for (int j = 0; j < 8; ++j)
                GLDS16(Wcr + (size_t)(c + 1) * 16384 + w1off[j], Wc + (wave * 8 + j) * 512);
        }
#pragma unroll
        for (int s = 0; s < 8; ++s) {
            accc[c][0] = __builtin_amdgcn_mfma_f32_16x16x32_bf16(af[0][s], bv[s], accc[c][0], 0, 0, 0);
            accc[c][1] = __builtin_amdgcn_mfma_f32_16x16x32_bf16(af[1][s], bv[s], accc[c][1], 0, 0, 0);
        }
    }

    // ---- LN1: v = accc + bcr + resid1; normalize over 256 cols ----
    float rs[2][4], rq[2][4];
#pragma unroll
    for (int x = 0; x < 2; ++x) {
#pragma unroll
        for (int r = 0; r < 4; ++r) {
            const int row = m0 + x * 16 + quad * 4 + r;
            float s = 0.f, q = 0.f;
#pragma unroll
            for (int c = 0; c < 4; ++c) {
                const int col = c * 64 + wave * 16 + fr;
                float v = accc[c][x][r] + bcr[col] + resid1[(size_t)row * 256 + col];
                accc[c][x][r] = v;
                s += v; q += v * v;
            }
            rs[x][r] = s; rq[x][r] = q;
        }
    }
#pragma unroll
    for (int off = 1; off < 16; off <<= 1) {
#pragma unroll
        for (int x = 0; x < 2; ++x)
#pragma unroll
            for (int r = 0; r < 4; ++r) {
                rs[x][r] += __shfl_xor(rs[x][r], off);
                rq[x][r] += __shfl_xor(rq[x][r], off);
            }
    }
    if ((lane & 15) == 0) {
#pragma unroll
        for (int x = 0; x < 2; ++x)
#pragma unroll
            for (int r = 0; r < 4; ++r)
                red[wave * 32 + x * 16 + quad * 4 + r] = make_float2(rs[x][r], rq[x][r]);
    }
    __syncthreads();   // red visible; all waves' c=3 Wc reads done (handoff safe)
#pragma unroll
    for (int x = 0; x < 2; ++x) {
#pragma unroll
        for (int r = 0; r < 4; ++r) {
            const int rl = x * 16 + quad * 4 + r;
            const float2 t0 = red[rl], t1 = red[32 + rl], t2r = red[64 + rl], t3 = red[96 + rl];
            const float sum = t0.x + t1.x + t2r.x + t3.x;
            const float sq  = t0.y + t1.y + t2r.y + t3.y;
            const float mean = sum * (1.f / 256.f);
            const float var  = sq * (1.f / 256.f) - mean * mean;
            const float inv  = rsqrtf(var + 1e-5f);
            const int row = m0 + rl;
#pragma unroll
            for (int c = 0; c < 4; ++c) {
                const int col = c * 64 + wave * 16 + fr;
                const float val = (accc[c][x][r] - mean) * inv * g1[col] + b1g[col];
                t2[(size_t)row * 256 + col] = val;
                // bf16 handoff into A-stage layout (local row rl, col)
                const int g8 = col >> 3;
                Wc[rl * 256 + ((g8 ^ (rl & 7)) << 3) + (col & 7)] = f2b(val);
            }
        }
    }
    __syncthreads();   // handoff visible; red reads done
    // reload af = LN1 output fragments
#pragma unroll
    for (int i = 0; i < 2; ++i)
#pragma unroll
        for (int s = 0; s < 8; ++s)
            af[i][s] = *(const bf16x8*)&Wc[((i * 16 + fr) * 32 + ((s * 4 + quad) ^ xm)) * 8];
    WAIT_LGKM0();
    __syncthreads();   // all af reloads done before W1[0] stage overwrites

    // ================= PHASE 2: FFN, 2 barriers per h =================
#pragma unroll
    for (int j = 0; j < 8; ++j)
        GLDS16(W1 + w1off[j], Wc + (wave * 8 + j) * 512);
    WAIT_VM0();        // W1[0] arrived (first iter only: exposed)

    f32x4 acc2[2][4] = {};

    for (int h = 0; h < 16; ++h) {
        // ---- gemm1: bv from own W1 region -> regs; restage own region ----
        bf16x8 bv[8];
#pragma unroll
        for (int s = 0; s < 8; ++s)
            bv[s] = *(const bf16x8*)&Wc[((wave * 16 + fr) * 32 + ((s * 4 + quad) ^ xm)) * 8];
        WAIT_LGKM0();
#pragma unroll
        for (int j = 0; j < 8; ++j)
            GLDS16(W2 + (size_t)h * 64 + w2off[j], Wc + (wave * 8 + j) * 512);
        f32x4 acc1[2] = {};
#pragma unroll
        for (int s = 0; s < 8; ++s) {
            acc1[0] = __builtin_amdgcn_mfma_f32_16x16x32_bf16(af[0][s], bv[s], acc1[0], 0, 0, 0);
            acc1[1] = __builtin_amdgcn_mfma_f32_16x16x32_bf16(af[1][s], bv[s], acc1[1], 0, 0, 0);
        }
        const float bias1 = b1[h * 64 + wave * 16 + fr];
#pragma unroll
        for (int i = 0; i < 2; ++i)
#pragma unroll
            for (int r = 0; r < 4; ++r) {
                float v = fmaxf(acc1[i][r] + bias1, 0.f);
                hid[(i * 16 + quad * 4 + r) * 72 + wave * 16 + fr] = f2b(v);
            }
        __syncthreads();   // hid visible; W2[h] drained (covered by gemm1)
        // ---- gemm2: b2v from own W2 region + a2 from hid -> regs ----
#pragma unroll
        for (int s = 0; s < 2; ++s) {
            bf16x8 a2[2], b2v[4];
#pragma unroll
            for (int j2 = 0; j2 < 4; ++j2) {
                const int nb = wave * 64 + j2 * 16 + fr;
                b2v[j2] = *(const bf16x8*)&Wc[(nb * 8 + ((s * 4 + quad) ^ xm)) * 8];
            }
#pragma unroll
            for (int i = 0; i < 2; ++i)
                a2[i] = *(const bf16x8*)&hid[(i * 16 + fr) * 72 + s * 32 + quad * 8];
            if (s == 1) {
                WAIT_LGKM0();          // all Wc/hid reads done
                if (h < 15) {
#pragma unroll
                    for (int j = 0; j < 8; ++j)
                        GLDS16(W1 + (size_t)(h + 1) * 16384 + w1off[j], Wc + (wave * 8 + j) * 512);
                }
            }
#pragma unroll
            for (int i = 0; i < 2; ++i)
#pragma unroll
                for (int j2 = 0; j2 < 4; ++j2)
                    acc2[i][j2] = __builtin_amdgcn_mfma_f32_16x16x32_bf16(
                        a2[i], b2v[j2], acc2[i][j2], 0, 0, 0);
        }
        __syncthreads();   // hid free for next h; W1[h+1] drained (covered)
    }

    // ---- epilogue: v = acc2 + b2 + t2(resid, self-written); LN3 ----
    const int colbase = wave * 64;
#pragma unroll
    for (int x = 0; x < 2; ++x) {
#pragma unroll
        for (int r = 0; r < 4; ++r) {
            const int row = m0 + x * 16 + quad * 4 + r;
            float s = 0.f, q = 0.f;
#pragma unroll
            for (int y = 0; y < 4; ++y) {
                const int col = colbase + y * 16 + fr;
                float v = acc2[x][y][r] + b2[col] + t2[(size_t)row * 256 + col];
                acc2[x][y][r] = v;
                s += v; q += v * v;
            }
            rs[x][r] = s; rq[x][r] = q;
        }
    }
#pragma unroll
    for (int off = 1; off < 16; off <<= 1) {
#pragma unroll
        for (int x = 0; x < 2; ++x)
#pragma unroll
            for (int r = 0; r < 4; ++r) {
                rs[x][r] += __shfl_xor(rs[x][r], off);
                rq[x][r] += __shfl_xor(rq[x][r], off);
            }
    }
    if ((lane & 15) == 0) {
#pragma unroll
        for (int x = 0; x < 2; ++x)
#pragma unroll
            for (int r = 0; r < 4; ++r)
                red[wave * 32 + x * 16 + quad * 4 + r] = make_float2(rs[x][r], rq[x][r]);
    }
    __syncthreads();
#pragma unroll
    for (int x = 0; x < 2; ++x) {
#pragma unroll
        for (int r = 0; r < 4; ++r) {
            const int rl = x * 16 + quad * 4 + r;
            const float2 t0 = red[rl], t1 = red[32 + rl], t2r = red[64 + rl], t3 = red[96 + rl];
            const float sum = t0.x + t1.x + t2r.x + t3.x;
            const float sq  = t0.y + t1.y + t2r.y + t3.y;
            const float mean = sum * (1.f / 256.f);
            const float var  = sq * (1.f / 256.f) - mean * mean;
            const float inv  = rsqrtf(var + 1e-5f);
            const int row = m0 + rl;
#pragma unroll
            for (int y = 0; y < 4; ++y) {
                const int col = colbase + y * 16 + fr;
                outf[(size_t)row * 256 + col] = (acc2[x][y][r] - mean) * inv * g3[col] + b3g[col];
            }
        }
    }
}

// ---------------------------------------------------------------------------
// Self-attention over S=8 (batch axis), vectorized I/O (R10 proven).
__global__ __launch_bounds__(256) void self_attn_kernel(
    const unsigned short* __restrict__ qkv, unsigned short* __restrict__ ctx)
{
    __shared__ float sh[8][768];                    // 24 KB
    __shared__ float ls[8][8][8];                   // [h][s][t], 2 KB
    __shared__ __align__(16) unsigned short ob[2048];  // 8 rows x 256, 4 KB
    const int n = blockIdx.x;
    const int t = threadIdx.x;

    // ---- vector load: 8 rows x 768 shorts = 6144 shorts; 24/thread ----
    const unsigned short* base = qkv + (size_t)n * 8 * 768;
#pragma unroll
    for (int i = 0; i < 3; ++i) {
        const int idx = (i * 256 + t) * 8;          // 16B-aligned short index
        bf16x8 v = *(const bf16x8*)&base[idx];
        const int s = idx / 768;                    // row 0..7 (768 % 8 == 0)
        const int c = idx - s * 768;
#pragma unroll
        for (int j = 0; j < 8; ++j)
            sh[s][c + j] = b2f((unsigned short)v[j]);
    }
    __syncthreads();
    const int h = t >> 5, j = t & 31;
#pragma unroll
    for (int pair = j; pair < 64; pair += 32) {
        const int s = pair >> 3, tt = pair & 7;
        float acc = 0.f;
#pragma unroll
        for (int d = 0; d < 32; ++d)
            acc += sh[s][h * 32 + d] * sh[tt][256 + h * 32 + d];
        ls[h][s][tt] = acc * 0.17677669529663687f;
    }
    __syncthreads();
    if (t < 64) {
        const int hh = t >> 3, s = t & 7;
        float mx = -1e30f;
        for (int tt = 0; tt < 8; ++tt) mx = fmaxf(mx, ls[hh][s][tt]);
        float sum = 0.f;
        for (int tt = 0; tt < 8; ++tt) { float e = expf(ls[hh][s][tt] - mx); ls[hh][s][tt] = e; sum += e; }
        const float inv = 1.f / sum;
        for (int tt = 0; tt < 8; ++tt) ls[hh][s][tt] *= inv;
    }
    __syncthreads();
    // ---- PV -> LDS staging (channel = h*32+j = t) ----
#pragma unroll
    for (int s = 0; s < 8; ++s) {
        float acc = 0.f;
#pragma unroll
        for (int tt = 0; tt < 8; ++tt)
            acc += ls[h][s][tt] * sh[tt][512 + h * 32 + j];
        ob[s * 256 + t] = f2b(acc);
    }
    __syncthreads();
    // ---- vector store: 2048 shorts = 256 threads x bf16x8 ----
    ((bf16x8*)ctx)[(size_t)n * 256 + t] = ((const bf16x8*)ob)[t];
}

// ---------------------------------------------------------------------------
// Merged msprep + deformable sampling (R6 proven).
__global__ __launch_bounds__(256) void msdeform_kernel(
    const unsigned short* __restrict__ value,
    const float* __restrict__ comb,
    unsigned short* __restrict__ out)
{
    const int bid = blockIdx.x;
    const int b   = bid & 7;
    const int lq0 = (bid >> 3) * 4;
    const int r    = threadIdx.x >> 6;
    const int lane = threadIdx.x & 63;
    const int h = lane >> 3;
    const int l = lane & 7;
    const int lq = lq0 + r;
    const int m = lq * 8 + b;

    // ---- load raw offsets + attention logits for (m,h) ----
    const float* offp = comb + (size_t)m * 288 + h * 24;
    const float* awp  = comb + (size_t)m * 288 + 192 + h * 12;
    float off[24], aw[12];
#pragma unroll
    for (int i = 0; i < 6; ++i) *(float4*)&off[i * 4] = ((const float4*)offp)[i];
#pragma unroll
    for (int i = 0; i < 3; ++i) *(float4*)&aw[i * 4] = ((const float4*)awp)[i];

    float mx = aw[0];
#pragma unroll
    for (int i = 1; i < 12; ++i) mx = fmaxf(mx, aw[i]);
    float se = 0.f;
#pragma unroll
    for (int i = 0; i < 12; ++i) { aw[i] = __expf(aw[i] - mx); se += aw[i]; }
    const float inv = 1.f / se;

    const float refx = ((lq % 60) + 0.5f) * (1.f / 60.f);
    const float refy = ((lq / 60) + 0.5f) * (1.f / 60.f);
    const int HW[3] = {60, 30, 15};
    const int ST[3] = {0, 3600, 4500};

    const unsigned short* vbase = value + (size_t)b * LIN * 256 + h * 32 + l * 4;

    float a0 = 0.f, a1 = 0.f, a2 = 0.f, a3 = 0.f;
#pragma unroll
    for (int lev = 0; lev < NLEV; ++lev) {
        const int Wl = HW[lev], s0 = ST[lev];
        const float fWl = (float)Wl;
#pragma unroll
        for (int p = 0; p < NPNT; ++p) {
            const int pt = lev * 4 + p;
            const float ox = off[lev * 8 + p * 2];
            const float oy = off[lev * 8 + p * 2 + 1];
            const float px = refx * fWl + ox - 0.5f;
            const float py = refy * fWl + oy - 0.5f;
            const float x0f = floorf(px), y0f = floorf(py);
            const float fx = px - x0f, fy = py - y0f;
            const int x0 = (int)x0f, y0 = (int)y0f;
            const float aww = aw[pt] * inv;
            const float vx0 = (x0 >= 0 && x0 < Wl) ? 1.f : 0.f;
            const float vx1 = (x0 >= -1 && x0 < Wl - 1) ? 1.f : 0.f;
            const float vy0 = (y0 >= 0 && y0 < Wl) ? 1.f : 0.f;
            const float vy1 = (y0 >= -1 && y0 < Wl - 1) ? 1.f : 0.f;
            const int xc0 = min(max(x0, 0), Wl - 1);
            const int xc1 = min(max(x0 + 1, 0), Wl - 1);
            const int yc0 = min(max(y0, 0), Wl - 1);
            const int yc1 = min(max(y0 + 1, 0), Wl - 1);
            const int sx  = xc1 - xc0;
            const int syW = (yc1 - yc0) * Wl;
            const int i00 = s0 + yc0 * Wl + xc0;
            const float w00 = (1.f - fx) * (1.f - fy) * aww * vx0 * vy0;
            const float w01 = fx * (1.f - fy) * aww * vx1 * vy0;
            const float w10 = (1.f - fx) * fy * aww * vx0 * vy1;
            const float w11 = fx * fy * aww * vx1 * vy1;
            const int i01 = i00 + sx;
            const int i10 = i00 + syW;
            const int i11 = i10 + sx;
            const ushort4 g00 = *(const ushort4*)(vbase + (size_t)i00 * 256);
            const ushort4 g01 = *(const ushort4*)(vbase + (size_t)i01 * 256);
            const ushort4 g10 = *(const ushort4*)(vbase + (size_t)i10 * 256);
            const ushort4 g11 = *(const ushort4*)(vbase + (size_t)i11 * 256);
            a0 += b2f(g00.x) * w00 + b2f(g01.x) * w01 + b2f(g10.x) * w10 + b2f(g11.x) * w11;
            a1 += b2f(g00.y) * w00 + b2f(g01.y) * w01 + b2f(g10.y) * w10 + b2f(g11.y) * w11;
            a2 += b2f(g00.z) * w00 + b2f(g01.z) * w01 + b2f(g10.z) * w10 + b2f(g11.z) * w11;
            a3 += b2f(g00.w) * w00 + b2f(g01.w) * w01 + b2f(g10.w) * w10 + b2f(g11.w) * w11;
        }
    }
    ushort4 o;
    o.x = f2b(a0); o.y = f2b(a1); o.z = f2b(a2); o.w = f2b(a3);
    *(ushort4*)(out + (size_t)m * 256 + h * 32 + l * 4) = o;
}

// ---------------------------------------------------------------------------
extern "C" void kernel_launch(void* const* d_in, const int* in_sizes, int n_in,
                              void* d_out, int out_size, void* d_ws, size_t ws_size,
                              hipStream_t stream)
{
    (void)in_sizes; (void)n_in; (void)out_size; (void)ws_size;
    const float* tgt          = (const float*)d_in[0];   // (LQ,B,D): (lq,b)-major rows
    const float* qp           = (const float*)d_in[1];
    const float* src          = (const float*)d_in[2];
    const float* in_proj_w    = (const float*)d_in[5];
    const float* in_proj_b    = (const float*)d_in[6];
    const float* out_proj_w   = (const float*)d_in[7];
    const float* out_proj_b   = (const float*)d_in[8];
    const float* samp_off_w   = (const float*)d_in[9];
    const float* samp_off_b   = (const float*)d_in[10];
    const float* attn_w_w     = (const float*)d_in[11];
    const float* attn_w_b     = (const float*)d_in[12];
    const float* value_proj_w = (const float*)d_in[13];
    const float* value_proj_b = (const float*)d_in[14];
    const float* cross_out_w  = (const float*)d_in[15];
    const float* cross_out_b  = (const float*)d_in[16];
    const float* ln1_g = (const float*)d_in[17];
    const float* ln1_b = (const float*)d_in[18];
    const float* ln2_g = (const float*)d_in[19];
    const float* ln2_b = (const float*)d_in[20];
    const float* ln3_g = (const float*)d_in[21];
    const float* ln3_b = (const float*)d_in[22];
    const float* ffn_w1 = (const float*)d_in[23];
    const float* ffn_b1 = (const float*)d_in[24];
    const float* ffn_w2 = (const float*)d_in[25];
    const float* ffn_b2 = (const float*)d_in[26];
    float* out = (float*)d_out;

    // ---- fp32 arena (floats) ----
    float* ws    = (float*)d_ws;
    float* t     = ws;                    // LN2 out (residual for LN1)
    float* t2    = ws + 7372800;          // LN1 out scratch (cross_ffn self RW)
    float* comb  = ws + 14745600;         // 28800x288 off+aw (raw, fp32)
    float* qpv   = ws + 23040000;         // 1056 qp-proj + 288 cbias
    float* cbias = qpv + 1056;

    // ---- bf16 arena (ushort), after fp32 arena (byte 92,165,376) ----
    unsigned short* bws    = (unsigned short*)((char*)d_ws + 92165376);
    unsigned short* s1     = bws;                  // tgtb -> ctxb
    unsigned short* tgtb   = s1;
    unsigned short* ctxb   = s1;
    unsigned short* s2     = bws + 7372800;        // qkvb / valueb+msoutb
    unsigned short* qkvb   = s2;
    unsigned short* valueb = s2;
    unsigned short* msoutb = s2 + 9676800;
    unsigned short* srcb   = bws + 36864000;
    unsigned short* wtsb   = bws + 46540800;       // 991,232 shorts

    // 1. merged prep (conversions + weight cast + query_pos projections)
    prep_kernel<<<17623, 256, 0, stream>>>(tgt, tgtb, src, srcb,
                                           in_proj_w, out_proj_w, value_proj_w,
                                           cross_out_w, samp_off_w, attn_w_w,
                                           ffn_w1, ffn_w2, wtsb,
                                           qp, samp_off_b, attn_w_b, qpv);
    // 2. QKV projection (Q,K cols get query_pos bias via qpv, cols < 512)
    gemm_bf16<<<dim3(225, 6), 256, 0, stream>>>(tgtb, wtsb + 0, in_proj_b, qpv, 512,
                                                nullptr, qkvb, MROWS, 768, 256, 0);
    // 3. self-attention over batch axis (vectorized I/O)
    self_attn_kernel<<<3600, 256, 0, stream>>>(qkvb, ctxb);
    // 4. t = LN2(tgt + out_proj(ctx)); comb = (t+qp) @ Wso^T  [megafused]
    ln2_offs_kernel<<<900, 256, 0, stream>>>(ctxb, wtsb + 196608, out_proj_b,
                                             tgt, ln2_g, ln2_b, t,
                                             wtsb + 393216, cbias, comb);
    // 5. value projection (M = 37800)
    gemm_bf16<<<dim3(296, 2), 256, 0, stream>>>(srcb, wtsb + 262144, value_proj_b, nullptr, 0,
                                                nullptr, valueb, BATCH * LIN, 256, 256, 0);
    // 6. deformable sampling with inline softmax/bilinear setup
    msdeform_kernel<<<7200, 256, 0, stream>>>(valueb, comb, msoutb);
    // 7. out = LN3(t2 + FFN(t2)), t2 = LN1(t + cross_out(msout))  [megafused]
    cross_ffn_kernel<<<900, 256, 0, stream>>>(msoutb, wtsb + 327680, cross_out_b,
                                              t, ln1_g, ln1_b, t2,
                                              wtsb + 466944, ffn_b1,
                                              wtsb + 729088, ffn_b2,
                                              ln3_g, ln3_b, out);
}

// Round 12
// 427.416 us; speedup vs baseline: 1.0740x; 1.0400x over previous
//
#include <hip/hip_runtime.h>
#include <hip/hip_bf16.h>
#include <cstddef>
#include <cstdint>

// Problem constants
#define D_MODEL 256
#define NHEAD   8
#define HDIM    32
#define NLEV    3
#define NPNT    4
#define DFF     1024
#define BATCH   8
#define LQ      3600
#define LIN     4725   // 60*60 + 30*30 + 15*15
#define MROWS   (BATCH*LQ)   // 28800; row order is (lq,b): m = lq*8 + b

typedef short bf16x8 __attribute__((ext_vector_type(8)));
typedef float f32x4  __attribute__((ext_vector_type(4)));

__device__ __forceinline__ unsigned short f2b(float x) {
    unsigned int u = __float_as_uint(x);
    unsigned int r = (u + 0x7fffu + ((u >> 16) & 1u)) >> 16;   // RNE
    return (unsigned short)r;
}
__device__ __forceinline__ float b2f(unsigned short s) {
    return __uint_as_float(((unsigned int)s) << 16);
}

#define GLDS16(g, l) __builtin_amdgcn_global_load_lds( \
    (const __attribute__((address_space(1))) void*)(g), \
    (__attribute__((address_space(3))) void*)(l), 16, 0, 0)

#define WAIT_VM0()  asm volatile("s_waitcnt vmcnt(0)" ::: "memory")
#define WAIT_LGKM0() asm volatile("s_waitcnt lgkmcnt(0)" ::: "memory")

// ---------------------------------------------------------------------------
// Merged prep: [0,7200) conv tgt->bf16; [7200,16650) conv src->bf16;
// [16650,17618) weight convert; [17618,17623) query_pos projections.
#define WTOT 991232
__global__ __launch_bounds__(256) void prep_kernel(
    const float* __restrict__ tgt, unsigned short* __restrict__ tgtb,
    const float* __restrict__ srcf, unsigned short* __restrict__ srcb,
    const float* __restrict__ w_in, const float* __restrict__ w_out,
    const float* __restrict__ w_val, const float* __restrict__ w_cross,
    const float* __restrict__ w_so, const float* __restrict__ w_aw,
    const float* __restrict__ w_f1, const float* __restrict__ w_f2,
    unsigned short* __restrict__ wdst,
    const float* __restrict__ qp, const float* __restrict__ so_b,
    const float* __restrict__ aw_b, float* __restrict__ qpv)
{
    const int bid = blockIdx.x;
    const int tid = threadIdx.x;
    if (bid < 7200) {
        int i = bid * 256 + tid;
        float4 v = ((const float4*)tgt)[i];
        ushort4 o; o.x = f2b(v.x); o.y = f2b(v.y); o.z = f2b(v.z); o.w = f2b(v.w);
        ((ushort4*)tgtb)[i] = o;
    } else if (bid < 16650) {
        int i = (bid - 7200) * 256 + tid;
        float4 v = ((const float4*)srcf)[i];
        ushort4 o; o.x = f2b(v.x); o.y = f2b(v.y); o.z = f2b(v.z); o.w = f2b(v.w);
        ((ushort4*)srcb)[i] = o;
    } else if (bid < 17618) {
        int idx = ((bid - 16650) * 256 + tid) * 4;
        if (idx >= WTOT) return;
        const float* src; int off;
        if      (idx < 196608) { src = w_in;    off = idx; }
        else if (idx < 262144) { src = w_out;   off = idx - 196608; }
        else if (idx < 327680) { src = w_val;   off = idx - 262144; }
        else if (idx < 393216) { src = w_cross; off = idx - 327680; }
        else if (idx < 442368) { src = w_so;    off = idx - 393216; }
        else if (idx < 466944) { src = w_aw;    off = idx - 442368; }
        else if (idx < 729088) { src = w_f1;    off = idx - 466944; }
        else                   { src = w_f2;    off = idx - 729088; }
        float4 v = *(const float4*)(src + off);
        ushort4 o; o.x = f2b(v.x); o.y = f2b(v.y); o.z = f2b(v.z); o.w = f2b(v.w);
        *(ushort4*)(wdst + idx) = o;
    } else {
        int o = (bid - 17618) * 256 + tid;
        if (o >= 768 + 192 + 96) return;
        const float* wrow;
        if (o < 768)       wrow = w_in + (size_t)o * D_MODEL;
        else if (o < 960)  wrow = w_so + (size_t)(o - 768) * D_MODEL;
        else               wrow = w_aw + (size_t)(o - 960) * D_MODEL;
        float acc = 0.f;
        for (int d = 0; d < D_MODEL; ++d) acc += qp[d] * wrow[d];
        qpv[o] = acc;
        if (o >= 768) {
            float bias = (o < 960) ? so_b[o - 768] : aw_b[o - 960];
            qpv[1056 + (o - 768)] = acc + bias;
        }
    }
}

// ---------------------------------------------------------------------------
// bf16 MFMA GEMM (R4 proven version): 128x128 tile, BK=64 (2x32 panels),
// global_load_lds width=16 staging. Used only for the value projection now.
__global__ __launch_bounds__(256) void gemm_bf16(
    const unsigned short* __restrict__ A,
    const unsigned short* __restrict__ W,
    const float* __restrict__ bias,
    const float* __restrict__ bias2, int b2lim,
    float* __restrict__ Cf, unsigned short* __restrict__ Cb,
    int M, int N, int K, int relu)
{
    __shared__ __align__(16) unsigned short As[2 * 128 * 32];   // 16 KB
    __shared__ __align__(16) unsigned short Bs[2 * 128 * 32];   // 16 KB
    const int tid  = threadIdx.x;
    const int wave = tid >> 6;
    const int lane = tid & 63;
    const int m0 = blockIdx.x * 128;
    const int n0 = blockIdx.y * 128;

    const int lr  = lane >> 2;
    const int lc8 = (lane & 3) * 8;
    int ar0 = m0 + wave * 32 + lr;      if (ar0 > M - 1) ar0 = M - 1;
    int ar1 = m0 + wave * 32 + 16 + lr; if (ar1 > M - 1) ar1 = M - 1;
    int br0 = n0 + wave * 32 + lr;      if (br0 > N - 1) br0 = N - 1;
    int br1 = n0 + wave * 32 + 16 + lr; if (br1 > N - 1) br1 = N - 1;
    const unsigned short* pa0 = A + (size_t)ar0 * K + lc8;
    const unsigned short* pa1 = A + (size_t)ar1 * K + lc8;
    const unsigned short* pb0 = W + (size_t)br0 * K + lc8;
    const unsigned short* pb1 = W + (size_t)br1 * K + lc8;
    unsigned short* la0 = As + wave * 1024;
    unsigned short* la1 = As + wave * 1024 + 512;
    unsigned short* lb0 = Bs + wave * 1024;
    unsigned short* lb1 = Bs + wave * 1024 + 512;

    const int wm = (wave >> 1) * 64;
    const int wn = (wave & 1) * 64;
    const int fr = lane & 15;
    const int fk = (lane >> 4) * 8;

    f32x4 acc[4][4] = {};

    for (int k0 = 0; k0 < K; k0 += 64) {
        GLDS16(pa0, la0); GLDS16(pa0 + 32, la0 + 4096);
        GLDS16(pa1, la1); GLDS16(pa1 + 32, la1 + 4096);
        GLDS16(pb0, lb0); GLDS16(pb0 + 32, lb0 + 4096);
        GLDS16(pb1, lb1); GLDS16(pb1 + 32, lb1 + 4096);
        pa0 += 64; pa1 += 64; pb0 += 64; pb1 += 64;
        __syncthreads();
#pragma unroll
        for (int p = 0; p < 2; ++p) {
            bf16x8 af[4], bfv[4];
#pragma unroll
            for (int i = 0; i < 4; ++i)
                af[i] = *(const bf16x8*)&As[p * 4096 + (wm + i * 16 + fr) * 32 + fk];
#pragma unroll
            for (int j = 0; j < 4; ++j)
                bfv[j] = *(const bf16x8*)&Bs[p * 4096 + (wn + j * 16 + fr) * 32 + fk];
#pragma unroll
            for (int i = 0; i < 4; ++i)
#pragma unroll
                for (int j = 0; j < 4; ++j)
                    acc[i][j] = __builtin_amdgcn_mfma_f32_16x16x32_bf16(
                        af[i], bfv[j], acc[i][j], 0, 0, 0);
        }
        __syncthreads();
    }

    const int quad = lane >> 4;
#pragma unroll
    for (int j = 0; j < 4; ++j) {
        const int col = n0 + wn + j * 16 + fr;
        if (col >= N) continue;
        float bv = 0.f;
        if (bias) bv += bias[col];
        if (bias2 && col < b2lim) bv += bias2[col];
#pragma unroll
        for (int i = 0; i < 4; ++i) {
#pragma unroll
            for (int r = 0; r < 4; ++r) {
                const int row = m0 + wm + i * 16 + quad * 4 + r;
                if (row >= M) continue;
                float v = acc[i][j][r] + bv;
                if (relu) v = fmaxf(v, 0.f);
                if (Cf) Cf[(size_t)row * N + col] = v;
                if (Cb) Cb[(size_t)row * N + col] = f2b(v);
            }
        }
    }
}

// ---------------------------------------------------------------------------
// GIGAFUSED: QKV GEMM + self-attention + out_proj + LN2 + offs projection.
// 32 rows/block = 4 COMPLETE attention groups (4 lq x 8 batch, since
// m = lq*8+b) -> attention is block-local. Structure (all proven patterns):
//  - wave-private chunked GEMM (R9): 12 chunks of W_in (N=768) in 3 passes
//    (Q/K/V, 4 chunks each); per-pass epilogue adds in_proj_b (+qpv for
//    cols<512) and parks the bf16 tile in LDS (stride 264 = +8 pad so the
//    8 si-lanes of a score read hit 8 distinct banks).
//  - attention: thread (g=wave, h=lane>>3, si=lane&7) owns score row
//    [si][0..7] -> softmax is thread-local (no shuffles); PV writes f2b
//    straight into Wc's A-stage swizzled layout (cross_ffn handoff).
//  - out_proj GEMM + LN2 -> t + handoff; offs GEMM (5 chunks, clamped
//    tail) -> comb. Verbatim from R11's ln2_offs.
// Eliminates: self_attn + ln2_offs launches, qkvb (44 MB w + 44 MB r),
// ctxb (14.7 w + re-read). Numerics bit-identical (same k-order and bf16
// rounding points as the qkvb/ctxb path). LDS 66 KB -> 2 blocks/CU;
// 900 blocks > resident set -> block-level pipelining retained.
__global__ __launch_bounds__(256) void qkv_attn_ln2_offs_kernel(
    const unsigned short* __restrict__ A,     // tgtb M x 256 bf16
    const unsigned short* __restrict__ Win,   // 768 x 256 bf16 (in_proj)
    const float* __restrict__ bin,            // in_proj_b (768)
    const float* __restrict__ qpv,            // qp @ Win rows (768)
    const unsigned short* __restrict__ Wo,    // 256 x 256 bf16 (out_proj)
    const float* __restrict__ bo,
    const float* __restrict__ resid,          // tgt M x 256 fp32
    const float* __restrict__ g2, const float* __restrict__ b2g,
    float* __restrict__ tout,                 // t M x 256 fp32
    const unsigned short* __restrict__ Wso,   // 288 x 256 bf16 (so+aw)
    const float* __restrict__ cbias,          // 288
    float* __restrict__ comb)                 // M x 288 fp32
{
    __shared__ __align__(16) unsigned short Wc[16384];   // 32 KB staging
    __shared__ __align__(16) unsigned short qt[32 * 264];// Q tile, 16.5 KB
    __shared__ __align__(16) unsigned short kvt[32 * 264];// K then V, 16.5 KB
    __shared__ float2 red[128];                          // LN reduction
    const int tid  = threadIdx.x;
    const int wave = tid >> 6;
    const int lane = tid & 63;
    const int m0 = blockIdx.x * 32;
    const int fr   = lane & 15;
    const int quad = lane >> 4;
    const int xm   = fr & 7;

    // ---- stage A=tgtb (32 rows) into Wc[0..8192), swizzled ----
#pragma unroll
    for (int j = 0; j < 4; ++j) {
        const int c  = wave * 4 + j;
        const int rA = c * 2 + (lane >> 5);
        const int k8 = (lane & 31) ^ (rA & 7);
        GLDS16(A + (size_t)(m0 + rA) * 256 + k8 * 8, Wc + c * 512);
    }
    // ---- per-lane swizzled staging offsets (64-row x 256-k chunks) ----
    int w1off[8], w4off[8];
#pragma unroll
    for (int j = 0; j < 8; ++j) {
        const int c  = wave * 8 + j;
        const int n1 = c * 2 + (lane >> 5);
        const int k1 = (lane & 31) ^ (n1 & 7);
        w1off[j] = n1 * 256 + k1 * 8;
        const int n4 = (n1 < 32) ? n1 : 31;        // clamp for Wso chunk 4
        const int k4 = (lane & 31) ^ (n4 & 7);
        w4off[j] = n4 * 256 + k4 * 8;
    }
    __syncthreads();                   // A visible
    bf16x8 af[2][8];
#pragma unroll
    for (int i = 0; i < 2; ++i)
#pragma unroll
        for (int s = 0; s < 8; ++s)
            af[i][s] = *(const bf16x8*)&Wc[((i * 16 + fr) * 32 + ((s * 4 + quad) ^ xm)) * 8];
    WAIT_LGKM0();
    __syncthreads();                   // af reads done before staging

    // ============ QKV GEMM: 3 passes x 4 chunks, wave-private ============
#pragma unroll
    for (int j = 0; j < 8; ++j)
        GLDS16(Win + w1off[j], Wc + (wave * 8 + j) * 512);

#define QCHUNK(CG, PF) {                                                     \
        WAIT_VM0();                                                          \
        bf16x8 bv[8];                                                        \
        _Pragma("unroll")                                                    \
        for (int s = 0; s < 8; ++s)                                          \
            bv[s] = *(const bf16x8*)&Wc[((wave * 16 + fr) * 32 + ((s * 4 + quad) ^ xm)) * 8]; \
        WAIT_LGKM0();                                                        \
        if (PF) {                                                            \
            _Pragma("unroll")                                                \
            for (int j = 0; j < 8; ++j)                                      \
                GLDS16(Win + (size_t)((CG) + 1) * 16384 + w1off[j], Wc + (wave * 8 + j) * 512); \
        }                                                                    \
        _Pragma("unroll")                                                    \
        for (int s = 0; s < 8; ++s) {                                        \
            acc[(CG) & 3][0] = __builtin_amdgcn_mfma_f32_16x16x32_bf16(af[0][s], bv[s], acc[(CG) & 3][0], 0, 0, 0); \
            acc[(CG) & 3][1] = __builtin_amdgcn_mfma_f32_16x16x32_bf16(af[1][s], bv[s], acc[(CG) & 3][1], 0, 0, 0); \
        }                                                                    \
    }

#define QKV_EPI(P, TILE) {                                                   \
        _Pragma("unroll")                                                    \
        for (int x = 0; x < 2; ++x)                                          \
        _Pragma("unroll")                                                    \
        for (int r = 0; r < 4; ++r) {                                        \
            const int rl = x * 16 + quad * 4 + r;                            \
            _Pragma("unroll")                                                \
            for (int c = 0; c < 4; ++c) {                                    \
                const int col  = c * 64 + wave * 16 + fr;                    \
                const int gcol = (P) * 256 + col;                            \
                float v = acc[c][x][r] + bin[gcol];                          \
                if ((P) < 2) v += qpv[gcol];                                 \
                (TILE)[rl * 264 + col] = f2b(v);                             \
            }                                                                \
        }                                                                    \
    }

    {
        f32x4 acc[4][2] = {};
#pragma unroll
        for (int c = 0; c < 4; ++c) QCHUNK(c, 1)
        QKV_EPI(0, qt)
    }
    {
        f32x4 acc[4][2] = {};
#pragma unroll
        for (int c = 4; c < 8; ++c) QCHUNK(c, 1)
        QKV_EPI(1, kvt)
    }
    __syncthreads();                   // qt + kt visible to all waves

    // ---- scores + softmax: thread (g=wave, h, si) owns one score row ----
    const int g  = wave;
    const int ah = lane >> 3;
    const int si = lane & 7;
    float p[8];
    {
        float qreg[32];
#pragma unroll
        for (int d = 0; d < 32; ++d)
            qreg[d] = b2f(qt[(g * 8 + si) * 264 + ah * 32 + d]);
        float mx = -1e30f;
#pragma unroll
        for (int ti = 0; ti < 8; ++ti) {
            float a = 0.f;
#pragma unroll
            for (int d = 0; d < 32; ++d)
                a += qreg[d] * b2f(kvt[(g * 8 + ti) * 264 + ah * 32 + d]);
            a *= 0.17677669529663687f;
            p[ti] = a;
            mx = fmaxf(mx, a);
        }
        float sum = 0.f;
#pragma unroll
        for (int ti = 0; ti < 8; ++ti) { p[ti] = expf(p[ti] - mx); sum += p[ti]; }
        const float inv = 1.f / sum;
#pragma unroll
        for (int ti = 0; ti < 8; ++ti) p[ti] *= inv;
    }
    __syncthreads();                   // kt reads done before V overwrites kvt

    {
        f32x4 acc[4][2] = {};
#pragma unroll
        for (int c = 8; c < 12; ++c) QCHUNK(c, (c < 11))
        QKV_EPI(2, kvt)
    }
    __syncthreads();                   // vt visible; all Wc GEMM reads done

    // ---- PV -> ctx, written directly into Wc A-stage handoff layout ----
    {
        const int rl = g * 8 + si;
#pragma unroll
        for (int d = 0; d < 32; ++d) {
            float a = 0.f;
#pragma unroll
            for (int ti = 0; ti < 8; ++ti)
                a += p[ti] * b2f(kvt[(g * 8 + ti) * 264 + ah * 32 + d]);
            const int col = ah * 32 + d;
            Wc[rl * 256 + (((col >> 3) ^ (rl & 7)) << 3) + (col & 7)] = f2b(a);
        }
    }
    __syncthreads();                   // handoff visible
    // reload af = ctx fragments
#pragma unroll
    for (int i = 0; i < 2; ++i)
#pragma unroll
        for (int s = 0; s < 8; ++s)
            af[i][s] = *(const bf16x8*)&Wc[((i * 16 + fr) * 32 + ((s * 4 + quad) ^ xm)) * 8];
    WAIT_LGKM0();
    __syncthreads();                   // af reloads done before Wo staging

    // ================= out_proj GEMM (4 chunks) + LN2 =================
#pragma unroll
    for (int j = 0; j < 8; ++j)
        GLDS16(Wo + w1off[j], Wc + (wave * 8 + j) * 512);
    f32x4 accc[4][2] = {};
    for (int c = 0; c < 4; ++c) {
        WAIT_VM0();
        bf16x8 bv[8];
#pragma unroll
        for (int s = 0; s < 8; ++s)
            bv[s] = *(const bf16x8*)&Wc[((wave * 16 + fr) * 32 + ((s * 4 + quad) ^ xm)) * 8];
        WAIT_LGKM0();
        if (c < 3) {
#pragma unroll
            for (int j = 0; j < 8; ++j)
                GLDS16(Wo + (size_t)(c + 1) * 16384 + w1off[j], Wc + (wave * 8 + j) * 512);
        }
#pragma unroll
        for (int s = 0; s < 8; ++s) {
            accc[c][0] = __builtin_amdgcn_mfma_f32_16x16x32_bf16(af[0][s], bv[s], accc[c][0], 0, 0, 0);
            accc[c][1] = __builtin_amdgcn_mfma_f32_16x16x32_bf16(af[1][s], bv[s], accc[c][1], 0, 0, 0);
        }
    }
    float rs[2][4], rq[2][4];
#pragma unroll
    for (int x = 0; x < 2; ++x) {
#pragma unroll
        for (int r = 0; r < 4; ++r) {
            const int row = m0 + x * 16 + quad * 4 + r;
            float s = 0.f, q = 0.f;
#pragma unroll
            for (int c = 0; c < 4; ++c) {
                const int col = c * 64 + wave * 16 + fr;
                float v = accc[c][x][r] + bo[col] + resid[(size_t)row * 256 + col];
                accc[c][x][r] = v;
                s += v; q += v * v;
            }
            rs[x][r] = s; rq[x][r] = q;
        }
    }
#pragma unroll
    for (int off = 1; off < 16; off <<= 1) {
#pragma unroll
        for (int x = 0; x < 2; ++x)
#pragma unroll
            for (int r = 0; r < 4; ++r) {
                rs[x][r] += __shfl_xor(rs[x][r], off);
                rq[x][r] += __shfl_xor(rq[x][r], off);
            }
    }
    if ((lane & 15) == 0) {
#pragma unroll
        for (int x = 0; x < 2; ++x)
#pragma unroll
            for (int r = 0; r < 4; ++r)
                red[wave * 32 + x * 16 + quad * 4 + r] = make_float2(rs[x][r], rq[x][r]);
    }
    __syncthreads();   // red visible; all waves' c=3 Wc reads done
#pragma unroll
    for (int x = 0; x < 2; ++x) {
#pragma unroll
        for (int r = 0; r < 4; ++r) {
            const int rl = x * 16 + quad * 4 + r;
            const float2 t0 = red[rl], t1 = red[32 + rl], t2r = red[64 + rl], t3 = red[96 + rl];
            const float sum = t0.x + t1.x + t2r.x + t3.x;
            const float sq  = t0.y + t1.y + t2r.y + t3.y;
            const float mean = sum * (1.f / 256.f);
            const float var  = sq * (1.f / 256.f) - mean * mean;
            const float inv  = rsqrtf(var + 1e-5f);
            const int row = m0 + rl;
#pragma unroll
            for (int c = 0; c < 4; ++c) {
                const int col = c * 64 + wave * 16 + fr;
                const float val = (accc[c][x][r] - mean) * inv * g2[col] + b2g[col];
                tout[(size_t)row * 256 + col] = val;
                const int g8 = col >> 3;
                Wc[rl * 256 + ((g8 ^ (rl & 7)) << 3) + (col & 7)] = f2b(val);
            }
        }
    }
    __syncthreads();   // handoff visible
#pragma unroll
    for (int i = 0; i < 2; ++i)
#pragma unroll
        for (int s = 0; s < 8; ++s)
            af[i][s] = *(const bf16x8*)&Wc[((i * 16 + fr) * 32 + ((s * 4 + quad) ^ xm)) * 8];
    WAIT_LGKM0();
    __syncthreads();   // af reloads done before Wso staging

    // ================= offs GEMM (5 chunks, clamped tail) =================
#pragma unroll
    for (int j = 0; j < 8; ++j)
        GLDS16(Wso + w1off[j], Wc + (wave * 8 + j) * 512);
    f32x4 accP[5][2] = {};
    for (int c = 0; c < 5; ++c) {
        WAIT_VM0();
        bf16x8 bv[8];
#pragma unroll
        for (int s = 0; s < 8; ++s)
            bv[s] = *(const bf16x8*)&Wc[((wave * 16 + fr) * 32 + ((s * 4 + quad) ^ xm)) * 8];
        WAIT_LGKM0();
        if (c < 4) {
            if (c < 3) {
#pragma unroll
                for (int j = 0; j < 8; ++j)
                    GLDS16(Wso + (size_t)(c + 1) * 16384 + w1off[j], Wc + (wave * 8 + j) * 512);
            } else {
#pragma unroll
                for (int j = 0; j < 8; ++j)
                    GLDS16(Wso + (size_t)4 * 16384 + w4off[j], Wc + (wave * 8 + j) * 512);
            }
        }
#pragma unroll
        for (int s = 0; s < 8; ++s) {
            accP[c][0] = __builtin_amdgcn_mfma_f32_16x16x32_bf16(af[0][s], bv[s], accP[c][0], 0, 0, 0);
            accP[c][1] = __builtin_amdgcn_mfma_f32_16x16x32_bf16(af[1][s], bv[s], accP[c][1], 0, 0, 0);
        }
    }
#pragma unroll
    for (int c = 0; c < 5; ++c) {
        const int col = c * 64 + wave * 16 + fr;
        if (col >= 288) continue;
        const float cb = cbias[col];
#pragma unroll
        for (int x = 0; x < 2; ++x)
#pragma unroll
            for (int r = 0; r < 4; ++r) {
                const int row = m0 + x * 16 + quad * 4 + r;
                comb[(size_t)row * 288 + col] = accP[c][x][r] + cb;
            }
    }
#undef QCHUNK
#undef QKV_EPI
}

// ---------------------------------------------------------------------------
// MEGAFUSED v2 (R9 proven: 96.5 us): cross_out GEMM + LN1 + FFN + LN3,
// wave-private staging pipeline. 2 barriers per h.
__global__ __launch_bounds__(256) void cross_ffn_kernel(
    const unsigned short* __restrict__ A,     // msoutb M x 256 bf16
    const unsigned short* __restrict__ Wcr,   // 256 x 256 bf16 (cross_out)
    const float* __restrict__ bcr,            // cross_out_b
    const float* __restrict__ resid1,         // t (LN2 out) M x 256 fp32
    const float* __restrict__ g1, const float* __restrict__ b1g,
    float* __restrict__ t2,                   // scratch M x 256 fp32
    const unsigned short* __restrict__ W1,    // 1024 x 256 bf16
    const float* __restrict__ b1,             // 1024
    const unsigned short* __restrict__ W2,    // 256 x 1024 bf16
    const float* __restrict__ b2,             // 256
    const float* __restrict__ g3, const float* __restrict__ b3g,
    float* __restrict__ outf)
{
    __shared__ __align__(16) unsigned short Wc[16384];   // A-stage / W-chunks
    __shared__ __align__(16) unsigned short hid[2304];   // 32 x 72 (padded)
    const int tid  = threadIdx.x;
    const int wave = tid >> 6;
    const int lane = tid & 63;
    const int m0 = blockIdx.x * 32;
    const int fr   = lane & 15;
    const int quad = lane >> 4;
    const int xm   = fr & 7;           // XOR mask for swizzled fragment reads
    float2* red = (float2*)hid;        // 128 float2 = 1 KB (LN reductions)

    // ---- stage A=msout (32 rows) into Wc[0..8192), swizzled ----
#pragma unroll
    for (int j = 0; j < 4; ++j) {
        const int c  = wave * 4 + j;               // 0..15
        const int rA = c * 2 + (lane >> 5);        // row 0..31
        const int k8 = (lane & 31) ^ (rA & 7);
        GLDS16(A + (size_t)(m0 + rA) * 256 + k8 * 8, Wc + c * 512);
    }
    // ---- per-lane swizzled staging offsets for 64-row x 256-k chunks ----
    int w1off[8], w2off[8];
#pragma unroll
    for (int j = 0; j < 8; ++j) {
        const int c  = wave * 8 + j;               // 0..31
        const int n1 = c * 2 + (lane >> 5);        // chunk row 0..63
        const int k1 = (lane & 31) ^ (n1 & 7);
        w1off[j] = n1 * 256 + k1 * 8;              // + chunk*16384
        const int n2 = c * 8 + (lane >> 3);        // W2 row 0..255
        const int k2 = (lane & 7) ^ (n2 & 7);
        w2off[j] = n2 * 1024 + k2 * 8;             // + h*64
    }
    __syncthreads();                   // A visible (cross-wave af reads)
    bf16x8 af[2][8];
#pragma unroll
    for (int i = 0; i < 2; ++i)
#pragma unroll
        for (int s = 0; s < 8; ++s)
            af[i][s] = *(const bf16x8*)&Wc[((i * 16 + fr) * 32 + ((s * 4 + quad) ^ xm)) * 8];
    WAIT_LGKM0();
    __syncthreads();                   // all af reads done before Wcr stage

    // ================= PHASE 1: cross_out GEMM (4 chunks, 0 barriers) =====
#pragma unroll
    for (int j = 0; j < 8; ++j)
        GLDS16(Wcr + w1off[j], Wc + (wave * 8 + j) * 512);
    f32x4 accc[4][2] = {};
    for (int c = 0; c < 4; ++c) {
        WAIT_VM0();                    // Wcr[c] arrived (wave-local)
        bf16x8 bv[8];
#pragma unroll
        for (int s = 0; s < 8; ++s)
            bv[s] = *(const bf16x8*)&Wc[((wave * 16 + fr) * 32 + ((s * 4 + quad) ^ xm)) * 8];
        WAIT_LGKM0();                  // reads done before overwrite
        if (c < 3) {
#pragma unroll
            for (int j = 0; j < 8; ++j)
                GLDS16(Wcr + (size_t)(c + 1) * 16384 + w1off[j], Wc + (wave * 8 + j) * 512);
        }
#pragma unroll
        for (int s = 0; s < 8; ++s) {
            accc[c][0] = __builtin_amdgcn_mfma_f32_16x16x32_bf16(af[0][s], bv[s], accc[c][0], 0, 0, 0);
            accc[c][1] = __builtin_amdgcn_mfma_f32_16x16x32_bf16(af[1][s], bv[s], accc[c][1], 0, 0, 0);
        }
    }

    // ---- LN1: v = accc + bcr + resid1; normalize over 256 cols ----
    float rs[2][4], rq[2][4];
#pragma unroll
    for (int x = 0; x < 2; ++x) {
#pragma unroll
        for (int r = 0; r < 4; ++r) {
            const int row = m0 + x * 16 + quad * 4 + r;
            float s = 0.f, q = 0.f;
#pragma unroll
            for (int c = 0; c < 4; ++c) {
                const int col = c * 64 + wave * 16 + fr;
                float v = accc[c][x][r] + bcr[col] + resid1[(size_t)row * 256 + col];
                accc[c][x][r] = v;
                s += v; q += v * v;
            }
            rs[x][r] = s; rq[x][r] = q;
        }
    }
#pragma unroll
    for (int off = 1; off < 16; off <<= 1) {
#pragma unroll
        for (int x = 0; x < 2; ++x)
#pragma unroll
            for (int r = 0; r < 4; ++r) {
                rs[x][r] += __shfl_xor(rs[x][r], off);
                rq[x][r] += __shfl_xor(rq[x][r], off);
            }
    }
    if ((lane & 15) == 0) {
#pragma unroll
        for (int x = 0; x < 2; ++x)
#pragma unroll
            for (int r = 0; r < 4; ++r)
                red[wave * 32 + x * 16 + quad * 4 + r] = make_float2(rs[x][r], rq[x][r]);
    }
    __syncthreads();   // red visible; all waves' c=3 Wc reads done (handoff safe)
#pragma unroll
    for (int x = 0; x < 2; ++x) {
#pragma unroll
        for (int r = 0; r < 4; ++r) {
            const int rl = x * 16 + quad * 4 + r;
            const float2 t0 = red[rl], t1 = red[32 + rl], t2r = red[64 + rl], t3 = red[96 + rl];
            const float sum = t0.x + t1.x + t2r.x + t3.x;
            const float sq  = t0.y + t1.y + t2r.y + t3.y;
            const float mean = sum * (1.f / 256.f);
            const float var  = sq * (1.f / 256.f) - mean * mean;
            const float inv  = rsqrtf(var + 1e-5f);
            const int row = m0 + rl;
#pragma unroll
            for (int c = 0; c < 4; ++c) {
                const int col = c * 64 + wave * 16 + fr;
                const float val = (accc[c][x][r] - mean) * inv * g1[col] + b1g[col];
                t2[(size_t)row * 256 + col] = val;
                // bf16 handoff into A-stage layout (local row rl, col)
                const int g8 = col >> 3;
                Wc[rl * 256 + ((g8 ^ (rl & 7)) << 3) + (col & 7)] = f2b(val);
            }
        }
    }
    __syncthreads();   // handoff visible; red reads done
    // reload af = LN1 output fragments
#pragma unroll
    for (int i = 0; i < 2; ++i)
#pragma unroll
        for (int s = 0; s < 8; ++s)
            af[i][s] = *(const bf16x8*)&Wc[((i * 16 + fr) * 32 + ((s * 4 + quad) ^ xm)) * 8];
    WAIT_LGKM0();
    __syncthreads();   // all af reloads done before W1[0] stage overwrites

    // ================= PHASE 2: FFN, 2 barriers per h =================
#pragma unroll
    for (int j = 0; j < 8; ++j)
        GLDS16(W1 + w1off[j], Wc + (wave * 8 + j) * 512);
    WAIT_VM0();        // W1[0] arrived (first iter only: exposed)

    f32x4 acc2[2][4] = {};

    for (int h = 0; h < 16; ++h) {
        // ---- gemm1: bv from own W1 region -> regs; restage own region ----
        bf16x8 bv[8];
#pragma unroll
        for (int s = 0; s < 8; ++s)
            bv[s] = *(const bf16x8*)&Wc[((wave * 16 + fr) * 32 + ((s * 4 + quad) ^ xm)) * 8];
        WAIT_LGKM0();
#pragma unroll
        for (int j = 0; j < 8; ++j)
            GLDS16(W2 + (size_t)h * 64 + w2off[j], Wc + (wave * 8 + j) * 512);
        f32x4 acc1[2] = {};
#pragma unroll
        for (int s = 0; s < 8; ++s) {
            acc1[0] = __builtin_amdgcn_mfma_f32_16x16x32_bf16(af[0][s], bv[s], acc1[0], 0, 0, 0);
            acc1[1] = __builtin_amdgcn_mfma_f32_16x16x32_bf16(af[1][s], bv[s], acc1[1], 0, 0, 0);
        }
        const float bias1 = b1[h * 64 + wave * 16 + fr];
#pragma unroll
        for (int i = 0; i < 2; ++i)
#pragma unroll
            for (int r = 0; r < 4; ++r) {
                float v = fmaxf(acc1[i][r] + bias1, 0.f);
                hid[(i * 16 + quad * 4 + r) * 72 + wave * 16 + fr] = f2b(v);
            }
        __syncthreads();   // hid visible; W2[h] drained (covered by gemm1)
        // ---- gemm2: b2v from own W2 region + a2 from hid -> regs ----
#pragma unroll
        for (int s = 0; s < 2; ++s) {
            bf16x8 a2[2], b2v[4];
#pragma unroll
            for (int j2 = 0; j2 < 4; ++j2) {
                const int nb = wave * 64 + j2 * 16 + fr;
                b2v[j2] = *(const bf16x8*)&Wc[(nb * 8 + ((s * 4 + quad) ^ xm)) * 8];
            }
#pragma unroll
            for (int i = 0; i < 2; ++i)
                a2[i] = *(const bf16x8*)&hid[(i * 16 + fr) * 72 + s * 32 + quad * 8];
            if (s == 1) {
                WAIT_LGKM0();          // all Wc/hid reads done
                if (h < 15) {
#pragma unroll
                    for (int j = 0; j < 8; ++j)
                        GLDS16(W1 + (size_t)(h + 1) * 16384 + w1off[j], Wc + (wave * 8 + j) * 512);
                }
            }
#pragma unroll
            for (int i = 0; i < 2; ++i)
#pragma unroll
                for (int j2 = 0; j2 < 4; ++j2)
                    acc2[i][j2] = __builtin_amdgcn_mfma_f32_16x16x32_bf16(
                        a2[i], b2v[j2], acc2[i][j2], 0, 0, 0);
        }
        __syncthreads();   // hid free for next h; W1[h+1] drained (covered)
    }

    // ---- epilogue: v = acc2 + b2 + t2(resid, self-written); LN3 ----
    const int colbase = wave * 64;
#pragma unroll
    for (int x = 0; x < 2; ++x) {
#pragma unroll
        for (int r = 0; r < 4; ++r) {
            const int row = m0 + x * 16 + quad * 4 + r;
            float s = 0.f, q = 0.f;
#pragma unroll
            for (int y = 0; y < 4; ++y) {
                const int col = colbase + y * 16 + fr;
                float v = acc2[x][y][r] + b2[col] + t2[(size_t)row * 256 + col];
                acc2[x][y][r] = v;
                s += v; q += v * v;
            }
            rs[x][r] = s; rq[x][r] = q;
        }
    }
#pragma unroll
    for (int off = 1; off < 16; off <<= 1) {
#pragma unroll
        for (int x = 0; x < 2; ++x)
#pragma unroll
            for (int r = 0; r < 4; ++r) {
                rs[x][r] += __shfl_xor(rs[x][r], off);
                rq[x][r] += __shfl_xor(rq[x][r], off);
            }
    }
    if ((lane & 15) == 0) {
#pragma unroll
        for (int x = 0; x < 2; ++x)
#pragma unroll
            for (int r = 0; r < 4; ++r)
                red[wave * 32 + x * 16 + quad * 4 + r] = make_float2(rs[x][r], rq[x][r]);
    }
    __syncthreads();
#pragma unroll
    for (int x = 0; x < 2; ++x) {
#pragma unroll
        for (int r = 0; r < 4; ++r) {
            const int rl = x * 16 + quad * 4 + r;
            const float2 t0 = red[rl], t1 = red[32 + rl], t2r = red[64 + rl], t3 = red[96 + rl];
            const float sum = t0.x + t1.x + t2r.x + t3.x;
            const float sq  = t0.y + t1.y + t2r.y + t3.y;
            const float mean = sum * (1.f / 256.f);
            const float var  = sq * (1.f / 256.f) - mean * mean;
            const float inv  = rsqrtf(var + 1e-5f);
            const int row = m0 + rl;
#pragma unroll
            for (int y = 0; y < 4; ++y) {
                const int col = colbase + y * 16 + fr;
                outf[(size_t)row * 256 + col] = (acc2[x][y][r] - mean) * inv * g3[col] + b3g[col];
            }
        }
    }
}

// ---------------------------------------------------------------------------
// Merged msprep + deformable sampling (R6 proven).
__global__ __launch_bounds__(256) void msdeform_kernel(
    const unsigned short* __restrict__ value,
    const float* __restrict__ comb,
    unsigned short* __restrict__ out)
{
    const int bid = blockIdx.x;
    const int b   = bid & 7;
    const int lq0 = (bid >> 3) * 4;
    const int r    = threadIdx.x >> 6;
    const int lane = threadIdx.x & 63;
    const int h = lane >> 3;
    const int l = lane & 7;
    const int lq = lq0 + r;
    const int m = lq * 8 + b;

    // ---- load raw offsets + attention logits for (m,h) ----
    const float* offp = comb + (size_t)m * 288 + h * 24;
    const float* awp  = comb + (size_t)m * 288 + 192 + h * 12;
    float off[24], aw[12];
#pragma unroll
    for (int i = 0; i < 6; ++i) *(float4*)&off[i * 4] = ((const float4*)offp)[i];
#pragma unroll
    for (int i = 0; i < 3; ++i) *(float4*)&aw[i * 4] = ((const float4*)awp)[i];

    float mx = aw[0];
#pragma unroll
    for (int i = 1; i < 12; ++i) mx = fmaxf(mx, aw[i]);
    float se = 0.f;
#pragma unroll
    for (int i = 0; i < 12; ++i) { aw[i] = __expf(aw[i] - mx); se += aw[i]; }
    const float inv = 1.f / se;

    const float refx = ((lq % 60) + 0.5f) * (1.f / 60.f);
    const float refy = ((lq / 60) + 0.5f) * (1.f / 60.f);
    const int HW[3] = {60, 30, 15};
    const int ST[3] = {0, 3600, 4500};

    const unsigned short* vbase = value + (size_t)b * LIN * 256 + h * 32 + l * 4;

    float a0 = 0.f, a1 = 0.f, a2 = 0.f, a3 = 0.f;
#pragma unroll
    for (int lev = 0; lev < NLEV; ++lev) {
        const int Wl = HW[lev], s0 = ST[lev];
        const float fWl = (float)Wl;
#pragma unroll
        for (int p = 0; p < NPNT; ++p) {
            const int pt = lev * 4 + p;
            const float ox = off[lev * 8 + p * 2];
            const float oy = off[lev * 8 + p * 2 + 1];
            const float px = refx * fWl + ox - 0.5f;
            const float py = refy * fWl + oy - 0.5f;
            const float x0f = floorf(px), y0f = floorf(py);
            const float fx = px - x0f, fy = py - y0f;
            const int x0 = (int)x0f, y0 = (int)y0f;
            const float aww = aw[pt] * inv;
            const float vx0 = (x0 >= 0 && x0 < Wl) ? 1.f : 0.f;
            const float vx1 = (x0 >= -1 && x0 < Wl - 1) ? 1.f : 0.f;
            const float vy0 = (y0 >= 0 && y0 < Wl) ? 1.f : 0.f;
            const float vy1 = (y0 >= -1 && y0 < Wl - 1) ? 1.f : 0.f;
            const int xc0 = min(max(x0, 0), Wl - 1);
            const int xc1 = min(max(x0 + 1, 0), Wl - 1);
            const int yc0 = min(max(y0, 0), Wl - 1);
            const int yc1 = min(max(y0 + 1, 0), Wl - 1);
            const int sx  = xc1 - xc0;
            const int syW = (yc1 - yc0) * Wl;
            const int i00 = s0 + yc0 * Wl + xc0;
            const float w00 = (1.f - fx) * (1.f - fy) * aww * vx0 * vy0;
            const float w01 = fx * (1.f - fy) * aww * vx1 * vy0;
            const float w10 = (1.f - fx) * fy * aww * vx0 * vy1;
            const float w11 = fx * fy * aww * vx1 * vy1;
            const int i01 = i00 + sx;
            const int i10 = i00 + syW;
            const int i11 = i10 + sx;
            const ushort4 g00 = *(const ushort4*)(vbase + (size_t)i00 * 256);
            const ushort4 g01 = *(const ushort4*)(vbase + (size_t)i01 * 256);
            const ushort4 g10 = *(const ushort4*)(vbase + (size_t)i10 * 256);
            const ushort4 g11 = *(const ushort4*)(vbase + (size_t)i11 * 256);
            a0 += b2f(g00.x) * w00 + b2f(g01.x) * w01 + b2f(g10.x) * w10 + b2f(g11.x) * w11;
            a1 += b2f(g00.y) * w00 + b2f(g01.y) * w01 + b2f(g10.y) * w10 + b2f(g11.y) * w11;
            a2 += b2f(g00.z) * w00 + b2f(g01.z) * w01 + b2f(g10.z) * w10 + b2f(g11.z) * w11;
            a3 += b2f(g00.w) * w00 + b2f(g01.w) * w01 + b2f(g10.w) * w10 + b2f(g11.w) * w11;
        }
    }
    ushort4 o;
    o.x = f2b(a0); o.y = f2b(a1); o.z = f2b(a2); o.w = f2b(a3);
    *(ushort4*)(out + (size_t)m * 256 + h * 32 + l * 4) = o;
}

// ---------------------------------------------------------------------------
extern "C" void kernel_launch(void* const* d_in, const int* in_sizes, int n_in,
                              void* d_out, int out_size, void* d_ws, size_t ws_size,
                              hipStream_t stream)
{
    (void)in_sizes; (void)n_in; (void)out_size; (void)ws_size;
    const float* tgt          = (const float*)d_in[0];   // (LQ,B,D): (lq,b)-major rows
    const float* qp           = (const float*)d_in[1];
    const float* src          = (const float*)d_in[2];
    const float* in_proj_w    = (const float*)d_in[5];
    const float* in_proj_b    = (const float*)d_in[6];
    const float* out_proj_w   = (const float*)d_in[7];
    const float* out_proj_b   = (const float*)d_in[8];
    const float* samp_off_w   = (const float*)d_in[9];
    const float* samp_off_b   = (const float*)d_in[10];
    const float* attn_w_w     = (const float*)d_in[11];
    const float* attn_w_b     = (const float*)d_in[12];
    const float* value_proj_w = (const float*)d_in[13];
    const float* value_proj_b = (const float*)d_in[14];
    const float* cross_out_w  = (const float*)d_in[15];
    const float* cross_out_b  = (const float*)d_in[16];
    const float* ln1_g = (const float*)d_in[17];
    const float* ln1_b = (const float*)d_in[18];
    const float* ln2_g = (const float*)d_in[19];
    const float* ln2_b = (const float*)d_in[20];
    const float* ln3_g = (const float*)d_in[21];
    const float* ln3_b = (const float*)d_in[22];
    const float* ffn_w1 = (const float*)d_in[23];
    const float* ffn_b1 = (const float*)d_in[24];
    const float* ffn_w2 = (const float*)d_in[25];
    const float* ffn_b2 = (const float*)d_in[26];
    float* out = (float*)d_out;

    // ---- fp32 arena (floats) ----
    float* ws    = (float*)d_ws;
    float* t     = ws;                    // LN2 out (residual for LN1)
    float* t2    = ws + 7372800;          // LN1 out scratch (cross_ffn self RW)
    float* comb  = ws + 14745600;         // 28800x288 off+aw (raw, fp32)
    float* qpv   = ws + 23040000;         // 1056 qp-proj + 288 cbias
    float* cbias = qpv + 1056;

    // ---- bf16 arena (ushort), after fp32 arena (byte 92,165,376) ----
    unsigned short* bws    = (unsigned short*)((char*)d_ws + 92165376);
    unsigned short* tgtb   = bws;
    unsigned short* s2     = bws + 7372800;        // valueb+msoutb
    unsigned short* valueb = s2;
    unsigned short* msoutb = s2 + 9676800;
    unsigned short* srcb   = bws + 36864000;
    unsigned short* wtsb   = bws + 46540800;       // 991,232 shorts

    // 1. merged prep (conversions + weight cast + query_pos projections)
    prep_kernel<<<17623, 256, 0, stream>>>(tgt, tgtb, src, srcb,
                                           in_proj_w, out_proj_w, value_proj_w,
                                           cross_out_w, samp_off_w, attn_w_w,
                                           ffn_w1, ffn_w2, wtsb,
                                           qp, samp_off_b, attn_w_b, qpv);
    // 2. value projection (M = 37800)
    gemm_bf16<<<dim3(296, 2), 256, 0, stream>>>(srcb, wtsb + 262144, value_proj_b, nullptr, 0,
                                                nullptr, valueb, BATCH * LIN, 256, 256, 0);
    // 3. QKV gemm + self-attn + out_proj + LN2 + offs projection [gigafused]
    qkv_attn_ln2_offs_kernel<<<900, 256, 0, stream>>>(
        tgtb, wtsb + 0, in_proj_b, qpv,
        wtsb + 196608, out_proj_b, tgt, ln2_g, ln2_b, t,
        wtsb + 393216, cbias, comb);
    // 4. deformable sampling with inline softmax/bilinear setup
    msdeform_kernel<<<7200, 256, 0, stream>>>(valueb, comb, msoutb);
    // 5. out = LN3(t2 + FFN(t2)), t2 = LN1(t + cross_out(msout))  [megafused]
    cross_ffn_kernel<<<900, 256, 0, stream>>>(msoutb, wtsb + 327680, cross_out_b,
                                              t, ln1_g, ln1_b, t2,
                                              wtsb + 466944, ffn_b1,
                                              wtsb + 729088, ffn_b2,
                                              ln3_g, ln3_b, out);
}

// Round 13
// 395.669 us; speedup vs baseline: 1.1602x; 1.0802x over previous
//
#include <hip/hip_runtime.h>
#include <hip/hip_bf16.h>
#include <cstddef>
#include <cstdint>

// Problem constants
#define D_MODEL 256
#define NHEAD   8
#define HDIM    32
#define NLEV    3
#define NPNT    4
#define DFF     1024
#define BATCH   8
#define LQ      3600
#define LIN     4725   // 60*60 + 30*30 + 15*15
#define MROWS   (BATCH*LQ)   // 28800; row order is (lq,b): m = lq*8 + b

typedef short bf16x8 __attribute__((ext_vector_type(8)));
typedef float f32x4  __attribute__((ext_vector_type(4)));

__device__ __forceinline__ unsigned short f2b(float x) {
    unsigned int u = __float_as_uint(x);
    unsigned int r = (u + 0x7fffu + ((u >> 16) & 1u)) >> 16;   // RNE
    return (unsigned short)r;
}
__device__ __forceinline__ float b2f(unsigned short s) {
    return __uint_as_float(((unsigned int)s) << 16);
}
__device__ __forceinline__ bf16x8 cvt8(float4 a, float4 b) {
    bf16x8 v;
    v[0] = (short)f2b(a.x); v[1] = (short)f2b(a.y);
    v[2] = (short)f2b(a.z); v[3] = (short)f2b(a.w);
    v[4] = (short)f2b(b.x); v[5] = (short)f2b(b.y);
    v[6] = (short)f2b(b.z); v[7] = (short)f2b(b.w);
    return v;
}

#define GLDS16(g, l) __builtin_amdgcn_global_load_lds( \
    (const __attribute__((address_space(1))) void*)(g), \
    (__attribute__((address_space(3))) void*)(l), 16, 0, 0)

#define WAIT_VM0()  asm volatile("s_waitcnt vmcnt(0)" ::: "memory")
#define WAIT_LGKM0() asm volatile("s_waitcnt lgkmcnt(0)" ::: "memory")

// ---------------------------------------------------------------------------
// Prep v2: ONLY weight conversion + query_pos projections (tgt/src bf16
// conversion passes eliminated -- consumers now convert inline from fp32).
// [0,968) weight convert (968*1024 = 991232 = WTOT exactly); [968,973) qpv.
#define WTOT 991232
__global__ __launch_bounds__(256) void prep_kernel(
    const float* __restrict__ w_in, const float* __restrict__ w_out,
    const float* __restrict__ w_val, const float* __restrict__ w_cross,
    const float* __restrict__ w_so, const float* __restrict__ w_aw,
    const float* __restrict__ w_f1, const float* __restrict__ w_f2,
    unsigned short* __restrict__ wdst,
    const float* __restrict__ qp, const float* __restrict__ so_b,
    const float* __restrict__ aw_b, float* __restrict__ qpv)
{
    const int bid = blockIdx.x;
    const int tid = threadIdx.x;
    if (bid < 968) {
        int idx = (bid * 256 + tid) * 4;
        const float* src; int off;
        if      (idx < 196608) { src = w_in;    off = idx; }
        else if (idx < 262144) { src = w_out;   off = idx - 196608; }
        else if (idx < 327680) { src = w_val;   off = idx - 262144; }
        else if (idx < 393216) { src = w_cross; off = idx - 327680; }
        else if (idx < 442368) { src = w_so;    off = idx - 393216; }
        else if (idx < 466944) { src = w_aw;    off = idx - 442368; }
        else if (idx < 729088) { src = w_f1;    off = idx - 466944; }
        else                   { src = w_f2;    off = idx - 729088; }
        float4 v = *(const float4*)(src + off);
        ushort4 o; o.x = f2b(v.x); o.y = f2b(v.y); o.z = f2b(v.z); o.w = f2b(v.w);
        *(ushort4*)(wdst + idx) = o;
    } else {
        int o = (bid - 968) * 256 + tid;
        if (o >= 768 + 192 + 96) return;
        const float* wrow;
        if (o < 768)       wrow = w_in + (size_t)o * D_MODEL;
        else if (o < 960)  wrow = w_so + (size_t)(o - 768) * D_MODEL;
        else               wrow = w_aw + (size_t)(o - 960) * D_MODEL;
        float acc = 0.f;
        for (int d = 0; d < D_MODEL; ++d) acc += qp[d] * wrow[d];
        qpv[o] = acc;
        if (o >= 768) {
            float bias = (o < 960) ? so_b[o - 768] : aw_b[o - 960];
            qpv[1056 + (o - 768)] = acc + bias;
        }
    }
}

// ---------------------------------------------------------------------------
// bf16 MFMA GEMM with FP32 A input (value projection): A staged via
// reg-load (2x float4, coalesced 32 B/lane) + f2b + ds_write_b128 into the
// proven As layout; B stays global_load_lds. Conversion = identical RNE at
// the identical point as the old prep pass -> bit-identical numerics.
__global__ __launch_bounds__(256) void gemm_af32(
    const float* __restrict__ A,              // M x K fp32
    const unsigned short* __restrict__ W,
    const float* __restrict__ bias,
    unsigned short* __restrict__ Cb,
    int M, int N, int K)
{
    __shared__ __align__(16) unsigned short As[2 * 128 * 32];   // 16 KB
    __shared__ __align__(16) unsigned short Bs[2 * 128 * 32];   // 16 KB
    const int tid  = threadIdx.x;
    const int wave = tid >> 6;
    const int lane = tid & 63;
    const int m0 = blockIdx.x * 128;
    const int n0 = blockIdx.y * 128;

    const int lr  = lane >> 2;
    const int lc8 = (lane & 3) * 8;
    int ar0 = m0 + wave * 32 + lr;      if (ar0 > M - 1) ar0 = M - 1;
    int ar1 = m0 + wave * 32 + 16 + lr; if (ar1 > M - 1) ar1 = M - 1;
    int br0 = n0 + wave * 32 + lr;      if (br0 > N - 1) br0 = N - 1;
    int br1 = n0 + wave * 32 + 16 + lr; if (br1 > N - 1) br1 = N - 1;
    const float* pa0 = A + (size_t)ar0 * K + lc8;
    const float* pa1 = A + (size_t)ar1 * K + lc8;
    const unsigned short* pb0 = W + (size_t)br0 * K + lc8;
    const unsigned short* pb1 = W + (size_t)br1 * K + lc8;
    unsigned short* lb0 = Bs + wave * 1024;
    unsigned short* lb1 = Bs + wave * 1024 + 512;
    unsigned short* sa  = As + wave * 1024 + lane * 8;

    const int wm = (wave >> 1) * 64;
    const int wn = (wave & 1) * 64;
    const int fr = lane & 15;
    const int fk = (lane >> 4) * 8;

    f32x4 acc[4][4] = {};

    for (int k0 = 0; k0 < K; k0 += 64) {
        float4 a00 = *(const float4*)(pa0);
        float4 a01 = *(const float4*)(pa0 + 4);
        float4 a02 = *(const float4*)(pa0 + 32);
        float4 a03 = *(const float4*)(pa0 + 36);
        float4 a10 = *(const float4*)(pa1);
        float4 a11 = *(const float4*)(pa1 + 4);
        float4 a12 = *(const float4*)(pa1 + 32);
        float4 a13 = *(const float4*)(pa1 + 36);
        GLDS16(pb0, lb0); GLDS16(pb0 + 32, lb0 + 4096);
        GLDS16(pb1, lb1); GLDS16(pb1 + 32, lb1 + 4096);
        pa0 += 64; pa1 += 64; pb0 += 64; pb1 += 64;
        *(bf16x8*)(sa)        = cvt8(a00, a01);   // rows wave*32+lr,  p0
        *(bf16x8*)(sa + 4096) = cvt8(a02, a03);   // p1 (cols +32)
        *(bf16x8*)(sa + 512)  = cvt8(a10, a11);   // rows +16, p0
        *(bf16x8*)(sa + 4608) = cvt8(a12, a13);   // rows +16, p1
        __syncthreads();
#pragma unroll
        for (int p = 0; p < 2; ++p) {
            bf16x8 af[4], bfv[4];
#pragma unroll
            for (int i = 0; i < 4; ++i)
                af[i] = *(const bf16x8*)&As[p * 4096 + (wm + i * 16 + fr) * 32 + fk];
#pragma unroll
            for (int j = 0; j < 4; ++j)
                bfv[j] = *(const bf16x8*)&Bs[p * 4096 + (wn + j * 16 + fr) * 32 + fk];
#pragma unroll
            for (int i = 0; i < 4; ++i)
#pragma unroll
                for (int j = 0; j < 4; ++j)
                    acc[i][j] = __builtin_amdgcn_mfma_f32_16x16x32_bf16(
                        af[i], bfv[j], acc[i][j], 0, 0, 0);
        }
        __syncthreads();
    }

    const int quad = lane >> 4;
#pragma unroll
    for (int j = 0; j < 4; ++j) {
        const int col = n0 + wn + j * 16 + fr;
        if (col >= N) continue;
        const float bv = bias ? bias[col] : 0.f;
#pragma unroll
        for (int i = 0; i < 4; ++i) {
#pragma unroll
            for (int r = 0; r < 4; ++r) {
                const int row = m0 + wm + i * 16 + quad * 4 + r;
                if (row >= M) continue;
                Cb[(size_t)row * N + col] = f2b(acc[i][j][r] + bv);
            }
        }
    }
}

// ---------------------------------------------------------------------------
// GIGAFUSED (R12 proven): QKV GEMM + self-attention + out_proj + LN2 +
// offs projection. v2: A-tile converted inline from fp32 tgt (reg-stage
// f2b + ds_write into the same swizzled Wc layout) -- tgtb eliminated.
__global__ __launch_bounds__(256) void qkv_attn_ln2_offs_kernel(
    const float* __restrict__ Atgt,           // tgt M x 256 fp32 (A + resid)
    const unsigned short* __restrict__ Win,   // 768 x 256 bf16 (in_proj)
    const float* __restrict__ bin,            // in_proj_b (768)
    const float* __restrict__ qpv,            // qp @ Win rows (768)
    const unsigned short* __restrict__ Wo,    // 256 x 256 bf16 (out_proj)
    const float* __restrict__ bo,
    const float* __restrict__ g2, const float* __restrict__ b2g,
    float* __restrict__ tout,                 // t M x 256 fp32
    const unsigned short* __restrict__ Wso,   // 288 x 256 bf16 (so+aw)
    const float* __restrict__ cbias,          // 288
    float* __restrict__ comb)                 // M x 288 fp32
{
    __shared__ __align__(16) unsigned short Wc[16384];   // 32 KB staging
    __shared__ __align__(16) unsigned short qt[32 * 264];// Q tile, 16.5 KB
    __shared__ __align__(16) unsigned short kvt[32 * 264];// K then V, 16.5 KB
    __shared__ float2 red[128];                          // LN reduction
    const int tid  = threadIdx.x;
    const int wave = tid >> 6;
    const int lane = tid & 63;
    const int m0 = blockIdx.x * 32;
    const int fr   = lane & 15;
    const int quad = lane >> 4;
    const int xm   = fr & 7;

    // ---- stage A=tgt fp32 (32 rows) -> bf16 into Wc, swizzled ----
#pragma unroll
    for (int j = 0; j < 4; ++j) {
        const int c  = wave * 4 + j;
        const int rA = c * 2 + (lane >> 5);
        const int k8 = (lane & 31) ^ (rA & 7);
        const float* p = Atgt + (size_t)(m0 + rA) * 256 + k8 * 8;
        float4 a = *(const float4*)p;
        float4 b = *(const float4*)(p + 4);
        *(bf16x8*)&Wc[c * 512 + lane * 8] = cvt8(a, b);
    }
    // ---- per-lane swizzled staging offsets (64-row x 256-k chunks) ----
    int w1off[8], w4off[8];
#pragma unroll
    for (int j = 0; j < 8; ++j) {
        const int c  = wave * 8 + j;
        const int n1 = c * 2 + (lane >> 5);
        const int k1 = (lane & 31) ^ (n1 & 7);
        w1off[j] = n1 * 256 + k1 * 8;
        const int n4 = (n1 < 32) ? n1 : 31;        // clamp for Wso chunk 4
        const int k4 = (lane & 31) ^ (n4 & 7);
        w4off[j] = n4 * 256 + k4 * 8;
    }
    __syncthreads();                   // A visible
    bf16x8 af[2][8];
#pragma unroll
    for (int i = 0; i < 2; ++i)
#pragma unroll
        for (int s = 0; s < 8; ++s)
            af[i][s] = *(const bf16x8*)&Wc[((i * 16 + fr) * 32 + ((s * 4 + quad) ^ xm)) * 8];
    WAIT_LGKM0();
    __syncthreads();                   // af reads done before staging

    // ============ QKV GEMM: 3 passes x 4 chunks, wave-private ============
#pragma unroll
    for (int j = 0; j < 8; ++j)
        GLDS16(Win + w1off[j], Wc + (wave * 8 + j) * 512);

#define QCHUNK(CG, PF) {                                                     \
        WAIT_VM0();                                                          \
        bf16x8 bv[8];                                                        \
        _Pragma("unroll")                                                    \
        for (int s = 0; s < 8; ++s)                                          \
            bv[s] = *(const bf16x8*)&Wc[((wave * 16 + fr) * 32 + ((s * 4 + quad) ^ xm)) * 8]; \
        WAIT_LGKM0();                                                        \
        if (PF) {                                                            \
            _Pragma("unroll")                                                \
            for (int j = 0; j < 8; ++j)                                      \
                GLDS16(Win + (size_t)((CG) + 1) * 16384 + w1off[j], Wc + (wave * 8 + j) * 512); \
        }                                                                    \
        _Pragma("unroll")                                                    \
        for (int s = 0; s < 8; ++s) {                                        \
            acc[(CG) & 3][0] = __builtin_amdgcn_mfma_f32_16x16x32_bf16(af[0][s], bv[s], acc[(CG) & 3][0], 0, 0, 0); \
            acc[(CG) & 3][1] = __builtin_amdgcn_mfma_f32_16x16x32_bf16(af[1][s], bv[s], acc[(CG) & 3][1], 0, 0, 0); \
        }                                                                    \
    }

#define QKV_EPI(P, TILE) {                                                   \
        _Pragma("unroll")                                                    \
        for (int x = 0; x < 2; ++x)                                          \
        _Pragma("unroll")                                                    \
        for (int r = 0; r < 4; ++r) {                                        \
            const int rl = x * 16 + quad * 4 + r;                            \
            _Pragma("unroll")                                                \
            for (int c = 0; c < 4; ++c) {                                    \
                const int col  = c * 64 + wave * 16 + fr;                    \
                const int gcol = (P) * 256 + col;                            \
                float v = acc[c][x][r] + bin[gcol];                          \
                if ((P) < 2) v += qpv[gcol];                                 \
                (TILE)[rl * 264 + col] = f2b(v);                             \
            }                                                                \
        }                                                                    \
    }

    {
        f32x4 acc[4][2] = {};
#pragma unroll
        for (int c = 0; c < 4; ++c) QCHUNK(c, 1)
        QKV_EPI(0, qt)
    }
    {
        f32x4 acc[4][2] = {};
#pragma unroll
        for (int c = 4; c < 8; ++c) QCHUNK(c, 1)
        QKV_EPI(1, kvt)
    }
    __syncthreads();                   // qt + kt visible to all waves

    // ---- scores + softmax: thread (g=wave, h, si) owns one score row ----
    const int g  = wave;
    const int ah = lane >> 3;
    const int si = lane & 7;
    float p[8];
    {
        float qreg[32];
#pragma unroll
        for (int d = 0; d < 32; ++d)
            qreg[d] = b2f(qt[(g * 8 + si) * 264 + ah * 32 + d]);
        float mx = -1e30f;
#pragma unroll
        for (int ti = 0; ti < 8; ++ti) {
            float a = 0.f;
#pragma unroll
            for (int d = 0; d < 32; ++d)
                a += qreg[d] * b2f(kvt[(g * 8 + ti) * 264 + ah * 32 + d]);
            a *= 0.17677669529663687f;
            p[ti] = a;
            mx = fmaxf(mx, a);
        }
        float sum = 0.f;
#pragma unroll
        for (int ti = 0; ti < 8; ++ti) { p[ti] = expf(p[ti] - mx); sum += p[ti]; }
        const float inv = 1.f / sum;
#pragma unroll
        for (int ti = 0; ti < 8; ++ti) p[ti] *= inv;
    }
    __syncthreads();                   // kt reads done before V overwrites kvt

    {
        f32x4 acc[4][2] = {};
#pragma unroll
        for (int c = 8; c < 12; ++c) QCHUNK(c, (c < 11))
        QKV_EPI(2, kvt)
    }
    __syncthreads();                   // vt visible; all Wc GEMM reads done

    // ---- PV -> ctx, written directly into Wc A-stage handoff layout ----
    {
        const int rl = g * 8 + si;
#pragma unroll
        for (int d = 0; d < 32; ++d) {
            float a = 0.f;
#pragma unroll
            for (int ti = 0; ti < 8; ++ti)
                a += p[ti] * b2f(kvt[(g * 8 + ti) * 264 + ah * 32 + d]);
            const int col = ah * 32 + d;
            Wc[rl * 256 + (((col >> 3) ^ (rl & 7)) << 3) + (col & 7)] = f2b(a);
        }
    }
    __syncthreads();                   // handoff visible
    // reload af = ctx fragments
#pragma unroll
    for (int i = 0; i < 2; ++i)
#pragma unroll
        for (int s = 0; s < 8; ++s)
            af[i][s] = *(const bf16x8*)&Wc[((i * 16 + fr) * 32 + ((s * 4 + quad) ^ xm)) * 8];
    WAIT_LGKM0();
    __syncthreads();                   // af reloads done before Wo staging

    // ================= out_proj GEMM (4 chunks) + LN2 =================
#pragma unroll
    for (int j = 0; j < 8; ++j)
        GLDS16(Wo + w1off[j], Wc + (wave * 8 + j) * 512);
    f32x4 accc[4][2] = {};
    for (int c = 0; c < 4; ++c) {
        WAIT_VM0();
        bf16x8 bv[8];
#pragma unroll
        for (int s = 0; s < 8; ++s)
            bv[s] = *(const bf16x8*)&Wc[((wave * 16 + fr) * 32 + ((s * 4 + quad) ^ xm)) * 8];
        WAIT_LGKM0();
        if (c < 3) {
#pragma unroll
            for (int j = 0; j < 8; ++j)
                GLDS16(Wo + (size_t)(c + 1) * 16384 + w1off[j], Wc + (wave * 8 + j) * 512);
        }
#pragma unroll
        for (int s = 0; s < 8; ++s) {
            accc[c][0] = __builtin_amdgcn_mfma_f32_16x16x32_bf16(af[0][s], bv[s], accc[c][0], 0, 0, 0);
            accc[c][1] = __builtin_amdgcn_mfma_f32_16x16x32_bf16(af[1][s], bv[s], accc[c][1], 0, 0, 0);
        }
    }
    float rs[2][4], rq[2][4];
#pragma unroll
    for (int x = 0; x < 2; ++x) {
#pragma unroll
        for (int r = 0; r < 4; ++r) {
            const int row = m0 + x * 16 + quad * 4 + r;
            float s = 0.f, q = 0.f;
#pragma unroll
            for (int c = 0; c < 4; ++c) {
                const int col = c * 64 + wave * 16 + fr;
                float v = accc[c][x][r] + bo[col] + Atgt[(size_t)row * 256 + col];
                accc[c][x][r] = v;
                s += v; q += v * v;
            }
            rs[x][r] = s; rq[x][r] = q;
        }
    }
#pragma unroll
    for (int off = 1; off < 16; off <<= 1) {
#pragma unroll
        for (int x = 0; x < 2; ++x)
#pragma unroll
            for (int r = 0; r < 4; ++r) {
                rs[x][r] += __shfl_xor(rs[x][r], off);
                rq[x][r] += __shfl_xor(rq[x][r], off);
            }
    }
    if ((lane & 15) == 0) {
#pragma unroll
        for (int x = 0; x < 2; ++x)
#pragma unroll
            for (int r = 0; r < 4; ++r)
                red[wave * 32 + x * 16 + quad * 4 + r] = make_float2(rs[x][r], rq[x][r]);
    }
    __syncthreads();   // red visible; all waves' c=3 Wc reads done
#pragma unroll
    for (int x = 0; x < 2; ++x) {
#pragma unroll
        for (int r = 0; r < 4; ++r) {
            const int rl = x * 16 + quad * 4 + r;
            const float2 t0 = red[rl], t1 = red[32 + rl], t2r = red[64 + rl], t3 = red[96 + rl];
            const float sum = t0.x + t1.x + t2r.x + t3.x;
            const float sq  = t0.y + t1.y + t2r.y + t3.y;
            const float mean = sum * (1.f / 256.f);
            const float var  = sq * (1.f / 256.f) - mean * mean;
            const float inv  = rsqrtf(var + 1e-5f);
            const int row = m0 + rl;
#pragma unroll
            for (int c = 0; c < 4; ++c) {
                const int col = c * 64 + wave * 16 + fr;
                const float val = (accc[c][x][r] - mean) * inv * g2[col] + b2g[col];
                tout[(size_t)row * 256 + col] = val;
                const int g8 = col >> 3;
                Wc[rl * 256 + ((g8 ^ (rl & 7)) << 3) + (col & 7)] = f2b(val);
            }
        }
    }
    __syncthreads();   // handoff visible
#pragma unroll
    for (int i = 0; i < 2; ++i)
#pragma unroll
        for (int s = 0; s < 8; ++s)
            af[i][s] = *(const bf16x8*)&Wc[((i * 16 + fr) * 32 + ((s * 4 + quad) ^ xm)) * 8];
    WAIT_LGKM0();
    __syncthreads();   // af reloads done before Wso staging

    // ================= offs GEMM (5 chunks, clamped tail) =================
#pragma unroll
    for (int j = 0; j < 8; ++j)
        GLDS16(Wso + w1off[j], Wc + (wave * 8 + j) * 512);
    f32x4 accP[5][2] = {};
    for (int c = 0; c < 5; ++c) {
        WAIT_VM0();
        bf16x8 bv[8];
#pragma unroll
        for (int s = 0; s < 8; ++s)
            bv[s] = *(const bf16x8*)&Wc[((wave * 16 + fr) * 32 + ((s * 4 + quad) ^ xm)) * 8];
        WAIT_LGKM0();
        if (c < 4) {
            if (c < 3) {
#pragma unroll
                for (int j = 0; j < 8; ++j)
                    GLDS16(Wso + (size_t)(c + 1) * 16384 + w1off[j], Wc + (wave * 8 + j) * 512);
            } else {
#pragma unroll
                for (int j = 0; j < 8; ++j)
                    GLDS16(Wso + (size_t)4 * 16384 + w4off[j], Wc + (wave * 8 + j) * 512);
            }
        }
#pragma unroll
        for (int s = 0; s < 8; ++s) {
            accP[c][0] = __builtin_amdgcn_mfma_f32_16x16x32_bf16(af[0][s], bv[s], accP[c][0], 0, 0, 0);
            accP[c][1] = __builtin_amdgcn_mfma_f32_16x16x32_bf16(af[1][s], bv[s], accP[c][1], 0, 0, 0);
        }
    }
#pragma unroll
    for (int c = 0; c < 5; ++c) {
        const int col = c * 64 + wave * 16 + fr;
        if (col >= 288) continue;
        const float cb = cbias[col];
#pragma unroll
        for (int x = 0; x < 2; ++x)
#pragma unroll
            for (int r = 0; r < 4; ++r) {
                const int row = m0 + x * 16 + quad * 4 + r;
                comb[(size_t)row * 288 + col] = accP[c][x][r] + cb;
            }
    }
#undef QCHUNK
#undef QKV_EPI
}

// ---------------------------------------------------------------------------
// MEGAFUSED v2 (R9 proven): cross_out GEMM + LN1 + FFN + LN3,
// wave-private staging pipeline. 2 barriers per h.
__global__ __launch_bounds__(256) void cross_ffn_kernel(
    const unsigned short* __restrict__ A,     // msoutb M x 256 bf16
    const unsigned short* __restrict__ Wcr,   // 256 x 256 bf16 (cross_out)
    const float* __restrict__ bcr,            // cross_out_b
    const float* __restrict__ resid1,         // t (LN2 out) M x 256 fp32
    const float* __restrict__ g1, const float* __restrict__ b1g,
    float* __restrict__ t2,                   // scratch M x 256 fp32
    const unsigned short* __restrict__ W1,    // 1024 x 256 bf16
    const float* __restrict__ b1,             // 1024
    const unsigned short* __restrict__ W2,    // 256 x 1024 bf16
    const float* __restrict__ b2,             // 256
    const float* __restrict__ g3, const float* __restrict__ b3g,
    float* __restrict__ outf)
{
    __shared__ __align__(16) unsigned short Wc[16384];   // A-stage / W-chunks
    __shared__ __align__(16) unsigned short hid[2304];   // 32 x 72 (padded)
    const int tid  = threadIdx.x;
    const int wave = tid >> 6;
    const int lane = tid & 63;
    const int m0 = blockIdx.x * 32;
    const int fr   = lane & 15;
    const int quad = lane >> 4;
    const int xm   = fr & 7;           // XOR mask for swizzled fragment reads
    float2* red = (float2*)hid;        // 128 float2 = 1 KB (LN reductions)

    // ---- stage A=msout (32 rows) into Wc[0..8192), swizzled ----
#pragma unroll
    for (int j = 0; j < 4; ++j) {
        const int c  = wave * 4 + j;               // 0..15
        const int rA = c * 2 + (lane >> 5);        // row 0..31
        const int k8 = (lane & 31) ^ (rA & 7);
        GLDS16(A + (size_t)(m0 + rA) * 256 + k8 * 8, Wc + c * 512);
    }
    // ---- per-lane swizzled staging offsets for 64-row x 256-k chunks ----
    int w1off[8], w2off[8];
#pragma unroll
    for (int j = 0; j < 8; ++j) {
        const int c  = wave * 8 + j;               // 0..31
        const int n1 = c * 2 + (lane >> 5);        // chunk row 0..63
        const int k1 = (lane & 31) ^ (n1 & 7);
        w1off[j] = n1 * 256 + k1 * 8;              // + chunk*16384
        const int n2 = c * 8 + (lane >> 3);        // W2 row 0..255
        const int k2 = (lane & 7) ^ (n2 & 7);
        w2off[j] = n2 * 1024 + k2 * 8;             // + h*64
    }
    __syncthreads();                   // A visible (cross-wave af reads)
    bf16x8 af[2][8];
#pragma unroll
    for (int i = 0; i < 2; ++i)
#pragma unroll
        for (int s = 0; s < 8; ++s)
            af[i][s] = *(const bf16x8*)&Wc[((i * 16 + fr) * 32 + ((s * 4 + quad) ^ xm)) * 8];
    WAIT_LGKM0();
    __syncthreads();                   // all af reads done before Wcr stage

    // ================= PHASE 1: cross_out GEMM (4 chunks, 0 barriers) =====
#pragma unroll
    for (int j = 0; j < 8; ++j)
        GLDS16(Wcr + w1off[j], Wc + (wave * 8 + j) * 512);
    f32x4 accc[4][2] = {};
    for (int c = 0; c < 4; ++c) {
        WAIT_VM0();                    // Wcr[c] arrived (wave-local)
        bf16x8 bv[8];
#pragma unroll
        for (int s = 0; s < 8; ++s)
            bv[s] = *(const bf16x8*)&Wc[((wave * 16 + fr) * 32 + ((s * 4 + quad) ^ xm)) * 8];
        WAIT_LGKM0();                  // reads done before overwrite
        if (c < 3) {
#pragma unroll
            for (int j = 0; j < 8; ++j)
                GLDS16(Wcr + (size_t)(c + 1) * 16384 + w1off[j], Wc + (wave * 8 + j) * 512);
        }
#pragma unroll
        for (int s = 0; s < 8; ++s) {
            accc[c][0] = __builtin_amdgcn_mfma_f32_16x16x32_bf16(af[0][s], bv[s], accc[c][0], 0, 0, 0);
            accc[c][1] = __builtin_amdgcn_mfma_f32_16x16x32_bf16(af[1][s], bv[s], accc[c][1], 0, 0, 0);
        }
    }

    // ---- LN1: v = accc + bcr + resid1; normalize over 256 cols ----
    float rs[2][4], rq[2][4];
#pragma unroll
    for (int x = 0; x < 2; ++x) {
#pragma unroll
        for (int r = 0; r < 4; ++r) {
            const int row = m0 + x * 16 + quad * 4 + r;
            float s = 0.f, q = 0.f;
#pragma unroll
            for (int c = 0; c < 4; ++c) {
                const int col = c * 64 + wave * 16 + fr;
                float v = accc[c][x][r] + bcr[col] + resid1[(size_t)row * 256 + col];
                accc[c][x][r] = v;
                s += v; q += v * v;
            }
            rs[x][r] = s; rq[x][r] = q;
        }
    }
#pragma unroll
    for (int off = 1; off < 16; off <<= 1) {
#pragma unroll
        for (int x = 0; x < 2; ++x)
#pragma unroll
            for (int r = 0; r < 4; ++r) {
                rs[x][r] += __shfl_xor(rs[x][r], off);
                rq[x][r] += __shfl_xor(rq[x][r], off);
            }
    }
    if ((lane & 15) == 0) {
#pragma unroll
        for (int x = 0; x < 2; ++x)
#pragma unroll
            for (int r = 0; r < 4; ++r)
                red[wave * 32 + x * 16 + quad * 4 + r] = make_float2(rs[x][r], rq[x][r]);
    }
    __syncthreads();   // red visible; all waves' c=3 Wc reads done (handoff safe)
#pragma unroll
    for (int x = 0; x < 2; ++x) {
#pragma unroll
        for (int r = 0; r < 4; ++r) {
            const int rl = x * 16 + quad * 4 + r;
            const float2 t0 = red[rl], t1 = red[32 + rl], t2r = red[64 + rl], t3 = red[96 + rl];
            const float sum = t0.x + t1.x + t2r.x + t3.x;
            const float sq  = t0.y + t1.y + t2r.y + t3.y;
            const float mean = sum * (1.f / 256.f);
            const float var  = sq * (1.f / 256.f) - mean * mean;
            const float inv  = rsqrtf(var + 1e-5f);
            const int row = m0 + rl;
#pragma unroll
            for (int c = 0; c < 4; ++c) {
                const int col = c * 64 + wave * 16 + fr;
                const float val = (accc[c][x][r] - mean) * inv * g1[col] + b1g[col];
                t2[(size_t)row * 256 + col] = val;
                // bf16 handoff into A-stage layout (local row rl, col)
                const int g8 = col >> 3;
                Wc[rl * 256 + ((g8 ^ (rl & 7)) << 3) + (col & 7)] = f2b(val);
            }
        }
    }
    __syncthreads();   // handoff visible; red reads done
    // reload af = LN1 output fragments
#pragma unroll
    for (int i = 0; i < 2; ++i)
#pragma unroll
        for (int s = 0; s < 8; ++s)
            af[i][s] = *(const bf16x8*)&Wc[((i * 16 + fr) * 32 + ((s * 4 + quad) ^ xm)) * 8];
    WAIT_LGKM0();
    __syncthreads();   // all af reloads done before W1[0] stage overwrites

    // ================= PHASE 2: FFN, 2 barriers per h =================
#pragma unroll
    for (int j = 0; j < 8; ++j)
        GLDS16(W1 + w1off[j], Wc + (wave * 8 + j) * 512);
    WAIT_VM0();        // W1[0] arrived (first iter only: exposed)

    f32x4 acc2[2][4] = {};

    for (int h = 0; h < 16; ++h) {
        // ---- gemm1: bv from own W1 region -> regs; restage own region ----
        bf16x8 bv[8];
#pragma unroll
        for (int s = 0; s < 8; ++s)
            bv[s] = *(const bf16x8*)&Wc[((wave * 16 + fr) * 32 + ((s * 4 + quad) ^ xm)) * 8];
        WAIT_LGKM0();
#pragma unroll
        for (int j = 0; j < 8; ++j)
            GLDS16(W2 + (size_t)h * 64 + w2off[j], Wc + (wave * 8 + j) * 512);
        f32x4 acc1[2] = {};
#pragma unroll
        for (int s = 0; s < 8; ++s) {
            acc1[0] = __builtin_amdgcn_mfma_f32_16x16x32_bf16(af[0][s], bv[s], acc1[0], 0, 0, 0);
            acc1[1] = __builtin_amdgcn_mfma_f32_16x16x32_bf16(af[1][s], bv[s], acc1[1], 0, 0, 0);
        }
        const float bias1 = b1[h * 64 + wave * 16 + fr];
#pragma unroll
        for (int i = 0; i < 2; ++i)
#pragma unroll
            for (int r = 0; r < 4; ++r) {
                float v = fmaxf(acc1[i][r] + bias1, 0.f);
                hid[(i * 16 + quad * 4 + r) * 72 + wave * 16 + fr] = f2b(v);
            }
        __syncthreads();   // hid visible; W2[h] drained (covered by gemm1)
        // ---- gemm2: b2v from own W2 region + a2 from hid -> regs ----
#pragma unroll
        for (int s = 0; s < 2; ++s) {
            bf16x8 a2[2], b2v[4];
#pragma unroll
            for (int j2 = 0; j2 < 4; ++j2) {
                const int nb = wave * 64 + j2 * 16 + fr;
                b2v[j2] = *(const bf16x8*)&Wc[(nb * 8 + ((s * 4 + quad) ^ xm)) * 8];
            }
#pragma unroll
            for (int i = 0; i < 2; ++i)
                a2[i] = *(const bf16x8*)&hid[(i * 16 + fr) * 72 + s * 32 + quad * 8];
            if (s == 1) {
                WAIT_LGKM0();          // all Wc/hid reads done
                if (h < 15) {
#pragma unroll
                    for (int j = 0; j < 8; ++j)
                        GLDS16(W1 + (size_t)(h + 1) * 16384 + w1off[j], Wc + (wave * 8 + j) * 512);
                }
            }
#pragma unroll
            for (int i = 0; i < 2; ++i)
#pragma unroll
                for (int j2 = 0; j2 < 4; ++j2)
                    acc2[i][j2] = __builtin_amdgcn_mfma_f32_16x16x32_bf16(
                        a2[i], b2v[j2], acc2[i][j2], 0, 0, 0);
        }
        __syncthreads();   // hid free for next h; W1[h+1] drained (covered)
    }

    // ---- epilogue: v = acc2 + b2 + t2(resid, self-written); LN3 ----
    const int colbase = wave * 64;
#pragma unroll
    for (int x = 0; x < 2; ++x) {
#pragma unroll
        for (int r = 0; r < 4; ++r) {
            const int row = m0 + x * 16 + quad * 4 + r;
            float s = 0.f, q = 0.f;
#pragma unroll
            for (int y = 0; y < 4; ++y) {
                const int col = colbase + y * 16 + fr;
                float v = acc2[x][y][r] + b2[col] + t2[(size_t)row * 256 + col];
                acc2[x][y][r] = v;
                s += v; q += v * v;
            }
            rs[x][r] = s; rq[x][r] = q;
        }
    }
#pragma unroll
    for (int off = 1; off < 16; off <<= 1) {
#pragma unroll
        for (int x = 0; x < 2; ++x)
#pragma unroll
            for (int r = 0; r < 4; ++r) {
                rs[x][r] += __shfl_xor(rs[x][r], off);
                rq[x][r] += __shfl_xor(rq[x][r], off);
            }
    }
    if ((lane & 15) == 0) {
#pragma unroll
        for (int x = 0; x < 2; ++x)
#pragma unroll
            for (int r = 0; r < 4; ++r)
                red[wave * 32 + x * 16 + quad * 4 + r] = make_float2(rs[x][r], rq[x][r]);
    }
    __syncthreads();
#pragma unroll
    for (int x = 0; x < 2; ++x) {
#pragma unroll
        for (int r = 0; r < 4; ++r) {
            const int rl = x * 16 + quad * 4 + r;
            const float2 t0 = red[rl], t1 = red[32 + rl], t2r = red[64 + rl], t3 = red[96 + rl];
            const float sum = t0.x + t1.x + t2r.x + t3.x;
            const float sq  = t0.y + t1.y + t2r.y + t3.y;
            const float mean = sum * (1.f / 256.f);
            const float var  = sq * (1.f / 256.f) - mean * mean;
            const float inv  = rsqrtf(var + 1e-5f);
            const int row = m0 + rl;
#pragma unroll
            for (int y = 0; y < 4; ++y) {
                const int col = colbase + y * 16 + fr;
                outf[(size_t)row * 256 + col] = (acc2[x][y][r] - mean) * inv * g3[col] + b3g[col];
            }
        }
    }
}

// ---------------------------------------------------------------------------
// Merged msprep + deformable sampling (R6 proven).
__global__ __launch_bounds__(256) void msdeform_kernel(
    const unsigned short* __restrict__ value,
    const float* __restrict__ comb,
    unsigned short* __restrict__ out)
{
    const int bid = blockIdx.x;
    const int b   = bid & 7;
    const int lq0 = (bid >> 3) * 4;
    const int r    = threadIdx.x >> 6;
    const int lane = threadIdx.x & 63;
    const int h = lane >> 3;
    const int l = lane & 7;
    const int lq = lq0 + r;
    const int m = lq * 8 + b;

    // ---- load raw offsets + attention logits for (m,h) ----
    const float* offp = comb + (size_t)m * 288 + h * 24;
    const float* awp  = comb + (size_t)m * 288 + 192 + h * 12;
    float off[24], aw[12];
#pragma unroll
    for (int i = 0; i < 6; ++i) *(float4*)&off[i * 4] = ((const float4*)offp)[i];
#pragma unroll
    for (int i = 0; i < 3; ++i) *(float4*)&aw[i * 4] = ((const float4*)awp)[i];

    float mx = aw[0];
#pragma unroll
    for (int i = 1; i < 12; ++i) mx = fmaxf(mx, aw[i]);
    float se = 0.f;
#pragma unroll
    for (int i = 0; i < 12; ++i) { aw[i] = __expf(aw[i] - mx); se += aw[i]; }
    const float inv = 1.f / se;

    const float refx = ((lq % 60) + 0.5f) * (1.f / 60.f);
    const float refy = ((lq / 60) + 0.5f) * (1.f / 60.f);
    const int HW[3] = {60, 30, 15};
    const int ST[3] = {0, 3600, 4500};

    const unsigned short* vbase = value + (size_t)b * LIN * 256 + h * 32 + l * 4;

    float a0 = 0.f, a1 = 0.f, a2 = 0.f, a3 = 0.f;
#pragma unroll
    for (int lev = 0; lev < NLEV; ++lev) {
        const int Wl = HW[lev], s0 = ST[lev];
        const float fWl = (float)Wl;
#pragma unroll
        for (int p = 0; p < NPNT; ++p) {
            const int pt = lev * 4 + p;
            const float ox = off[lev * 8 + p * 2];
            const float oy = off[lev * 8 + p * 2 + 1];
            const float px = refx * fWl + ox - 0.5f;
            const float py = refy * fWl + oy - 0.5f;
            const float x0f = floorf(px), y0f = floorf(py);
            const float fx = px - x0f, fy = py - y0f;
            const int x0 = (int)x0f, y0 = (int)y0f;
            const float aww = aw[pt] * inv;
            const float vx0 = (x0 >= 0 && x0 < Wl) ? 1.f : 0.f;
            const float vx1 = (x0 >= -1 && x0 < Wl - 1) ? 1.f : 0.f;
            const float vy0 = (y0 >= 0 && y0 < Wl) ? 1.f : 0.f;
            const float vy1 = (y0 >= -1 && y0 < Wl - 1) ? 1.f : 0.f;
            const int xc0 = min(max(x0, 0), Wl - 1);
            const int xc1 = min(max(x0 + 1, 0), Wl - 1);
            const int yc0 = min(max(y0, 0), Wl - 1);
            const int yc1 = min(max(y0 + 1, 0), Wl - 1);
            const int sx  = xc1 - xc0;
            const int syW = (yc1 - yc0) * Wl;
            const int i00 = s0 + yc0 * Wl + xc0;
            const float w00 = (1.f - fx) * (1.f - fy) * aww * vx0 * vy0;
            const float w01 = fx * (1.f - fy) * aww * vx1 * vy0;
            const float w10 = (1.f - fx) * fy * aww * vx0 * vy1;
            const float w11 = fx * fy * aww * vx1 * vy1;
            const int i01 = i00 + sx;
            const int i10 = i00 + syW;
            const int i11 = i10 + sx;
            const ushort4 g00 = *(const ushort4*)(vbase + (size_t)i00 * 256);
            const ushort4 g01 = *(const ushort4*)(vbase + (size_t)i01 * 256);
            const ushort4 g10 = *(const ushort4*)(vbase + (size_t)i10 * 256);
            const ushort4 g11 = *(const ushort4*)(vbase + (size_t)i11 * 256);
            a0 += b2f(g00.x) * w00 + b2f(g01.x) * w01 + b2f(g10.x) * w10 + b2f(g11.x) * w11;
            a1 += b2f(g00.y) * w00 + b2f(g01.y) * w01 + b2f(g10.y) * w10 + b2f(g11.y) * w11;
            a2 += b2f(g00.z) * w00 + b2f(g01.z) * w01 + b2f(g10.z) * w10 + b2f(g11.z) * w11;
            a3 += b2f(g00.w) * w00 + b2f(g01.w) * w01 + b2f(g10.w) * w10 + b2f(g11.w) * w11;
        }
    }
    ushort4 o;
    o.x = f2b(a0); o.y = f2b(a1); o.z = f2b(a2); o.w = f2b(a3);
    *(ushort4*)(out + (size_t)m * 256 + h * 32 + l * 4) = o;
}

// ---------------------------------------------------------------------------
extern "C" void kernel_launch(void* const* d_in, const int* in_sizes, int n_in,
                              void* d_out, int out_size, void* d_ws, size_t ws_size,
                              hipStream_t stream)
{
    (void)in_sizes; (void)n_in; (void)out_size; (void)ws_size;
    const float* tgt          = (const float*)d_in[0];   // (LQ,B,D): (lq,b)-major rows
    const float* qp           = (const float*)d_in[1];
    const float* src          = (const float*)d_in[2];
    const float* in_proj_w    = (const float*)d_in[5];
    const float* in_proj_b    = (const float*)d_in[6];
    const float* out_proj_w   = (const float*)d_in[7];
    const float* out_proj_b   = (const float*)d_in[8];
    const float* samp_off_w   = (const float*)d_in[9];
    const float* samp_off_b   = (const float*)d_in[10];
    const float* attn_w_w     = (const float*)d_in[11];
    const float* attn_w_b     = (const float*)d_in[12];
    const float* value_proj_w = (const float*)d_in[13];
    const float* value_proj_b = (const float*)d_in[14];
    const float* cross_out_w  = (const float*)d_in[15];
    const float* cross_out_b  = (const float*)d_in[16];
    const float* ln1_g = (const float*)d_in[17];
    const float* ln1_b = (const float*)d_in[18];
    const float* ln2_g = (const float*)d_in[19];
    const float* ln2_b = (const float*)d_in[20];
    const float* ln3_g = (const float*)d_in[21];
    const float* ln3_b = (const float*)d_in[22];
    const float* ffn_w1 = (const float*)d_in[23];
    const float* ffn_b1 = (const float*)d_in[24];
    const float* ffn_w2 = (const float*)d_in[25];
    const float* ffn_b2 = (const float*)d_in[26];
    float* out = (float*)d_out;

    // ---- fp32 arena (floats) ----
    float* ws    = (float*)d_ws;
    float* t     = ws;                    // LN2 out (residual for LN1)
    float* t2    = ws + 7372800;          // LN1 out scratch (cross_ffn self RW)
    float* comb  = ws + 14745600;         // 28800x288 off+aw (raw, fp32)
    float* qpv   = ws + 23040000;         // 1056 qp-proj + 288 cbias
    float* cbias = qpv + 1056;

    // ---- bf16 arena (ushort), after fp32 arena (byte 92,165,376) ----
    unsigned short* bws    = (unsigned short*)((char*)d_ws + 92165376);
    unsigned short* s2     = bws + 7372800;        // valueb+msoutb
    unsigned short* valueb = s2;
    unsigned short* msoutb = s2 + 9676800;
    unsigned short* wtsb   = bws + 46540800;       // 991,232 shorts

    // 1. prep (weight cast + query_pos projections only)
    prep_kernel<<<973, 256, 0, stream>>>(in_proj_w, out_proj_w, value_proj_w,
                                         cross_out_w, samp_off_w, attn_w_w,
                                         ffn_w1, ffn_w2, wtsb,
                                         qp, samp_off_b, attn_w_b, qpv);
    // 2. value projection (M = 37800), fp32 A converted inline
    gemm_af32<<<dim3(296, 2), 256, 0, stream>>>(src, wtsb + 262144, value_proj_b,
                                                valueb, BATCH * LIN, 256, 256);
    // 3. QKV gemm + self-attn + out_proj + LN2 + offs projection [gigafused]
    qkv_attn_ln2_offs_kernel<<<900, 256, 0, stream>>>(
        tgt, wtsb + 0, in_proj_b, qpv,
        wtsb + 196608, out_proj_b, ln2_g, ln2_b, t,
        wtsb + 393216, cbias, comb);
    // 4. deformable sampling with inline softmax/bilinear setup
    msdeform_kernel<<<7200, 256, 0, stream>>>(valueb, comb, msoutb);
    // 5. out = LN3(t2 + FFN(t2)), t2 = LN1(t + cross_out(msout))  [megafused]
    cross_ffn_kernel<<<900, 256, 0, stream>>>(msoutb, wtsb + 327680, cross_out_b,
                                              t, ln1_g, ln1_b, t2,
                                              wtsb + 466944, ffn_b1,
                                              wtsb + 729088, ffn_b2,
                                              ln3_g, ln3_b, out);
}